// Round 6
// baseline (551.906 us; speedup 1.0000x reference)
//
#include <hip/hip_runtime.h>
#include <hip/hip_bf16.h>

// NodeProcessor via MFMA. Single merged edge kernel, transposed LDS feature
// store fT[j][e] (stride 68 u16, <=2-way banks), register-built A-fragments,
// and REGION-BATCHED register prefetch of LDS scalars (one ds_read burst +
// one wait per region instead of a 120-cyc chain per kt iteration).
//   GEMM-S: A_s[64e x 1280k] @ W_S[1280 x 96]  (bf16, B pre-packed frag order)
//   GEMM-V: A_v[p][64e x 1280k] @ W_V[1280 x 32]
// mfma_f32_16x16x32_bf16; A: A[m=lane&15][k=quad*8+j]; B: n=lane&15,k=quad*8+j;
// C/D: col=lane&15, row=quad*4+reg. Region order: ss, dot3, S-epi, cross
// (reuses dot3's v1 registers), sv, vs.

#define NNODES 10000
#define NEDGES 160000

typedef unsigned short u16;
typedef unsigned int u32;
typedef short short8 __attribute__((ext_vector_type(8)));
typedef float f32x4 __attribute__((ext_vector_type(4)));

__device__ __forceinline__ float b2f(u16 u) {
  union { u32 i; float f; } v; v.i = ((u32)u) << 16; return v.f;
}
__device__ __forceinline__ u16 f2b(float f) {  // RNE
  union { float f; u32 i; } v; v.f = f;
  u32 r = v.i + 0x7FFFu + ((v.i >> 16) & 1u);
  return (u16)(r >> 16);
}
// pack two f32 -> dword of two truncated bf16 (lo in low half): 1 v_perm_b32
__device__ __forceinline__ u32 pk2(float lo, float hi) {
  return __builtin_amdgcn_perm(__float_as_uint(hi), __float_as_uint(lo), 0x07060302u);
}
union frag_u { u32 w[4]; short8 s; };

#define INVF  0.02795084971874737f   // 1/sqrt(1280)
#define INV3  0.5773502691896258f    // 1/sqrt(3)
#define INV2  0.7071067811865476f    // 1/sqrt(2)

#define FSTR 68                      // fT row stride in u16

// ---- prep: pack weights into B-frag order + zero accumulators ------------
// WSp u16[6nt][40kt][64lane][8j]; WVp u16[2nt][40kt][64lane][8j]
__global__ void prep_kernel(const float* __restrict__ W_ss, const float* __restrict__ W_vv_s,
                            const float* __restrict__ W_sv, const float* __restrict__ W_vs,
                            const float* __restrict__ W_vv_v,
                            u32* __restrict__ WSd, u32* __restrict__ WVd,
                            float* __restrict__ zr) {
  int t = blockIdx.x * 256 + threadIdx.x;
  if (t < 1600160) zr[t] = 0.f;          // s_n + v_n + stats
  if (t < 61440) {            // W_S dwords
    int d = t;
    int nt = d / 10240, r = d - nt * 10240;
    int kt = r >> 8, l = (r & 255) >> 2, jp = r & 3;
    int n = nt * 16 + (l & 15);
    int k0 = kt * 32 + ((l >> 4) << 3) + jp * 2;
    float f0, f1;
    f0 = (k0     < 1024) ? W_ss[k0 * 96 + n] * INVF       : W_vv_s[(k0 - 1024) * 96 + n] * (INVF * INV3);
    f1 = (k0 + 1 < 1024) ? W_ss[(k0 + 1) * 96 + n] * INVF : W_vv_s[(k0 - 1023) * 96 + n] * (INVF * INV3);
    WSd[d] = (u32)f2b(f0) | ((u32)f2b(f1) << 16);
  } else if (t < 81920) {     // W_V dwords
    int d = t - 61440;
    int nt = d / 10240, r = d - nt * 10240;
    int kt = r >> 8, l = (r & 255) >> 2, jp = r & 3;
    int n = nt * 16 + (l & 15);
    int k0 = kt * 32 + ((l >> 4) << 3) + jp * 2;
    float f[2];
#pragma unroll
    for (int jj = 0; jj < 2; jj++) {
      int k = k0 + jj;
      if (k < 512)       f[jj] = W_sv[k * 32 + n] * INVF;
      else if (k < 1024) f[jj] = W_vs[(k - 512) * 32 + n] * INVF;
      else               f[jj] = W_vv_v[(k - 1024) * 32 + n] * (INVF * INV2);
    }
    WVd[d] = (u32)f2b(f[0]) | ((u32)f2b(f[1]) << 16);
  }
}

// ---- merged edge kernel --------------------------------------------------
__global__ __launch_bounds__(256, 4) void edge_kernel(
    const float* __restrict__ x, const float* __restrict__ ea,
    const int* __restrict__ eidx,
    const u16* __restrict__ WSp, const u16* __restrict__ WVp,
    float* __restrict__ s_n, float* __restrict__ v_n) {
  __shared__ int idxL[64];
  __shared__ u16 fT[200 * FSTR];  // fT[j][e]; j: 0..63 s1, 64..159 v1, 160..175 s2, 176..199 v2
  const int tid = threadIdx.x;
  const int eb = blockIdx.x * 64;

  if (tid < 64) idxL[tid] = eidx[eb + tid];
  __syncthreads();
  for (int t = tid; t < 64 * 200; t += 256) {
    int e = t / 200, j = t - e * 200;
    float v = (j < 160) ? x[(size_t)idxL[e] * 160 + j]
                        : ea[(size_t)(eb + e) * 40 + (j - 160)];
    fT[j * FSTR + e] = f2b(v);
  }
  __syncthreads();

  const int wv = tid >> 6, lane = tid & 63;
  const int ln = lane & 15, quad = lane >> 4;
  const int e = wv * 16 + ln;
  const int qh = quad >> 1, bb = (quad & 1) * 8;

  // hoists (one burst)
  float s2h[8], v2f[24];
#pragma unroll
  for (int i = 0; i < 8; i++)  s2h[i] = b2f(fT[(160 + bb + i) * FSTR + e]);
#pragma unroll
  for (int i = 0; i < 24; i++) v2f[i] = b2f(fT[(176 + i) * FSTR + e]);

  // ================= S phase =================
  f32x4 aS[6];
#pragma unroll
  for (int i = 0; i < 6; i++) aS[i] = (f32x4){0.f, 0.f, 0.f, 0.f};

  // region ss: kt 0..31, af[j] = s1[2kt+qh] * s2h[j]  — batch all 32 scalars
  {
    float s1v[32];
#pragma unroll
    for (int i = 0; i < 32; i++) s1v[i] = b2f(fT[(2 * i + qh) * FSTR + e]);
#pragma unroll 8
    for (int kt = 0; kt < 32; kt++) {
      frag_u A;
#pragma unroll
      for (int jp = 0; jp < 4; jp++)
        A.w[jp] = pk2(s1v[kt] * s2h[2 * jp], s1v[kt] * s2h[2 * jp + 1]);
      const u16* Bb = WSp + (size_t)(kt * 64 + lane) * 8;
#pragma unroll
      for (int nt = 0; nt < 6; nt++) {
        short8 bf = *(const short8*)(Bb + nt * 20480);
        aS[nt] = __builtin_amdgcn_mfma_f32_16x16x32_bf16(A.s, bf, aS[nt], 0, 0, 0);
      }
    }
  }
  // region dot3: kt2 0..7, a = 4kt2+quad — batch v1 (kept for cross region)
  float d3[8][3];
#pragma unroll
  for (int kt2 = 0; kt2 < 8; kt2++) {
    int base = (64 + (4 * kt2 + quad) * 3) * FSTR + e;
#pragma unroll
    for (int p = 0; p < 3; p++) d3[kt2][p] = b2f(fT[base + p * FSTR]);
  }
#pragma unroll 4
  for (int kt2 = 0; kt2 < 8; kt2++) {
    frag_u A;
#pragma unroll
    for (int jp = 0; jp < 4; jp++) {
      int j0 = 2 * jp, j1 = 2 * jp + 1;
      float d0 = d3[kt2][0] * v2f[j0 * 3] + d3[kt2][1] * v2f[j0 * 3 + 1] + d3[kt2][2] * v2f[j0 * 3 + 2];
      float d1 = d3[kt2][0] * v2f[j1 * 3] + d3[kt2][1] * v2f[j1 * 3 + 1] + d3[kt2][2] * v2f[j1 * 3 + 2];
      A.w[jp] = pk2(d0, d1);
    }
    const u16* Bb = WSp + (size_t)((32 + kt2) * 64 + lane) * 8;
#pragma unroll
    for (int nt = 0; nt < 6; nt++) {
      short8 bf = *(const short8*)(Bb + nt * 20480);
      aS[nt] = __builtin_amdgcn_mfma_f32_16x16x32_bf16(A.s, bf, aS[nt], 0, 0, 0);
    }
  }

  // S epilogue: silu -> atomics (nt 0..3); sigmoid gates -> registers (nt 4,5)
  float gateR[8];
#pragma unroll
  for (int r = 0; r < 4; r++) {
    int er = wv * 16 + quad * 4 + r;
    int nid = idxL[er];
#pragma unroll
    for (int nt = 0; nt < 6; nt++) {
      float v = aS[nt][r];
      float sg = 1.f / (1.f + __expf(-v));
      if (nt < 4) atomicAdd(&s_n[nid * 64 + nt * 16 + ln], v * sg);
      else        gateR[(nt - 4) * 4 + r] = sg;
    }
  }

  // ================= V phase =================
  f32x4 aV[3][2];
#pragma unroll
  for (int p = 0; p < 3; p++)
#pragma unroll
    for (int nt = 0; nt < 2; nt++) aV[p][nt] = (f32x4){0.f, 0.f, 0.f, 0.f};

  // region cross: kt2 0..7 — REUSES d3 (same v1 scalars as dot3), no LDS reads
#pragma unroll 4
  for (int kt2 = 0; kt2 < 8; kt2++) {
    const u16* Bb = WVp + (size_t)((32 + kt2) * 64 + lane) * 8;
    short8 bf0 = *(const short8*)(Bb);
    short8 bf1 = *(const short8*)(Bb + 20480);
#pragma unroll
    for (int p = 0; p < 3; p++) {
      const int p1 = (p + 1) % 3, p2 = (p + 2) % 3;
      frag_u A;
#pragma unroll
      for (int jp = 0; jp < 4; jp++) {
        int j0 = 2 * jp, j1 = 2 * jp + 1;
        float d0 = d3[kt2][p1] * v2f[j0 * 3 + p2] - d3[kt2][p2] * v2f[j0 * 3 + p1];
        float d1 = d3[kt2][p1] * v2f[j1 * 3 + p2] - d3[kt2][p2] * v2f[j1 * 3 + p1];
        A.w[jp] = pk2(d0, d1);
      }
      aV[p][0] = __builtin_amdgcn_mfma_f32_16x16x32_bf16(A.s, bf0, aV[p][0], 0, 0, 0);
      aV[p][1] = __builtin_amdgcn_mfma_f32_16x16x32_bf16(A.s, bf1, aV[p][1], 0, 0, 0);
    }
  }
  // region sv: kt 0..15, af_p[j] = s1[4kt+quad] * v2f[j*3+p] — batch 16 scalars
  {
    float s1q[16];
#pragma unroll
    for (int i = 0; i < 16; i++) s1q[i] = b2f(fT[(4 * i + quad) * FSTR + e]);
#pragma unroll 4
    for (int kt = 0; kt < 16; kt++) {
      const u16* Bb = WVp + (size_t)(kt * 64 + lane) * 8;
      short8 bf0 = *(const short8*)(Bb);
      short8 bf1 = *(const short8*)(Bb + 20480);
#pragma unroll
      for (int p = 0; p < 3; p++) {
        frag_u A;
#pragma unroll
        for (int jp = 0; jp < 4; jp++)
          A.w[jp] = pk2(s1q[kt] * v2f[(2 * jp) * 3 + p], s1q[kt] * v2f[(2 * jp + 1) * 3 + p]);
        aV[p][0] = __builtin_amdgcn_mfma_f32_16x16x32_bf16(A.s, bf0, aV[p][0], 0, 0, 0);
        aV[p][1] = __builtin_amdgcn_mfma_f32_16x16x32_bf16(A.s, bf1, aV[p][1], 0, 0, 0);
      }
    }
  }
  // region vs: kt2 0..15, a = 2kt2+qh, af_p[j] = v1[a*3+p] * s2h[j] — 2 halves
#pragma unroll
  for (int h = 0; h < 2; h++) {
    float vv[8][3];
#pragma unroll
    for (int i = 0; i < 8; i++) {
      int base = (64 + (2 * (h * 8 + i) + qh) * 3) * FSTR + e;
#pragma unroll
      for (int p = 0; p < 3; p++) vv[i][p] = b2f(fT[base + p * FSTR]);
    }
#pragma unroll 4
    for (int i = 0; i < 8; i++) {
      int kt2 = h * 8 + i;
      const u16* Bb = WVp + (size_t)((16 + kt2) * 64 + lane) * 8;
      short8 bf0 = *(const short8*)(Bb);
      short8 bf1 = *(const short8*)(Bb + 20480);
#pragma unroll
      for (int p = 0; p < 3; p++) {
        frag_u A;
#pragma unroll
        for (int jp = 0; jp < 4; jp++)
          A.w[jp] = pk2(vv[i][p] * s2h[2 * jp], vv[i][p] * s2h[2 * jp + 1]);
        aV[p][0] = __builtin_amdgcn_mfma_f32_16x16x32_bf16(A.s, bf0, aV[p][0], 0, 0, 0);
        aV[p][1] = __builtin_amdgcn_mfma_f32_16x16x32_bf16(A.s, bf1, aV[p][1], 0, 0, 0);
      }
    }
  }

  // V epilogue: gate + scatter
#pragma unroll
  for (int r = 0; r < 4; r++) {
    int er = wv * 16 + quad * 4 + r;
    int nid = idxL[er];
#pragma unroll
    for (int nt = 0; nt < 2; nt++) {
      int c = nt * 16 + ln;
      float g = gateR[nt * 4 + r];
#pragma unroll
      for (int p = 0; p < 3; p++)
        atomicAdd(&v_n[nid * 96 + c * 3 + p], aV[p][nt][r] * g);
    }
  }
}

// ---- BN stats ------------------------------------------------------------
__global__ void stats_kernel(const float* __restrict__ s_n, const float* __restrict__ v_n,
                             float* __restrict__ stats) {
  int b = blockIdx.x, tid = threadIdx.x;
  int r0 = b * 50;
  int c = tid & 63, rg = tid >> 6;
  float s = 0.f, sq = 0.f;
  for (int r = r0 + rg; r < r0 + 50; r += 4) {
    float v = s_n[r * 64 + c];
    s += v; sq += v * v;
  }
  atomicAdd(&stats[c], s);
  atomicAdd(&stats[64 + c], sq);
  int c2 = tid & 31, rg2 = tid >> 5;
  float vn = 0.f;
  for (int r = r0 + rg2; r < r0 + 50; r += 8) {
    const float* vp = &v_n[r * 96 + c2 * 3];
    vn += vp[0] * vp[0] + vp[1] * vp[1] + vp[2] * vp[2];
  }
  atomicAdd(&stats[128 + c2], vn);
}

// ---- finalize ------------------------------------------------------------
__global__ void finalize_kernel(const float* __restrict__ s_n, const float* __restrict__ v_n,
                                const float* __restrict__ stats,
                                const float* __restrict__ x,
                                const float* __restrict__ bw_s, const float* __restrict__ bb_s,
                                const float* __restrict__ bw_v,
                                float* __restrict__ out) {
  int t = blockIdx.x * 256 + threadIdx.x;
  if (t >= NNODES * 160) return;
  int n = t / 160, j = t - n * 160;
  float xv = x[t];
  float r;
  if (j < 64) {
    float mu  = stats[j] * (1.f / NNODES);
    float var = stats[64 + j] * (1.f / NNODES) - mu * mu;
    var = fmaxf(var, 0.f);
    float v = s_n[n * 64 + j];
    r = (v - mu) * rsqrtf(var + 1e-5f) * bw_s[j] + bb_s[j];
  } else {
    int qq = j - 64;
    int c = qq / 3;
    float vn = stats[128 + c] * (1.f / (3.f * NNODES));
    float v = v_n[n * 96 + qq];
    r = v * rsqrtf(vn + 1e-5f) * bw_v[c];
  }
  out[t] = r + xv;
}

extern "C" void kernel_launch(void* const* d_in, const int* in_sizes, int n_in,
                              void* d_out, int out_size, void* d_ws, size_t ws_size,
                              hipStream_t stream) {
  const float* x      = (const float*)d_in[0];
  const float* ea     = (const float*)d_in[1];
  const float* W_ss   = (const float*)d_in[2];
  const float* W_vv_s = (const float*)d_in[3];
  const float* W_sv   = (const float*)d_in[4];
  const float* W_vs   = (const float*)d_in[5];
  const float* W_vv_v = (const float*)d_in[6];
  const float* bw_s   = (const float*)d_in[7];
  const float* bb_s   = (const float*)d_in[8];
  const float* bw_v   = (const float*)d_in[9];
  const int* eidx     = (const int*)d_in[10];
  float* out = (float*)d_out;

  u16* WSp     = (u16*)d_ws;              // 122880 u16
  u16* WVp     = WSp + 122880;            // 40960 u16
  float* s_n   = (float*)d_ws + 81920;    // 640000
  float* v_n   = s_n + 640000;            // 960000
  float* stats = v_n + 960000;            // 160

  prep_kernel<<<6251, 256, 0, stream>>>(W_ss, W_vv_s, W_sv, W_vs, W_vv_v,
                                        (u32*)WSp, (u32*)WVp, s_n);
  edge_kernel<<<NEDGES / 64, 256, 0, stream>>>(x, ea, eidx, WSp, WVp, s_n, v_n);
  stats_kernel<<<200, 256, 0, stream>>>(s_n, v_n, stats);
  finalize_kernel<<<(NNODES * 160 + 255) / 256, 256, 0, stream>>>(
      s_n, v_n, stats, x, bw_s, bb_s, bw_v, out);
}

// Round 7
// 467.458 us; speedup vs baseline: 1.1807x; 1.1807x over previous
//
#include <hip/hip_runtime.h>
#include <hip/hip_bf16.h>

// NodeProcessor via MFMA. 128 edges/block, 2 row-tiles per lane: every
// B-fragment load feeds 2 MFMAs (tiles e and e+64). LDS features are
// edge-paired dwords fTd[j][ep] = bf16(edge ep) | bf16(edge ep+64)<<16,
// row stride 66 dwords (== 2 mod 32 -> 2-way bank aliasing, free), so one
// ds_read_b32 serves both rows.
//   GEMM-S: A_s[128e x 1280k] @ W_S[1280 x 96]  (bf16, B pre-packed frag order)
//   GEMM-V: A_v[p][128e x 1280k] @ W_V[1280 x 32]
// mfma_f32_16x16x32_bf16; A: A[m=lane&15][k=quad*8+j]; B: n=lane&15,k=quad*8+j;
// C/D: col=lane&15, row=quad*4+reg. Regions: ss, dot3, S-epi, cross (reuses
// dot3 registers), sv, vs, V-epi.

#define NNODES 10000
#define NEDGES 160000
#define EB 128
#define FSTRD 66                    // fTd row stride in dwords

typedef unsigned short u16;
typedef unsigned int u32;
typedef short short8 __attribute__((ext_vector_type(8)));
typedef float f32x4 __attribute__((ext_vector_type(4)));

__device__ __forceinline__ u16 f2b(float f) {  // RNE
  union { float f; u32 i; } v; v.f = f;
  u32 r = v.i + 0x7FFFu + ((v.i >> 16) & 1u);
  return (u16)(r >> 16);
}
__device__ __forceinline__ float lo_f(u32 d) {
  union { u32 i; float f; } v; v.i = d << 16; return v.f;
}
__device__ __forceinline__ float hi_f(u32 d) {
  union { u32 i; float f; } v; v.i = d & 0xFFFF0000u; return v.f;
}
// pack two f32 -> dword of two truncated bf16 (lo in low half): 1 v_perm_b32
__device__ __forceinline__ u32 pk2(float lo, float hi) {
  return __builtin_amdgcn_perm(__float_as_uint(hi), __float_as_uint(lo), 0x07060302u);
}
union frag_u { u32 w[4]; short8 s; };

#define INVF  0.02795084971874737f   // 1/sqrt(1280)
#define INV3  0.5773502691896258f    // 1/sqrt(3)
#define INV2  0.7071067811865476f    // 1/sqrt(2)

// ---- prep: pack weights into B-frag order + zero accumulators ------------
// WSp u16[6nt][40kt][64lane][8j]; WVp u16[2nt][40kt][64lane][8j]
__global__ void prep_kernel(const float* __restrict__ W_ss, const float* __restrict__ W_vv_s,
                            const float* __restrict__ W_sv, const float* __restrict__ W_vs,
                            const float* __restrict__ W_vv_v,
                            u32* __restrict__ WSd, u32* __restrict__ WVd,
                            float* __restrict__ zr) {
  int t = blockIdx.x * 256 + threadIdx.x;
  if (t < 1600160) zr[t] = 0.f;          // s_n + v_n + stats
  if (t < 61440) {            // W_S dwords
    int d = t;
    int nt = d / 10240, r = d - nt * 10240;
    int kt = r >> 8, l = (r & 255) >> 2, jp = r & 3;
    int n = nt * 16 + (l & 15);
    int k0 = kt * 32 + ((l >> 4) << 3) + jp * 2;
    float f0, f1;
    f0 = (k0     < 1024) ? W_ss[k0 * 96 + n] * INVF       : W_vv_s[(k0 - 1024) * 96 + n] * (INVF * INV3);
    f1 = (k0 + 1 < 1024) ? W_ss[(k0 + 1) * 96 + n] * INVF : W_vv_s[(k0 - 1023) * 96 + n] * (INVF * INV3);
    WSd[d] = (u32)f2b(f0) | ((u32)f2b(f1) << 16);
  } else if (t < 81920) {     // W_V dwords
    int d = t - 61440;
    int nt = d / 10240, r = d - nt * 10240;
    int kt = r >> 8, l = (r & 255) >> 2, jp = r & 3;
    int n = nt * 16 + (l & 15);
    int k0 = kt * 32 + ((l >> 4) << 3) + jp * 2;
    float f[2];
#pragma unroll
    for (int jj = 0; jj < 2; jj++) {
      int k = k0 + jj;
      if (k < 512)       f[jj] = W_sv[k * 32 + n] * INVF;
      else if (k < 1024) f[jj] = W_vs[(k - 512) * 32 + n] * INVF;
      else               f[jj] = W_vv_v[(k - 1024) * 32 + n] * (INVF * INV2);
    }
    WVd[d] = (u32)f2b(f[0]) | ((u32)f2b(f[1]) << 16);
  }
}

// ---- edge kernel ---------------------------------------------------------
__global__ __launch_bounds__(256, 2) void edge_kernel(
    const float* __restrict__ x, const float* __restrict__ ea,
    const int* __restrict__ eidx,
    const u16* __restrict__ WSp, const u16* __restrict__ WVp,
    float* __restrict__ s_n, float* __restrict__ v_n) {
  __shared__ int idxL[EB];
  __shared__ u32 fTd[200 * FSTRD];  // [j][ep]: lo=edge ep, hi=edge ep+64
  const int tid = threadIdx.x;
  const int eb = blockIdx.x * EB;

  if (tid < EB) idxL[tid] = eidx[eb + tid];
  __syncthreads();
  // stage: thread handles (ep, j-range); lanes cover consecutive j -> coalesced
  for (int t = tid; t < 64 * 200; t += 256) {
    int ep = t / 200, j = t - ep * 200;
    float vlo, vhi;
    if (j < 160) {
      vlo = x[(size_t)idxL[ep] * 160 + j];
      vhi = x[(size_t)idxL[ep + 64] * 160 + j];
    } else {
      vlo = ea[(size_t)(eb + ep) * 40 + (j - 160)];
      vhi = ea[(size_t)(eb + ep + 64) * 40 + (j - 160)];
    }
    fTd[j * FSTRD + ep] = (u32)f2b(vlo) | ((u32)f2b(vhi) << 16);
  }
  __syncthreads();

  const int wv = tid >> 6, lane = tid & 63;
  const int ln = lane & 15, quad = lane >> 4;
  const int ep = wv * 16 + ln;            // lo row = edge ep, hi row = ep+64
  const int qh = quad >> 1, bb = (quad & 1) * 8;

  // hoists (each dword = both rows)
  float s2l[8], s2h[8], v2l[24], v2h[24];
#pragma unroll
  for (int i = 0; i < 8; i++) {
    u32 d = fTd[(160 + bb + i) * FSTRD + ep];
    s2l[i] = lo_f(d); s2h[i] = hi_f(d);
  }
#pragma unroll
  for (int i = 0; i < 24; i++) {
    u32 d = fTd[(176 + i) * FSTRD + ep];
    v2l[i] = lo_f(d); v2h[i] = hi_f(d);
  }

  // ================= S phase =================
  f32x4 aS[2][6];
#pragma unroll
  for (int t = 0; t < 2; t++)
#pragma unroll
    for (int i = 0; i < 6; i++) aS[t][i] = (f32x4){0.f, 0.f, 0.f, 0.f};

  // region ss: kt 0..31, af[j] = s1[2kt+qh] * s2[j]; chunks of 8
#pragma unroll
  for (int ch = 0; ch < 4; ch++) {
    u32 s1d[8];
#pragma unroll
    for (int i = 0; i < 8; i++)
      s1d[i] = fTd[(2 * (ch * 8 + i) + qh) * FSTRD + ep];
#pragma unroll
    for (int i = 0; i < 8; i++) {
      int kt = ch * 8 + i;
      float slo = lo_f(s1d[i]), shi = hi_f(s1d[i]);
      frag_u Al, Ah;
#pragma unroll
      for (int jp = 0; jp < 4; jp++) {
        Al.w[jp] = pk2(slo * s2l[2 * jp], slo * s2l[2 * jp + 1]);
        Ah.w[jp] = pk2(shi * s2h[2 * jp], shi * s2h[2 * jp + 1]);
      }
      const u16* Bb = WSp + (size_t)(kt * 64 + lane) * 8;
#pragma unroll
      for (int nt = 0; nt < 6; nt++) {
        short8 bf = *(const short8*)(Bb + nt * 20480);
        aS[0][nt] = __builtin_amdgcn_mfma_f32_16x16x32_bf16(Al.s, bf, aS[0][nt], 0, 0, 0);
        aS[1][nt] = __builtin_amdgcn_mfma_f32_16x16x32_bf16(Ah.s, bf, aS[1][nt], 0, 0, 0);
      }
    }
  }
  // region dot3: kt2 0..7, a = 4kt2+quad; v1 kept in regs for cross region
  float d3l[24], d3h[24];
#pragma unroll
  for (int kt2 = 0; kt2 < 8; kt2++) {
    int base = (64 + (4 * kt2 + quad) * 3) * FSTRD + ep;
#pragma unroll
    for (int p = 0; p < 3; p++) {
      u32 d = fTd[base + p * FSTRD];
      d3l[kt2 * 3 + p] = lo_f(d); d3h[kt2 * 3 + p] = hi_f(d);
    }
  }
#pragma unroll 4
  for (int kt2 = 0; kt2 < 8; kt2++) {
    frag_u Al, Ah;
#pragma unroll
    for (int jp = 0; jp < 4; jp++) {
      int j0 = 2 * jp, j1 = 2 * jp + 1;
      float l0 = d3l[kt2*3] * v2l[j0*3] + d3l[kt2*3+1] * v2l[j0*3+1] + d3l[kt2*3+2] * v2l[j0*3+2];
      float l1 = d3l[kt2*3] * v2l[j1*3] + d3l[kt2*3+1] * v2l[j1*3+1] + d3l[kt2*3+2] * v2l[j1*3+2];
      float h0 = d3h[kt2*3] * v2h[j0*3] + d3h[kt2*3+1] * v2h[j0*3+1] + d3h[kt2*3+2] * v2h[j0*3+2];
      float h1 = d3h[kt2*3] * v2h[j1*3] + d3h[kt2*3+1] * v2h[j1*3+1] + d3h[kt2*3+2] * v2h[j1*3+2];
      Al.w[jp] = pk2(l0, l1); Ah.w[jp] = pk2(h0, h1);
    }
    const u16* Bb = WSp + (size_t)((32 + kt2) * 64 + lane) * 8;
#pragma unroll
    for (int nt = 0; nt < 6; nt++) {
      short8 bf = *(const short8*)(Bb + nt * 20480);
      aS[0][nt] = __builtin_amdgcn_mfma_f32_16x16x32_bf16(Al.s, bf, aS[0][nt], 0, 0, 0);
      aS[1][nt] = __builtin_amdgcn_mfma_f32_16x16x32_bf16(Ah.s, bf, aS[1][nt], 0, 0, 0);
    }
  }

  // S epilogue: silu -> atomics (nt 0..3); sigmoid gates -> regs (nt 4,5)
  float gateR[16];                        // [tile*8 + g*4 + r]
#pragma unroll
  for (int t = 0; t < 2; t++) {
#pragma unroll
    for (int r = 0; r < 4; r++) {
      int er = wv * 16 + quad * 4 + r + t * 64;
      int nid = idxL[er];
#pragma unroll
      for (int nt = 0; nt < 6; nt++) {
        float v = aS[t][nt][r];
        float sg = 1.f / (1.f + __expf(-v));
        if (nt < 4) atomicAdd(&s_n[nid * 64 + nt * 16 + ln], v * sg);
        else        gateR[t * 8 + (nt - 4) * 4 + r] = sg;
      }
    }
  }

  // ================= V phase =================
  f32x4 aV[2][3][2];
#pragma unroll
  for (int t = 0; t < 2; t++)
#pragma unroll
    for (int p = 0; p < 3; p++)
#pragma unroll
      for (int nt = 0; nt < 2; nt++) aV[t][p][nt] = (f32x4){0.f, 0.f, 0.f, 0.f};

  // region cross: kt2 0..7 — reuses d3l/d3h, no LDS reads
#pragma unroll 4
  for (int kt2 = 0; kt2 < 8; kt2++) {
    const u16* Bb = WVp + (size_t)((32 + kt2) * 64 + lane) * 8;
    short8 bf0 = *(const short8*)(Bb);
    short8 bf1 = *(const short8*)(Bb + 20480);
#pragma unroll
    for (int p = 0; p < 3; p++) {
      const int p1 = (p + 1) % 3, p2 = (p + 2) % 3;
      frag_u Al, Ah;
#pragma unroll
      for (int jp = 0; jp < 4; jp++) {
        int j0 = 2 * jp, j1 = 2 * jp + 1;
        float l0 = d3l[kt2*3+p1] * v2l[j0*3+p2] - d3l[kt2*3+p2] * v2l[j0*3+p1];
        float l1 = d3l[kt2*3+p1] * v2l[j1*3+p2] - d3l[kt2*3+p2] * v2l[j1*3+p1];
        float h0 = d3h[kt2*3+p1] * v2h[j0*3+p2] - d3h[kt2*3+p2] * v2h[j0*3+p1];
        float h1 = d3h[kt2*3+p1] * v2h[j1*3+p2] - d3h[kt2*3+p2] * v2h[j1*3+p1];
        Al.w[jp] = pk2(l0, l1); Ah.w[jp] = pk2(h0, h1);
      }
      aV[0][p][0] = __builtin_amdgcn_mfma_f32_16x16x32_bf16(Al.s, bf0, aV[0][p][0], 0, 0, 0);
      aV[0][p][1] = __builtin_amdgcn_mfma_f32_16x16x32_bf16(Al.s, bf1, aV[0][p][1], 0, 0, 0);
      aV[1][p][0] = __builtin_amdgcn_mfma_f32_16x16x32_bf16(Ah.s, bf0, aV[1][p][0], 0, 0, 0);
      aV[1][p][1] = __builtin_amdgcn_mfma_f32_16x16x32_bf16(Ah.s, bf1, aV[1][p][1], 0, 0, 0);
    }
  }
  // region sv: kt 0..15, af_p[j] = s1[4kt+quad] * v2[j*3+p]; chunks of 8
#pragma unroll
  for (int ch = 0; ch < 2; ch++) {
    u32 s1d[8];
#pragma unroll
    for (int i = 0; i < 8; i++)
      s1d[i] = fTd[(4 * (ch * 8 + i) + quad) * FSTRD + ep];
#pragma unroll
    for (int i = 0; i < 8; i++) {
      int kt = ch * 8 + i;
      float slo = lo_f(s1d[i]), shi = hi_f(s1d[i]);
      const u16* Bb = WVp + (size_t)(kt * 64 + lane) * 8;
      short8 bf0 = *(const short8*)(Bb);
      short8 bf1 = *(const short8*)(Bb + 20480);
#pragma unroll
      for (int p = 0; p < 3; p++) {
        frag_u Al, Ah;
#pragma unroll
        for (int jp = 0; jp < 4; jp++) {
          Al.w[jp] = pk2(slo * v2l[(2 * jp) * 3 + p], slo * v2l[(2 * jp + 1) * 3 + p]);
          Ah.w[jp] = pk2(shi * v2h[(2 * jp) * 3 + p], shi * v2h[(2 * jp + 1) * 3 + p]);
        }
        aV[0][p][0] = __builtin_amdgcn_mfma_f32_16x16x32_bf16(Al.s, bf0, aV[0][p][0], 0, 0, 0);
        aV[0][p][1] = __builtin_amdgcn_mfma_f32_16x16x32_bf16(Al.s, bf1, aV[0][p][1], 0, 0, 0);
        aV[1][p][0] = __builtin_amdgcn_mfma_f32_16x16x32_bf16(Ah.s, bf0, aV[1][p][0], 0, 0, 0);
        aV[1][p][1] = __builtin_amdgcn_mfma_f32_16x16x32_bf16(Ah.s, bf1, aV[1][p][1], 0, 0, 0);
      }
    }
  }
  // region vs: kt2 0..15, a = 2kt2+qh, af_p[j] = v1[a*3+p] * s2[j]; halves of 8
#pragma unroll
  for (int h = 0; h < 2; h++) {
    float vl[8][3], vh[8][3];
#pragma unroll
    for (int i = 0; i < 8; i++) {
      int base = (64 + (2 * (h * 8 + i) + qh) * 3) * FSTRD + ep;
#pragma unroll
      for (int p = 0; p < 3; p++) {
        u32 d = fTd[base + p * FSTRD];
        vl[i][p] = lo_f(d); vh[i][p] = hi_f(d);
      }
    }
#pragma unroll
    for (int i = 0; i < 8; i++) {
      int kt2 = h * 8 + i;
      const u16* Bb = WVp + (size_t)((16 + kt2) * 64 + lane) * 8;
      short8 bf0 = *(const short8*)(Bb);
      short8 bf1 = *(const short8*)(Bb + 20480);
#pragma unroll
      for (int p = 0; p < 3; p++) {
        frag_u Al, Ah;
#pragma unroll
        for (int jp = 0; jp < 4; jp++) {
          Al.w[jp] = pk2(vl[i][p] * s2l[2 * jp], vl[i][p] * s2l[2 * jp + 1]);
          Ah.w[jp] = pk2(vh[i][p] * s2h[2 * jp], vh[i][p] * s2h[2 * jp + 1]);
        }
        aV[0][p][0] = __builtin_amdgcn_mfma_f32_16x16x32_bf16(Al.s, bf0, aV[0][p][0], 0, 0, 0);
        aV[0][p][1] = __builtin_amdgcn_mfma_f32_16x16x32_bf16(Al.s, bf1, aV[0][p][1], 0, 0, 0);
        aV[1][p][0] = __builtin_amdgcn_mfma_f32_16x16x32_bf16(Ah.s, bf0, aV[1][p][0], 0, 0, 0);
        aV[1][p][1] = __builtin_amdgcn_mfma_f32_16x16x32_bf16(Ah.s, bf1, aV[1][p][1], 0, 0, 0);
      }
    }
  }

  // V epilogue: gate + scatter
#pragma unroll
  for (int t = 0; t < 2; t++) {
#pragma unroll
    for (int r = 0; r < 4; r++) {
      int er = wv * 16 + quad * 4 + r + t * 64;
      int nid = idxL[er];
#pragma unroll
      for (int nt = 0; nt < 2; nt++) {
        int c = nt * 16 + ln;
        float g = gateR[t * 8 + nt * 4 + r];
#pragma unroll
        for (int p = 0; p < 3; p++)
          atomicAdd(&v_n[nid * 96 + c * 3 + p], aV[t][p][nt][r] * g);
      }
    }
  }
}

// ---- BN stats ------------------------------------------------------------
__global__ void stats_kernel(const float* __restrict__ s_n, const float* __restrict__ v_n,
                             float* __restrict__ stats) {
  int b = blockIdx.x, tid = threadIdx.x;
  int r0 = b * 50;
  int c = tid & 63, rg = tid >> 6;
  float s = 0.f, sq = 0.f;
  for (int r = r0 + rg; r < r0 + 50; r += 4) {
    float v = s_n[r * 64 + c];
    s += v; sq += v * v;
  }
  atomicAdd(&stats[c], s);
  atomicAdd(&stats[64 + c], sq);
  int c2 = tid & 31, rg2 = tid >> 5;
  float vn = 0.f;
  for (int r = r0 + rg2; r < r0 + 50; r += 8) {
    const float* vp = &v_n[r * 96 + c2 * 3];
    vn += vp[0] * vp[0] + vp[1] * vp[1] + vp[2] * vp[2];
  }
  atomicAdd(&stats[128 + c2], vn);
}

// ---- finalize ------------------------------------------------------------
__global__ void finalize_kernel(const float* __restrict__ s_n, const float* __restrict__ v_n,
                                const float* __restrict__ stats,
                                const float* __restrict__ x,
                                const float* __restrict__ bw_s, const float* __restrict__ bb_s,
                                const float* __restrict__ bw_v,
                                float* __restrict__ out) {
  int t = blockIdx.x * 256 + threadIdx.x;
  if (t >= NNODES * 160) return;
  int n = t / 160, j = t - n * 160;
  float xv = x[t];
  float r;
  if (j < 64) {
    float mu  = stats[j] * (1.f / NNODES);
    float var = stats[64 + j] * (1.f / NNODES) - mu * mu;
    var = fmaxf(var, 0.f);
    float v = s_n[n * 64 + j];
    r = (v - mu) * rsqrtf(var + 1e-5f) * bw_s[j] + bb_s[j];
  } else {
    int qq = j - 64;
    int c = qq / 3;
    float vn = stats[128 + c] * (1.f / (3.f * NNODES));
    float v = v_n[n * 96 + qq];
    r = v * rsqrtf(vn + 1e-5f) * bw_v[c];
  }
  out[t] = r + xv;
}

extern "C" void kernel_launch(void* const* d_in, const int* in_sizes, int n_in,
                              void* d_out, int out_size, void* d_ws, size_t ws_size,
                              hipStream_t stream) {
  const float* x      = (const float*)d_in[0];
  const float* ea     = (const float*)d_in[1];
  const float* W_ss   = (const float*)d_in[2];
  const float* W_vv_s = (const float*)d_in[3];
  const float* W_sv   = (const float*)d_in[4];
  const float* W_vs   = (const float*)d_in[5];
  const float* W_vv_v = (const float*)d_in[6];
  const float* bw_s   = (const float*)d_in[7];
  const float* bb_s   = (const float*)d_in[8];
  const float* bw_v   = (const float*)d_in[9];
  const int* eidx     = (const int*)d_in[10];
  float* out = (float*)d_out;

  u16* WSp     = (u16*)d_ws;              // 122880 u16
  u16* WVp     = WSp + 122880;            // 40960 u16
  float* s_n   = (float*)d_ws + 81920;    // 640000
  float* v_n   = s_n + 640000;            // 960000
  float* stats = v_n + 960000;            // 160

  prep_kernel<<<6251, 256, 0, stream>>>(W_ss, W_vv_s, W_sv, W_vs, W_vv_v,
                                        (u32*)WSp, (u32*)WVp, s_n);
  edge_kernel<<<NEDGES / EB, 256, 0, stream>>>(x, ea, eidx, WSp, WVp, s_n, v_n);
  stats_kernel<<<200, 256, 0, stream>>>(s_n, v_n, stats);
  finalize_kernel<<<(NNODES * 160 + 255) / 256, 256, 0, stream>>>(
      s_n, v_n, stats, x, bw_s, bb_s, bw_v, out);
}

// Round 8
// 449.806 us; speedup vs baseline: 1.2270x; 1.0392x over previous
//
#include <hip/hip_runtime.h>
#include <hip/hip_bf16.h>

// NodeProcessor via MFMA. 128 edges/block, 2 row-tiles/lane, edge-paired LDS
// features, and EXPLICIT 2-DEEP REGISTER DOUBLE-BUFFERING of B fragments:
// prefetch B(kt+1) before building A(kt); MFMA kt uses B loaded last iter.
// First V-phase B load is issued before the S-epilogue atomics so its wait
// doesn't drain the atomic queue.
//   GEMM-S: A_s[128e x 1280k] @ W_S[1280 x 96]; GEMM-V: A_v[p][128e] @ W_V[1280 x 32]
// mfma_f32_16x16x32_bf16; A: A[m=lane&15][k=quad*8+j]; B: n=lane&15,k=quad*8+j;
// C/D: col=lane&15, row=quad*4+reg.

#define NNODES 10000
#define NEDGES 160000
#define EB 128
#define FSTRD 66                    // fTd row stride in dwords

typedef unsigned short u16;
typedef unsigned int u32;
typedef short short8 __attribute__((ext_vector_type(8)));
typedef float f32x4 __attribute__((ext_vector_type(4)));

__device__ __forceinline__ u16 f2b(float f) {  // RNE
  union { float f; u32 i; } v; v.f = f;
  u32 r = v.i + 0x7FFFu + ((v.i >> 16) & 1u);
  return (u16)(r >> 16);
}
__device__ __forceinline__ float lo_f(u32 d) {
  union { u32 i; float f; } v; v.i = d << 16; return v.f;
}
__device__ __forceinline__ float hi_f(u32 d) {
  union { u32 i; float f; } v; v.i = d & 0xFFFF0000u; return v.f;
}
__device__ __forceinline__ u32 pk2(float lo, float hi) {
  return __builtin_amdgcn_perm(__float_as_uint(hi), __float_as_uint(lo), 0x07060302u);
}
union frag_u { u32 w[4]; short8 s; };

#define INVF  0.02795084971874737f   // 1/sqrt(1280)
#define INV3  0.5773502691896258f    // 1/sqrt(3)
#define INV2  0.7071067811865476f    // 1/sqrt(2)

// ---- prep: pack weights into B-frag order + zero accumulators ------------
__global__ void prep_kernel(const float* __restrict__ W_ss, const float* __restrict__ W_vv_s,
                            const float* __restrict__ W_sv, const float* __restrict__ W_vs,
                            const float* __restrict__ W_vv_v,
                            u32* __restrict__ WSd, u32* __restrict__ WVd,
                            float* __restrict__ zr) {
  int t = blockIdx.x * 256 + threadIdx.x;
  if (t < 1600160) zr[t] = 0.f;          // s_n + v_n + stats
  if (t < 61440) {            // W_S dwords
    int d = t;
    int nt = d / 10240, r = d - nt * 10240;
    int kt = r >> 8, l = (r & 255) >> 2, jp = r & 3;
    int n = nt * 16 + (l & 15);
    int k0 = kt * 32 + ((l >> 4) << 3) + jp * 2;
    float f0, f1;
    f0 = (k0     < 1024) ? W_ss[k0 * 96 + n] * INVF       : W_vv_s[(k0 - 1024) * 96 + n] * (INVF * INV3);
    f1 = (k0 + 1 < 1024) ? W_ss[(k0 + 1) * 96 + n] * INVF : W_vv_s[(k0 - 1023) * 96 + n] * (INVF * INV3);
    WSd[d] = (u32)f2b(f0) | ((u32)f2b(f1) << 16);
  } else if (t < 81920) {     // W_V dwords
    int d = t - 61440;
    int nt = d / 10240, r = d - nt * 10240;
    int kt = r >> 8, l = (r & 255) >> 2, jp = r & 3;
    int n = nt * 16 + (l & 15);
    int k0 = kt * 32 + ((l >> 4) << 3) + jp * 2;
    float f[2];
#pragma unroll
    for (int jj = 0; jj < 2; jj++) {
      int k = k0 + jj;
      if (k < 512)       f[jj] = W_sv[k * 32 + n] * INVF;
      else if (k < 1024) f[jj] = W_vs[(k - 512) * 32 + n] * INVF;
      else               f[jj] = W_vv_v[(k - 1024) * 32 + n] * (INVF * INV2);
    }
    WVd[d] = (u32)f2b(f[0]) | ((u32)f2b(f[1]) << 16);
  }
}

// ---- edge kernel ---------------------------------------------------------
__global__ __launch_bounds__(256, 2) void edge_kernel(
    const float* __restrict__ x, const float* __restrict__ ea,
    const int* __restrict__ eidx,
    const u16* __restrict__ WSp, const u16* __restrict__ WVp,
    float* __restrict__ s_n, float* __restrict__ v_n) {
  __shared__ int idxL[EB];
  __shared__ u32 fTd[200 * FSTRD];  // [j][ep]: lo=edge ep, hi=edge ep+64
  const int tid = threadIdx.x;
  const int eb = blockIdx.x * EB;

  if (tid < EB) idxL[tid] = eidx[eb + tid];
  __syncthreads();
  for (int t = tid; t < 64 * 200; t += 256) {
    int ep = t / 200, j = t - ep * 200;
    float vlo, vhi;
    if (j < 160) {
      vlo = x[(size_t)idxL[ep] * 160 + j];
      vhi = x[(size_t)idxL[ep + 64] * 160 + j];
    } else {
      vlo = ea[(size_t)(eb + ep) * 40 + (j - 160)];
      vhi = ea[(size_t)(eb + ep + 64) * 40 + (j - 160)];
    }
    fTd[j * FSTRD + ep] = (u32)f2b(vlo) | ((u32)f2b(vhi) << 16);
  }
  __syncthreads();

  const int wv = tid >> 6, lane = tid & 63;
  const int ln = lane & 15, quad = lane >> 4;
  const int ep = wv * 16 + ln;
  const int qh = quad >> 1, bb = (quad & 1) * 8;

  // s2 hoists (used in ss and vs regions)
  float s2l[8], s2h[8];
#pragma unroll
  for (int i = 0; i < 8; i++) {
    u32 d = fTd[(160 + bb + i) * FSTRD + ep];
    s2l[i] = lo_f(d); s2h[i] = hi_f(d);
  }

  const u16* WS_l = WSp + (size_t)lane * 8;  // + kt*512 + nt*20480
  const u16* WV_l = WVp + (size_t)lane * 8;

  // ================= S phase (pipelined) =================
  f32x4 aS[2][6];
#pragma unroll
  for (int t = 0; t < 2; t++)
#pragma unroll
    for (int i = 0; i < 6; i++) aS[t][i] = (f32x4){0.f, 0.f, 0.f, 0.f};

  frag_u B0[6], B1[6];
#pragma unroll
  for (int nt = 0; nt < 6; nt++)
    B0[nt].s = *(const short8*)(WS_l + nt * 20480);

  u32 s1d[8];
  float v2l[24], v2h[24];
  float c3l[6], c3h[6];

#pragma unroll
  for (int kt = 0; kt < 40; kt += 2) {
    // chunked scalar loads (compile-time predicates after unroll)
    if (kt < 32 && (kt & 7) == 0) {
#pragma unroll
      for (int i = 0; i < 8; i++)
        s1d[i] = fTd[(2 * (kt + i) + qh) * FSTRD + ep];
    }
    if (kt == 32) {   // v2 hoists needed from dot3 on (and all of V phase)
#pragma unroll
      for (int i = 0; i < 24; i++) {
        u32 d = fTd[(176 + i) * FSTRD + ep];
        v2l[i] = lo_f(d); v2h[i] = hi_f(d);
      }
    }
    if (kt >= 32) {   // dot3 scalars for this kt pair
#pragma unroll
      for (int u = 0; u < 2; u++) {
        int base = (64 + (4 * (kt + u - 32) + quad) * 3) * FSTRD + ep;
#pragma unroll
        for (int p = 0; p < 3; p++) {
          u32 d = fTd[base + p * FSTRD];
          c3l[u * 3 + p] = lo_f(d); c3h[u * 3 + p] = hi_f(d);
        }
      }
    }
    // prefetch B(kt+1)
#pragma unroll
    for (int nt = 0; nt < 6; nt++)
      B1[nt].s = *(const short8*)(WS_l + (size_t)(kt + 1) * 512 + nt * 20480);
    // build + MFMA kt with B0
    {
      frag_u Al, Ah;
      if (kt < 32) {
        float slo = lo_f(s1d[kt & 7]), shi = hi_f(s1d[kt & 7]);
#pragma unroll
        for (int jp = 0; jp < 4; jp++) {
          Al.w[jp] = pk2(slo * s2l[2 * jp], slo * s2l[2 * jp + 1]);
          Ah.w[jp] = pk2(shi * s2h[2 * jp], shi * s2h[2 * jp + 1]);
        }
      } else {
#pragma unroll
        for (int jp = 0; jp < 4; jp++) {
          int j0 = 2 * jp, j1 = 2 * jp + 1;
          float l0 = c3l[0]*v2l[j0*3] + c3l[1]*v2l[j0*3+1] + c3l[2]*v2l[j0*3+2];
          float l1 = c3l[0]*v2l[j1*3] + c3l[1]*v2l[j1*3+1] + c3l[2]*v2l[j1*3+2];
          float h0 = c3h[0]*v2h[j0*3] + c3h[1]*v2h[j0*3+1] + c3h[2]*v2h[j0*3+2];
          float h1 = c3h[0]*v2h[j1*3] + c3h[1]*v2h[j1*3+1] + c3h[2]*v2h[j1*3+2];
          Al.w[jp] = pk2(l0, l1); Ah.w[jp] = pk2(h0, h1);
        }
      }
#pragma unroll
      for (int nt = 0; nt < 6; nt++) {
        aS[0][nt] = __builtin_amdgcn_mfma_f32_16x16x32_bf16(Al.s, B0[nt].s, aS[0][nt], 0, 0, 0);
        aS[1][nt] = __builtin_amdgcn_mfma_f32_16x16x32_bf16(Ah.s, B0[nt].s, aS[1][nt], 0, 0, 0);
      }
    }
    // prefetch B(kt+2)
    if (kt + 2 < 40) {
#pragma unroll
      for (int nt = 0; nt < 6; nt++)
        B0[nt].s = *(const short8*)(WS_l + (size_t)(kt + 2) * 512 + nt * 20480);
    }
    // build + MFMA kt+1 with B1
    {
      frag_u Al, Ah;
      if (kt + 1 < 32) {
        float slo = lo_f(s1d[(kt + 1) & 7]), shi = hi_f(s1d[(kt + 1) & 7]);
#pragma unroll
        for (int jp = 0; jp < 4; jp++) {
          Al.w[jp] = pk2(slo * s2l[2 * jp], slo * s2l[2 * jp + 1]);
          Ah.w[jp] = pk2(shi * s2h[2 * jp], shi * s2h[2 * jp + 1]);
        }
      } else {
#pragma unroll
        for (int jp = 0; jp < 4; jp++) {
          int j0 = 2 * jp, j1 = 2 * jp + 1;
          float l0 = c3l[3]*v2l[j0*3] + c3l[4]*v2l[j0*3+1] + c3l[5]*v2l[j0*3+2];
          float l1 = c3l[3]*v2l[j1*3] + c3l[4]*v2l[j1*3+1] + c3l[5]*v2l[j1*3+2];
          float h0 = c3h[3]*v2h[j0*3] + c3h[4]*v2h[j0*3+1] + c3h[5]*v2h[j0*3+2];
          float h1 = c3h[3]*v2h[j1*3] + c3h[4]*v2h[j1*3+1] + c3h[5]*v2h[j1*3+2];
          Al.w[jp] = pk2(l0, l1); Ah.w[jp] = pk2(h0, h1);
        }
      }
#pragma unroll
      for (int nt = 0; nt < 6; nt++) {
        aS[0][nt] = __builtin_amdgcn_mfma_f32_16x16x32_bf16(Al.s, B1[nt].s, aS[0][nt], 0, 0, 0);
        aS[1][nt] = __builtin_amdgcn_mfma_f32_16x16x32_bf16(Ah.s, B1[nt].s, aS[1][nt], 0, 0, 0);
      }
    }
  }

  // first V-phase B prefetch BEFORE the atomic epilogue (V kt order starts at 32)
  frag_u C0[2], C1[2];
#pragma unroll
  for (int nt = 0; nt < 2; nt++)
    C0[nt].s = *(const short8*)(WV_l + (size_t)32 * 512 + nt * 20480);

  // S epilogue: silu -> atomics (nt 0..3); sigmoid gates -> regs (nt 4,5)
  float gateR[16];
#pragma unroll
  for (int t = 0; t < 2; t++) {
#pragma unroll
    for (int r = 0; r < 4; r++) {
      int er = wv * 16 + quad * 4 + r + t * 64;
      int nid = idxL[er];
#pragma unroll
      for (int nt = 0; nt < 6; nt++) {
        float v = aS[t][nt][r];
        float sg = 1.f / (1.f + __expf(-v));
        if (nt < 4) atomicAdd(&s_n[nid * 64 + nt * 16 + ln], v * sg);
        else        gateR[t * 8 + (nt - 4) * 4 + r] = sg;
      }
    }
  }

  // ================= V phase (pipelined) =================
  // kt order: 32..39 (cross), 0..15 (sv), 16..31 (vs); i -> kt mapping below.
  f32x4 aV[2][3][2];
#pragma unroll
  for (int t = 0; t < 2; t++)
#pragma unroll
    for (int p = 0; p < 3; p++)
#pragma unroll
      for (int nt = 0; nt < 2; nt++) aV[t][p][nt] = (f32x4){0.f, 0.f, 0.f, 0.f};

  float vvl[6], vvh[6];

#pragma unroll
  for (int i = 0; i < 40; i += 2) {
    const int kt  = (i     < 8) ? (32 + i)     : (i - 8);
    const int ktb = (i + 1 < 8) ? (32 + i + 1) : (i + 1 - 8);
    // chunked scalar loads
    if (i < 8) {            // cross scalars for this kt pair (same addrs as dot3)
#pragma unroll
      for (int u = 0; u < 2; u++) {
        int base = (64 + (4 * (kt + u - 32) + quad) * 3) * FSTRD + ep;
#pragma unroll
        for (int p = 0; p < 3; p++) {
          u32 d = fTd[base + p * FSTRD];
          c3l[u * 3 + p] = lo_f(d); c3h[u * 3 + p] = hi_f(d);
        }
      }
    }
    if (i == 8 || i == 16) { // sv scalars, 8 kts
#pragma unroll
      for (int u = 0; u < 8; u++)
        s1d[u] = fTd[(4 * (kt + u) + quad) * FSTRD + ep];
    }
    if (i >= 24) {           // vs scalars for this kt pair
#pragma unroll
      for (int u = 0; u < 2; u++) {
        int base = (64 + (2 * (kt + u - 16) + qh) * 3) * FSTRD + ep;
#pragma unroll
        for (int p = 0; p < 3; p++) {
          u32 d = fTd[base + p * FSTRD];
          vvl[u * 3 + p] = lo_f(d); vvh[u * 3 + p] = hi_f(d);
        }
      }
    }
    // prefetch C(i+1)
#pragma unroll
    for (int nt = 0; nt < 2; nt++)
      C1[nt].s = *(const short8*)(WV_l + (size_t)ktb * 512 + nt * 20480);
    // build + MFMA kt with C0
#pragma unroll
    for (int p = 0; p < 3; p++) {
      frag_u Al, Ah;
      if (i < 8) {           // cross, u=0
        const int p1 = (p + 1) % 3, p2 = (p + 2) % 3;
#pragma unroll
        for (int jp = 0; jp < 4; jp++) {
          int j0 = 2 * jp, j1 = 2 * jp + 1;
          float l0 = c3l[p1]*v2l[j0*3+p2] - c3l[p2]*v2l[j0*3+p1];
          float l1 = c3l[p1]*v2l[j1*3+p2] - c3l[p2]*v2l[j1*3+p1];
          float h0 = c3h[p1]*v2h[j0*3+p2] - c3h[p2]*v2h[j0*3+p1];
          float h1 = c3h[p1]*v2h[j1*3+p2] - c3h[p2]*v2h[j1*3+p1];
          Al.w[jp] = pk2(l0, l1); Ah.w[jp] = pk2(h0, h1);
        }
      } else if (i < 24) {   // sv
        float slo = lo_f(s1d[kt & 7]), shi = hi_f(s1d[kt & 7]);
#pragma unroll
        for (int jp = 0; jp < 4; jp++) {
          Al.w[jp] = pk2(slo * v2l[(2*jp)*3 + p], slo * v2l[(2*jp+1)*3 + p]);
          Ah.w[jp] = pk2(shi * v2h[(2*jp)*3 + p], shi * v2h[(2*jp+1)*3 + p]);
        }
      } else {               // vs, u=0
#pragma unroll
        for (int jp = 0; jp < 4; jp++) {
          Al.w[jp] = pk2(vvl[p] * s2l[2*jp], vvl[p] * s2l[2*jp+1]);
          Ah.w[jp] = pk2(vvh[p] * s2h[2*jp], vvh[p] * s2h[2*jp+1]);
        }
      }
      aV[0][p][0] = __builtin_amdgcn_mfma_f32_16x16x32_bf16(Al.s, C0[0].s, aV[0][p][0], 0, 0, 0);
      aV[0][p][1] = __builtin_amdgcn_mfma_f32_16x16x32_bf16(Al.s, C0[1].s, aV[0][p][1], 0, 0, 0);
      aV[1][p][0] = __builtin_amdgcn_mfma_f32_16x16x32_bf16(Ah.s, C0[0].s, aV[1][p][0], 0, 0, 0);
      aV[1][p][1] = __builtin_amdgcn_mfma_f32_16x16x32_bf16(Ah.s, C0[1].s, aV[1][p][1], 0, 0, 0);
    }
    // prefetch C(i+2)
    if (i + 2 < 40) {
      const int ktc = (i + 2 < 8) ? (32 + i + 2) : (i + 2 - 8);
#pragma unroll
      for (int nt = 0; nt < 2; nt++)
        C0[nt].s = *(const short8*)(WV_l + (size_t)ktc * 512 + nt * 20480);
    }
    // build + MFMA kt+1 with C1
#pragma unroll
    for (int p = 0; p < 3; p++) {
      frag_u Al, Ah;
      if (i < 8) {           // cross, u=1
        const int p1 = (p + 1) % 3, p2 = (p + 2) % 3;
#pragma unroll
        for (int jp = 0; jp < 4; jp++) {
          int j0 = 2 * jp, j1 = 2 * jp + 1;
          float l0 = c3l[3+p1]*v2l[j0*3+p2] - c3l[3+p2]*v2l[j0*3+p1];
          float l1 = c3l[3+p1]*v2l[j1*3+p2] - c3l[3+p2]*v2l[j1*3+p1];
          float h0 = c3h[3+p1]*v2h[j0*3+p2] - c3h[3+p2]*v2h[j0*3+p1];
          float h1 = c3h[3+p1]*v2h[j1*3+p2] - c3h[3+p2]*v2h[j1*3+p1];
          Al.w[jp] = pk2(l0, l1); Ah.w[jp] = pk2(h0, h1);
        }
      } else if (i < 24) {   // sv
        float slo = lo_f(s1d[ktb & 7]), shi = hi_f(s1d[ktb & 7]);
#pragma unroll
        for (int jp = 0; jp < 4; jp++) {
          Al.w[jp] = pk2(slo * v2l[(2*jp)*3 + p], slo * v2l[(2*jp+1)*3 + p]);
          Ah.w[jp] = pk2(shi * v2h[(2*jp)*3 + p], shi * v2h[(2*jp+1)*3 + p]);
        }
      } else {               // vs, u=1
#pragma unroll
        for (int jp = 0; jp < 4; jp++) {
          Al.w[jp] = pk2(vvl[3+p] * s2l[2*jp], vvl[3+p] * s2l[2*jp+1]);
          Ah.w[jp] = pk2(vvh[3+p] * s2h[2*jp], vvh[3+p] * s2h[2*jp+1]);
        }
      }
      aV[0][p][0] = __builtin_amdgcn_mfma_f32_16x16x32_bf16(Al.s, C1[0].s, aV[0][p][0], 0, 0, 0);
      aV[0][p][1] = __builtin_amdgcn_mfma_f32_16x16x32_bf16(Al.s, C1[1].s, aV[0][p][1], 0, 0, 0);
      aV[1][p][0] = __builtin_amdgcn_mfma_f32_16x16x32_bf16(Ah.s, C1[0].s, aV[1][p][0], 0, 0, 0);
      aV[1][p][1] = __builtin_amdgcn_mfma_f32_16x16x32_bf16(Ah.s, C1[1].s, aV[1][p][1], 0, 0, 0);
    }
  }

  // V epilogue: gate + scatter
#pragma unroll
  for (int t = 0; t < 2; t++) {
#pragma unroll
    for (int r = 0; r < 4; r++) {
      int er = wv * 16 + quad * 4 + r + t * 64;
      int nid = idxL[er];
#pragma unroll
      for (int nt = 0; nt < 2; nt++) {
        int c = nt * 16 + ln;
        float g = gateR[t * 8 + nt * 4 + r];
#pragma unroll
        for (int p = 0; p < 3; p++)
          atomicAdd(&v_n[nid * 96 + c * 3 + p], aV[t][p][nt][r] * g);
      }
    }
  }
}

// ---- BN stats ------------------------------------------------------------
__global__ void stats_kernel(const float* __restrict__ s_n, const float* __restrict__ v_n,
                             float* __restrict__ stats) {
  int b = blockIdx.x, tid = threadIdx.x;
  int r0 = b * 50;
  int c = tid & 63, rg = tid >> 6;
  float s = 0.f, sq = 0.f;
  for (int r = r0 + rg; r < r0 + 50; r += 4) {
    float v = s_n[r * 64 + c];
    s += v; sq += v * v;
  }
  atomicAdd(&stats[c], s);
  atomicAdd(&stats[64 + c], sq);
  int c2 = tid & 31, rg2 = tid >> 5;
  float vn = 0.f;
  for (int r = r0 + rg2; r < r0 + 50; r += 8) {
    const float* vp = &v_n[r * 96 + c2 * 3];
    vn += vp[0] * vp[0] + vp[1] * vp[1] + vp[2] * vp[2];
  }
  atomicAdd(&stats[128 + c2], vn);
}

// ---- finalize ------------------------------------------------------------
__global__ void finalize_kernel(const float* __restrict__ s_n, const float* __restrict__ v_n,
                                const float* __restrict__ stats,
                                const float* __restrict__ x,
                                const float* __restrict__ bw_s, const float* __restrict__ bb_s,
                                const float* __restrict__ bw_v,
                                float* __restrict__ out) {
  int t = blockIdx.x * 256 + threadIdx.x;
  if (t >= NNODES * 160) return;
  int n = t / 160, j = t - n * 160;
  float xv = x[t];
  float r;
  if (j < 64) {
    float mu  = stats[j] * (1.f / NNODES);
    float var = stats[64 + j] * (1.f / NNODES) - mu * mu;
    var = fmaxf(var, 0.f);
    float v = s_n[n * 64 + j];
    r = (v - mu) * rsqrtf(var + 1e-5f) * bw_s[j] + bb_s[j];
  } else {
    int qq = j - 64;
    int c = qq / 3;
    float vn = stats[128 + c] * (1.f / (3.f * NNODES));
    float v = v_n[n * 96 + qq];
    r = v * rsqrtf(vn + 1e-5f) * bw_v[c];
  }
  out[t] = r + xv;
}

extern "C" void kernel_launch(void* const* d_in, const int* in_sizes, int n_in,
                              void* d_out, int out_size, void* d_ws, size_t ws_size,
                              hipStream_t stream) {
  const float* x      = (const float*)d_in[0];
  const float* ea     = (const float*)d_in[1];
  const float* W_ss   = (const float*)d_in[2];
  const float* W_vv_s = (const float*)d_in[3];
  const float* W_sv   = (const float*)d_in[4];
  const float* W_vs   = (const float*)d_in[5];
  const float* W_vv_v = (const float*)d_in[6];
  const float* bw_s   = (const float*)d_in[7];
  const float* bb_s   = (const float*)d_in[8];
  const float* bw_v   = (const float*)d_in[9];
  const int* eidx     = (const int*)d_in[10];
  float* out = (float*)d_out;

  u16* WSp     = (u16*)d_ws;              // 122880 u16
  u16* WVp     = WSp + 122880;            // 40960 u16
  float* s_n   = (float*)d_ws + 81920;    // 640000
  float* v_n   = s_n + 640000;            // 960000
  float* stats = v_n + 960000;            // 160

  prep_kernel<<<6251, 256, 0, stream>>>(W_ss, W_vv_s, W_sv, W_vs, W_vv_v,
                                        (u32*)WSp, (u32*)WVp, s_n);
  edge_kernel<<<NEDGES / EB, 256, 0, stream>>>(x, ea, eidx, WSp, WVp, s_n, v_n);
  stats_kernel<<<200, 256, 0, stream>>>(s_n, v_n, stats);
  finalize_kernel<<<(NNODES * 160 + 255) / 256, 256, 0, stream>>>(
      s_n, v_n, stats, x, bw_s, bb_s, bw_v, out);
}

// Round 9
// 448.188 us; speedup vs baseline: 1.2314x; 1.0036x over previous
//
#include <hip/hip_runtime.h>
#include <hip/hip_bf16.h>

// NodeProcessor via MFMA. R9: same algorithm as R8 (128 edges/block, 2 row
// tiles/lane, edge-paired LDS features, 2-deep B register dbuf) but with
// ROLLED region loops (#pragma unroll 1) and compact 2-kt bodies so the hot
// code fits the 32 KB L1 I-cache (R4-R8 fully-unrolled bodies ~50 KB thrash
// it -> both pipes idle at 24%/10% despite no data-side bottleneck).
//   GEMM-S: A_s[128e x 1280k] @ W_S[1280 x 96]; GEMM-V: A_v[p][128e] @ W_V[1280 x 32]
// mfma_f32_16x16x32_bf16; A: A[m=lane&15][k=quad*8+j]; B: n=lane&15,k=quad*8+j;
// C/D: col=lane&15, row=quad*4+reg.

#define NNODES 10000
#define NEDGES 160000
#define EB 128
#define FSTRD 66                    // fTd row stride in dwords

typedef unsigned short u16;
typedef unsigned int u32;
typedef short short8 __attribute__((ext_vector_type(8)));
typedef float f32x4 __attribute__((ext_vector_type(4)));

__device__ __forceinline__ u16 f2b(float f) {  // RNE
  union { float f; u32 i; } v; v.f = f;
  u32 r = v.i + 0x7FFFu + ((v.i >> 16) & 1u);
  return (u16)(r >> 16);
}
__device__ __forceinline__ float lo_f(u32 d) {
  union { u32 i; float f; } v; v.i = d << 16; return v.f;
}
__device__ __forceinline__ float hi_f(u32 d) {
  union { u32 i; float f; } v; v.i = d & 0xFFFF0000u; return v.f;
}
__device__ __forceinline__ u32 pk2(float lo, float hi) {
  return __builtin_amdgcn_perm(__float_as_uint(hi), __float_as_uint(lo), 0x07060302u);
}
union frag_u { u32 w[4]; short8 s; };

#define INVF  0.02795084971874737f   // 1/sqrt(1280)
#define INV3  0.5773502691896258f    // 1/sqrt(3)
#define INV2  0.7071067811865476f    // 1/sqrt(2)

// ---- prep: pack weights into B-frag order + zero accumulators ------------
__global__ void prep_kernel(const float* __restrict__ W_ss, const float* __restrict__ W_vv_s,
                            const float* __restrict__ W_sv, const float* __restrict__ W_vs,
                            const float* __restrict__ W_vv_v,
                            u32* __restrict__ WSd, u32* __restrict__ WVd,
                            float* __restrict__ zr) {
  int t = blockIdx.x * 256 + threadIdx.x;
  if (t < 1600160) zr[t] = 0.f;          // s_n + v_n + stats
  if (t < 61440) {            // W_S dwords
    int d = t;
    int nt = d / 10240, r = d - nt * 10240;
    int kt = r >> 8, l = (r & 255) >> 2, jp = r & 3;
    int n = nt * 16 + (l & 15);
    int k0 = kt * 32 + ((l >> 4) << 3) + jp * 2;
    float f0, f1;
    f0 = (k0     < 1024) ? W_ss[k0 * 96 + n] * INVF       : W_vv_s[(k0 - 1024) * 96 + n] * (INVF * INV3);
    f1 = (k0 + 1 < 1024) ? W_ss[(k0 + 1) * 96 + n] * INVF : W_vv_s[(k0 - 1023) * 96 + n] * (INVF * INV3);
    WSd[d] = (u32)f2b(f0) | ((u32)f2b(f1) << 16);
  } else if (t < 81920) {     // W_V dwords
    int d = t - 61440;
    int nt = d / 10240, r = d - nt * 10240;
    int kt = r >> 8, l = (r & 255) >> 2, jp = r & 3;
    int n = nt * 16 + (l & 15);
    int k0 = kt * 32 + ((l >> 4) << 3) + jp * 2;
    float f[2];
#pragma unroll
    for (int jj = 0; jj < 2; jj++) {
      int k = k0 + jj;
      if (k < 512)       f[jj] = W_sv[k * 32 + n] * INVF;
      else if (k < 1024) f[jj] = W_vs[(k - 512) * 32 + n] * INVF;
      else               f[jj] = W_vv_v[(k - 1024) * 32 + n] * (INVF * INV2);
    }
    WVd[d] = (u32)f2b(f[0]) | ((u32)f2b(f[1]) << 16);
  }
}

// ---- edge kernel ---------------------------------------------------------
__global__ __launch_bounds__(256, 2) void edge_kernel(
    const float* __restrict__ x, const float* __restrict__ ea,
    const int* __restrict__ eidx,
    const u16* __restrict__ WSp, const u16* __restrict__ WVp,
    float* __restrict__ s_n, float* __restrict__ v_n) {
  __shared__ int idxL[EB];
  __shared__ u32 fTd[200 * FSTRD];  // [j][ep]: lo=edge ep, hi=edge ep+64
  const int tid = threadIdx.x;
  const int eb = blockIdx.x * EB;

  if (tid < EB) idxL[tid] = eidx[eb + tid];
  __syncthreads();
#pragma unroll 1
  for (int t = tid; t < 64 * 200; t += 256) {
    int ep = t / 200, j = t - ep * 200;
    float vlo, vhi;
    if (j < 160) {
      vlo = x[(size_t)idxL[ep] * 160 + j];
      vhi = x[(size_t)idxL[ep + 64] * 160 + j];
    } else {
      vlo = ea[(size_t)(eb + ep) * 40 + (j - 160)];
      vhi = ea[(size_t)(eb + ep + 64) * 40 + (j - 160)];
    }
    fTd[j * FSTRD + ep] = (u32)f2b(vlo) | ((u32)f2b(vhi) << 16);
  }
  __syncthreads();

  const int wv = tid >> 6, lane = tid & 63;
  const int ln = lane & 15, quad = lane >> 4;
  const int ep = wv * 16 + ln;
  const int qh = quad >> 1, bb = (quad & 1) * 8;

  // hoists (each dword = both rows)
  float s2l[8], s2h[8], v2l[24], v2h[24];
#pragma unroll
  for (int i = 0; i < 8; i++) {
    u32 d = fTd[(160 + bb + i) * FSTRD + ep];
    s2l[i] = lo_f(d); s2h[i] = hi_f(d);
  }
#pragma unroll
  for (int i = 0; i < 24; i++) {
    u32 d = fTd[(176 + i) * FSTRD + ep];
    v2l[i] = lo_f(d); v2h[i] = hi_f(d);
  }

  const u16* WS_l = WSp + (size_t)lane * 8;  // + kt*512 + nt*20480
  const u16* WV_l = WVp + (size_t)lane * 8;

#define LOAD_BS(B, ktv) { _Pragma("unroll") \
  for (int nt = 0; nt < 6; nt++) B[nt].s = *(const short8*)(WS_l + (size_t)(ktv) * 512 + nt * 20480); }
#define LOAD_BV(C, ktv) { _Pragma("unroll") \
  for (int nt = 0; nt < 2; nt++) C[nt].s = *(const short8*)(WV_l + (size_t)(ktv) * 512 + nt * 20480); }
#define MFMA_S(Al, Ah, B) { _Pragma("unroll") \
  for (int nt = 0; nt < 6; nt++) { \
    aS[0][nt] = __builtin_amdgcn_mfma_f32_16x16x32_bf16(Al.s, B[nt].s, aS[0][nt], 0, 0, 0); \
    aS[1][nt] = __builtin_amdgcn_mfma_f32_16x16x32_bf16(Ah.s, B[nt].s, aS[1][nt], 0, 0, 0); } }
#define MFMA_V(Al, Ah, C, p) { \
    aV[0][p][0] = __builtin_amdgcn_mfma_f32_16x16x32_bf16(Al.s, C[0].s, aV[0][p][0], 0, 0, 0); \
    aV[0][p][1] = __builtin_amdgcn_mfma_f32_16x16x32_bf16(Al.s, C[1].s, aV[0][p][1], 0, 0, 0); \
    aV[1][p][0] = __builtin_amdgcn_mfma_f32_16x16x32_bf16(Ah.s, C[0].s, aV[1][p][0], 0, 0, 0); \
    aV[1][p][1] = __builtin_amdgcn_mfma_f32_16x16x32_bf16(Ah.s, C[1].s, aV[1][p][1], 0, 0, 0); }

  // ================= S phase =================
  f32x4 aS[2][6];
#pragma unroll
  for (int t = 0; t < 2; t++)
#pragma unroll
    for (int i = 0; i < 6; i++) aS[t][i] = (f32x4){0.f, 0.f, 0.f, 0.f};

  frag_u B0[6], B1[6];
  LOAD_BS(B0, 0);

  // region ss: kt 0..31 (rolled, 2 kt per iter)
#pragma unroll 1
  for (int c = 0; c < 16; c++) {
    int kt = 2 * c;
    u32 dA = fTd[(2 * kt + qh) * FSTRD + ep];
    u32 dB = fTd[(2 * kt + 2 + qh) * FSTRD + ep];
    LOAD_BS(B1, kt + 1);
    {
      frag_u Al, Ah;
      float slo = lo_f(dA), shi = hi_f(dA);
#pragma unroll
      for (int jp = 0; jp < 4; jp++) {
        Al.w[jp] = pk2(slo * s2l[2 * jp], slo * s2l[2 * jp + 1]);
        Ah.w[jp] = pk2(shi * s2h[2 * jp], shi * s2h[2 * jp + 1]);
      }
      MFMA_S(Al, Ah, B0);
    }
    LOAD_BS(B0, kt + 2);   // c==15 loads kt=32 (dot3's first B) — chain continues
    {
      frag_u Al, Ah;
      float slo = lo_f(dB), shi = hi_f(dB);
#pragma unroll
      for (int jp = 0; jp < 4; jp++) {
        Al.w[jp] = pk2(slo * s2l[2 * jp], slo * s2l[2 * jp + 1]);
        Ah.w[jp] = pk2(shi * s2h[2 * jp], shi * s2h[2 * jp + 1]);
      }
      MFMA_S(Al, Ah, B1);
    }
  }
  // region dot3: kt 32..39 (rolled, 2 kt per iter)
#pragma unroll 1
  for (int c = 0; c < 4; c++) {
    int kt = 32 + 2 * c;
    int r0 = (64 + (4 * (kt - 32) + quad) * 3) * FSTRD + ep;
    int r1 = r0 + 12 * FSTRD;
    u32 d0 = fTd[r0], d1 = fTd[r0 + FSTRD], d2 = fTd[r0 + 2 * FSTRD];
    u32 e0 = fTd[r1], e1 = fTd[r1 + FSTRD], e2 = fTd[r1 + 2 * FSTRD];
    LOAD_BS(B1, kt + 1);
    {
      frag_u Al, Ah;
      float x0 = lo_f(d0), x1 = lo_f(d1), x2 = lo_f(d2);
      float y0 = hi_f(d0), y1 = hi_f(d1), y2 = hi_f(d2);
#pragma unroll
      for (int jp = 0; jp < 4; jp++) {
        int j0 = 6 * jp, j1 = 6 * jp + 3;
        Al.w[jp] = pk2(x0*v2l[j0] + x1*v2l[j0+1] + x2*v2l[j0+2],
                       x0*v2l[j1] + x1*v2l[j1+1] + x2*v2l[j1+2]);
        Ah.w[jp] = pk2(y0*v2h[j0] + y1*v2h[j0+1] + y2*v2h[j0+2],
                       y0*v2h[j1] + y1*v2h[j1+1] + y2*v2h[j1+2]);
      }
      MFMA_S(Al, Ah, B0);
    }
    LOAD_BS(B0, kt + 2);   // c==3 reads adjacent (valid) region; never consumed
    {
      frag_u Al, Ah;
      float x0 = lo_f(e0), x1 = lo_f(e1), x2 = lo_f(e2);
      float y0 = hi_f(e0), y1 = hi_f(e1), y2 = hi_f(e2);
#pragma unroll
      for (int jp = 0; jp < 4; jp++) {
        int j0 = 6 * jp, j1 = 6 * jp + 3;
        Al.w[jp] = pk2(x0*v2l[j0] + x1*v2l[j0+1] + x2*v2l[j0+2],
                       x0*v2l[j1] + x1*v2l[j1+1] + x2*v2l[j1+2]);
        Ah.w[jp] = pk2(y0*v2h[j0] + y1*v2h[j0+1] + y2*v2h[j0+2],
                       y0*v2h[j1] + y1*v2h[j1+1] + y2*v2h[j1+2]);
      }
      MFMA_S(Al, Ah, B1);
    }
  }

  // first V B prefetch (cross starts at kt=32) BEFORE the atomic epilogue
  frag_u C0[2], C1[2];
  LOAD_BV(C0, 32);

  // S epilogue: silu -> atomics (nt 0..3); sigmoid gates -> regs (nt 4,5)
  float gateR[16];
#pragma unroll
  for (int t = 0; t < 2; t++) {
#pragma unroll
    for (int r = 0; r < 4; r++) {
      int er = wv * 16 + quad * 4 + r + t * 64;
      int nid = idxL[er];
#pragma unroll
      for (int nt = 0; nt < 6; nt++) {
        float v = aS[t][nt][r];
        float sg = 1.f / (1.f + __expf(-v));
        if (nt < 4) atomicAdd(&s_n[nid * 64 + nt * 16 + ln], v * sg);
        else        gateR[t * 8 + (nt - 4) * 4 + r] = sg;
      }
    }
  }

  // ================= V phase =================
  f32x4 aV[2][3][2];
#pragma unroll
  for (int t = 0; t < 2; t++)
#pragma unroll
    for (int p = 0; p < 3; p++)
#pragma unroll
      for (int nt = 0; nt < 2; nt++) aV[t][p][nt] = (f32x4){0.f, 0.f, 0.f, 0.f};

  // region cross: kt 32..39 (rolled, 2 kt per iter); then sv (0..15), vs (16..31)
#pragma unroll 1
  for (int c = 0; c < 4; c++) {
    int kt = 32 + 2 * c;
    int r0 = (64 + (4 * (kt - 32) + quad) * 3) * FSTRD + ep;
    int r1 = r0 + 12 * FSTRD;
    u32 d0 = fTd[r0], d1 = fTd[r0 + FSTRD], d2 = fTd[r0 + 2 * FSTRD];
    u32 e0 = fTd[r1], e1 = fTd[r1 + FSTRD], e2 = fTd[r1 + 2 * FSTRD];
    LOAD_BV(C1, kt + 1);
    {
      float wl[3] = { lo_f(d0), lo_f(d1), lo_f(d2) };
      float wh[3] = { hi_f(d0), hi_f(d1), hi_f(d2) };
#pragma unroll
      for (int p = 0; p < 3; p++) {
        const int p1 = (p + 1) % 3, p2 = (p + 2) % 3;
        frag_u Al, Ah;
#pragma unroll
        for (int jp = 0; jp < 4; jp++) {
          int j0 = 6 * jp, j1 = 6 * jp + 3;
          Al.w[jp] = pk2(wl[p1]*v2l[j0+p2] - wl[p2]*v2l[j0+p1],
                         wl[p1]*v2l[j1+p2] - wl[p2]*v2l[j1+p1]);
          Ah.w[jp] = pk2(wh[p1]*v2h[j0+p2] - wh[p2]*v2h[j0+p1],
                         wh[p1]*v2h[j1+p2] - wh[p2]*v2h[j1+p1]);
        }
        MFMA_V(Al, Ah, C0, p);
      }
    }
    LOAD_BV(C0, (c < 3) ? (kt + 2) : 0);   // tail chains into sv (kt=0)
    {
      float wl[3] = { lo_f(e0), lo_f(e1), lo_f(e2) };
      float wh[3] = { hi_f(e0), hi_f(e1), hi_f(e2) };
#pragma unroll
      for (int p = 0; p < 3; p++) {
        const int p1 = (p + 1) % 3, p2 = (p + 2) % 3;
        frag_u Al, Ah;
#pragma unroll
        for (int jp = 0; jp < 4; jp++) {
          int j0 = 6 * jp, j1 = 6 * jp + 3;
          Al.w[jp] = pk2(wl[p1]*v2l[j0+p2] - wl[p2]*v2l[j0+p1],
                         wl[p1]*v2l[j1+p2] - wl[p2]*v2l[j1+p1]);
          Ah.w[jp] = pk2(wh[p1]*v2h[j0+p2] - wh[p2]*v2h[j0+p1],
                         wh[p1]*v2h[j1+p2] - wh[p2]*v2h[j1+p1]);
        }
        MFMA_V(Al, Ah, C1, p);
      }
    }
  }
  // region sv: kt 0..15
#pragma unroll 1
  for (int c = 0; c < 8; c++) {
    int kt = 2 * c;
    u32 dA = fTd[(4 * kt + quad) * FSTRD + ep];
    u32 dB = fTd[(4 * kt + 4 + quad) * FSTRD + ep];
    LOAD_BV(C1, kt + 1);
    {
      float slo = lo_f(dA), shi = hi_f(dA);
#pragma unroll
      for (int p = 0; p < 3; p++) {
        frag_u Al, Ah;
#pragma unroll
        for (int jp = 0; jp < 4; jp++) {
          Al.w[jp] = pk2(slo * v2l[(2*jp)*3 + p], slo * v2l[(2*jp+1)*3 + p]);
          Ah.w[jp] = pk2(shi * v2h[(2*jp)*3 + p], shi * v2h[(2*jp+1)*3 + p]);
        }
        MFMA_V(Al, Ah, C0, p);
      }
    }
    LOAD_BV(C0, kt + 2);   // c==7 chains into vs (kt=16)
    {
      float slo = lo_f(dB), shi = hi_f(dB);
#pragma unroll
      for (int p = 0; p < 3; p++) {
        frag_u Al, Ah;
#pragma unroll
        for (int jp = 0; jp < 4; jp++) {
          Al.w[jp] = pk2(slo * v2l[(2*jp)*3 + p], slo * v2l[(2*jp+1)*3 + p]);
          Ah.w[jp] = pk2(shi * v2h[(2*jp)*3 + p], shi * v2h[(2*jp+1)*3 + p]);
        }
        MFMA_V(Al, Ah, C1, p);
      }
    }
  }
  // region vs: kt 16..31
#pragma unroll 1
  for (int c = 0; c < 8; c++) {
    int kt = 16 + 2 * c;
    int r0 = (64 + (2 * (kt - 16) + qh) * 3) * FSTRD + ep;
    int r1 = r0 + 6 * FSTRD;
    u32 d0 = fTd[r0], d1 = fTd[r0 + FSTRD], d2 = fTd[r0 + 2 * FSTRD];
    u32 e0 = fTd[r1], e1 = fTd[r1 + FSTRD], e2 = fTd[r1 + 2 * FSTRD];
    LOAD_BV(C1, kt + 1);
    {
      float vl[3] = { lo_f(d0), lo_f(d1), lo_f(d2) };
      float vh[3] = { hi_f(d0), hi_f(d1), hi_f(d2) };
#pragma unroll
      for (int p = 0; p < 3; p++) {
        frag_u Al, Ah;
#pragma unroll
        for (int jp = 0; jp < 4; jp++) {
          Al.w[jp] = pk2(vl[p] * s2l[2*jp], vl[p] * s2l[2*jp+1]);
          Ah.w[jp] = pk2(vh[p] * s2h[2*jp], vh[p] * s2h[2*jp+1]);
        }
        MFMA_V(Al, Ah, C0, p);
      }
    }
    LOAD_BV(C0, (c < 7) ? (kt + 2) : 0);   // tail load never consumed (valid addr)
    {
      float vl[3] = { lo_f(e0), lo_f(e1), lo_f(e2) };
      float vh[3] = { hi_f(e0), hi_f(e1), hi_f(e2) };
#pragma unroll
      for (int p = 0; p < 3; p++) {
        frag_u Al, Ah;
#pragma unroll
        for (int jp = 0; jp < 4; jp++) {
          Al.w[jp] = pk2(vl[p] * s2l[2*jp], vl[p] * s2l[2*jp+1]);
          Ah.w[jp] = pk2(vh[p] * s2h[2*jp], vh[p] * s2h[2*jp+1]);
        }
        MFMA_V(Al, Ah, C1, p);
      }
    }
  }

  // V epilogue: gate + scatter
#pragma unroll
  for (int t = 0; t < 2; t++) {
#pragma unroll
    for (int r = 0; r < 4; r++) {
      int er = wv * 16 + quad * 4 + r + t * 64;
      int nid = idxL[er];
#pragma unroll
      for (int nt = 0; nt < 2; nt++) {
        int c = nt * 16 + ln;
        float g = gateR[t * 8 + nt * 4 + r];
#pragma unroll
        for (int p = 0; p < 3; p++)
          atomicAdd(&v_n[nid * 96 + c * 3 + p], aV[t][p][nt][r] * g);
      }
    }
  }
}

// ---- BN stats ------------------------------------------------------------
__global__ void stats_kernel(const float* __restrict__ s_n, const float* __restrict__ v_n,
                             float* __restrict__ stats) {
  int b = blockIdx.x, tid = threadIdx.x;
  int r0 = b * 50;
  int c = tid & 63, rg = tid >> 6;
  float s = 0.f, sq = 0.f;
  for (int r = r0 + rg; r < r0 + 50; r += 4) {
    float v = s_n[r * 64 + c];
    s += v; sq += v * v;
  }
  atomicAdd(&stats[c], s);
  atomicAdd(&stats[64 + c], sq);
  int c2 = tid & 31, rg2 = tid >> 5;
  float vn = 0.f;
  for (int r = r0 + rg2; r < r0 + 50; r += 8) {
    const float* vp = &v_n[r * 96 + c2 * 3];
    vn += vp[0] * vp[0] + vp[1] * vp[1] + vp[2] * vp[2];
  }
  atomicAdd(&stats[128 + c2], vn);
}

// ---- finalize ------------------------------------------------------------
__global__ void finalize_kernel(const float* __restrict__ s_n, const float* __restrict__ v_n,
                                const float* __restrict__ stats,
                                const float* __restrict__ x,
                                const float* __restrict__ bw_s, const float* __restrict__ bb_s,
                                const float* __restrict__ bw_v,
                                float* __restrict__ out) {
  int t = blockIdx.x * 256 + threadIdx.x;
  if (t >= NNODES * 160) return;
  int n = t / 160, j = t - n * 160;
  float xv = x[t];
  float r;
  if (j < 64) {
    float mu  = stats[j] * (1.f / NNODES);
    float var = stats[64 + j] * (1.f / NNODES) - mu * mu;
    var = fmaxf(var, 0.f);
    float v = s_n[n * 64 + j];
    r = (v - mu) * rsqrtf(var + 1e-5f) * bw_s[j] + bb_s[j];
  } else {
    int qq = j - 64;
    int c = qq / 3;
    float vn = stats[128 + c] * (1.f / (3.f * NNODES));
    float v = v_n[n * 96 + qq];
    r = v * rsqrtf(vn + 1e-5f) * bw_v[c];
  }
  out[t] = r + xv;
}

extern "C" void kernel_launch(void* const* d_in, const int* in_sizes, int n_in,
                              void* d_out, int out_size, void* d_ws, size_t ws_size,
                              hipStream_t stream) {
  const float* x      = (const float*)d_in[0];
  const float* ea     = (const float*)d_in[1];
  const float* W_ss   = (const float*)d_in[2];
  const float* W_vv_s = (const float*)d_in[3];
  const float* W_sv   = (const float*)d_in[4];
  const float* W_vs   = (const float*)d_in[5];
  const float* W_vv_v = (const float*)d_in[6];
  const float* bw_s   = (const float*)d_in[7];
  const float* bb_s   = (const float*)d_in[8];
  const float* bw_v   = (const float*)d_in[9];
  const int* eidx     = (const int*)d_in[10];
  float* out = (float*)d_out;

  u16* WSp     = (u16*)d_ws;              // 122880 u16
  u16* WVp     = WSp + 122880;            // 40960 u16
  float* s_n   = (float*)d_ws + 81920;    // 640000
  float* v_n   = s_n + 640000;            // 960000
  float* stats = v_n + 960000;            // 160

  prep_kernel<<<6251, 256, 0, stream>>>(W_ss, W_vv_s, W_sv, W_vs, W_vv_v,
                                        (u32*)WSp, (u32*)WVp, s_n);
  edge_kernel<<<NEDGES / EB, 256, 0, stream>>>(x, ea, eidx, WSp, WVp, s_n, v_n);
  stats_kernel<<<200, 256, 0, stream>>>(s_n, v_n, stats);
  finalize_kernel<<<(NNODES * 160 + 255) / 256, 256, 0, stream>>>(
      s_n, v_n, stats, x, bw_s, bb_s, bw_v, out);
}

// Round 10
// 421.216 us; speedup vs baseline: 1.3103x; 1.0640x over previous
//
#include <hip/hip_runtime.h>
#include <hip/hip_bf16.h>

// NodeProcessor via MFMA. R10: REMOVE the 25.6M-atomic scatter (the R3-R9
// invariant wall: 84 G RMW/s at the coherence point). Edge kernel writes
// bf16 messages to per-edge buffers (coalesced stores); CSR (count/scan/
// fill) + gather kernel do the segment-sum without atomics. Falls back to
// the atomic epilogue if ws_size < 58.7 MB.
// GEMM structure unchanged from R9 (128 edges/block, 2 row-tiles/lane,
// edge-paired LDS features, rolled region loops, 2-deep B register dbuf).

#define NNODES 10000
#define NEDGES 160000
#define EB 128
#define FSTRD 66                    // fTd row stride in dwords

typedef unsigned short u16;
typedef unsigned int u32;
typedef short short8 __attribute__((ext_vector_type(8)));
typedef float f32x4 __attribute__((ext_vector_type(4)));

__device__ __forceinline__ u16 f2b(float f) {  // RNE
  union { float f; u32 i; } v; v.f = f;
  u32 r = v.i + 0x7FFFu + ((v.i >> 16) & 1u);
  return (u16)(r >> 16);
}
__device__ __forceinline__ float lo_f(u32 d) {
  union { u32 i; float f; } v; v.i = d << 16; return v.f;
}
__device__ __forceinline__ float hi_f(u32 d) {
  union { u32 i; float f; } v; v.i = d & 0xFFFF0000u; return v.f;
}
__device__ __forceinline__ u32 pk2(float lo, float hi) {
  return __builtin_amdgcn_perm(__float_as_uint(hi), __float_as_uint(lo), 0x07060302u);
}
union frag_u { u32 w[4]; short8 s; };

#define INVF  0.02795084971874737f   // 1/sqrt(1280)
#define INV3  0.5773502691896258f    // 1/sqrt(3)
#define INV2  0.7071067811865476f    // 1/sqrt(2)

// ---- prep: pack weights into B-frag order + zero a region ----------------
__global__ void prep_kernel(const float* __restrict__ W_ss, const float* __restrict__ W_vv_s,
                            const float* __restrict__ W_sv, const float* __restrict__ W_vs,
                            const float* __restrict__ W_vv_v,
                            u32* __restrict__ WSd, u32* __restrict__ WVd,
                            float* __restrict__ zbase, int zcount) {
  int t = blockIdx.x * 256 + threadIdx.x;
  if (t < zcount) zbase[t] = 0.f;
  if (t < 61440) {            // W_S dwords
    int d = t;
    int nt = d / 10240, r = d - nt * 10240;
    int kt = r >> 8, l = (r & 255) >> 2, jp = r & 3;
    int n = nt * 16 + (l & 15);
    int k0 = kt * 32 + ((l >> 4) << 3) + jp * 2;
    float f0, f1;
    f0 = (k0     < 1024) ? W_ss[k0 * 96 + n] * INVF       : W_vv_s[(k0 - 1024) * 96 + n] * (INVF * INV3);
    f1 = (k0 + 1 < 1024) ? W_ss[(k0 + 1) * 96 + n] * INVF : W_vv_s[(k0 - 1023) * 96 + n] * (INVF * INV3);
    WSd[d] = (u32)f2b(f0) | ((u32)f2b(f1) << 16);
  } else if (t < 81920) {     // W_V dwords
    int d = t - 61440;
    int nt = d / 10240, r = d - nt * 10240;
    int kt = r >> 8, l = (r & 255) >> 2, jp = r & 3;
    int n = nt * 16 + (l & 15);
    int k0 = kt * 32 + ((l >> 4) << 3) + jp * 2;
    float f[2];
#pragma unroll
    for (int jj = 0; jj < 2; jj++) {
      int k = k0 + jj;
      if (k < 512)       f[jj] = W_sv[k * 32 + n] * INVF;
      else if (k < 1024) f[jj] = W_vs[(k - 512) * 32 + n] * INVF;
      else               f[jj] = W_vv_v[(k - 1024) * 32 + n] * (INVF * INV2);
    }
    WVd[d] = (u32)f2b(f[0]) | ((u32)f2b(f[1]) << 16);
  }
}

// ---- CSR build -----------------------------------------------------------
__global__ void count_kernel(const int* __restrict__ eidx, int* __restrict__ cnt) {
  int t = blockIdx.x * 256 + threadIdx.x;
  if (t < NEDGES) atomicAdd(&cnt[eidx[t]], 1);
}

__global__ void scan_kernel(const int* __restrict__ cnt, int* __restrict__ off,
                            int* __restrict__ cursor) {
  __shared__ int part[1024];
  int t = threadIdx.x;
  int local[10]; int s = 0;
  if (t < 1000) {
#pragma unroll
    for (int i = 0; i < 10; i++) { local[i] = cnt[t * 10 + i]; s += local[i]; }
  }
  part[t] = s; __syncthreads();
  for (int d = 1; d < 1024; d <<= 1) {
    int v = (t >= d) ? part[t - d] : 0; __syncthreads();
    part[t] += v; __syncthreads();
  }
  if (t < 1000) {
    int ex = (t == 0) ? 0 : part[t - 1];
#pragma unroll
    for (int i = 0; i < 10; i++) { off[t * 10 + i] = ex; cursor[t * 10 + i] = ex; ex += local[i]; }
  }
  if (t == 0) off[10000] = NEDGES;
}

__global__ void fill_kernel(const int* __restrict__ eidx, int* __restrict__ cursor,
                            int* __restrict__ elist) {
  int t = blockIdx.x * 256 + threadIdx.x;
  if (t < NEDGES) {
    int slot = atomicAdd(&cursor[eidx[t]], 1);
    elist[slot] = t;
  }
}

// ---- edge kernel ---------------------------------------------------------
__global__ __launch_bounds__(256, 2) void edge_kernel(
    const float* __restrict__ x, const float* __restrict__ ea,
    const int* __restrict__ eidx,
    const u16* __restrict__ WSp, const u16* __restrict__ WVp,
    float* __restrict__ s_n, float* __restrict__ v_n,
    u16* __restrict__ ms16, u16* __restrict__ mv16, int use_msg) {
  __shared__ int idxL[EB];
  __shared__ u32 fTd[200 * FSTRD];  // [j][ep]: lo=edge ep, hi=edge ep+64
  const int tid = threadIdx.x;
  const int eb = blockIdx.x * EB;

  if (tid < EB) idxL[tid] = eidx[eb + tid];
  __syncthreads();
#pragma unroll 1
  for (int t = tid; t < 64 * 200; t += 256) {
    int ep = t / 200, j = t - ep * 200;
    float vlo, vhi;
    if (j < 160) {
      vlo = x[(size_t)idxL[ep] * 160 + j];
      vhi = x[(size_t)idxL[ep + 64] * 160 + j];
    } else {
      vlo = ea[(size_t)(eb + ep) * 40 + (j - 160)];
      vhi = ea[(size_t)(eb + ep + 64) * 40 + (j - 160)];
    }
    fTd[j * FSTRD + ep] = (u32)f2b(vlo) | ((u32)f2b(vhi) << 16);
  }
  __syncthreads();

  const int wv = tid >> 6, lane = tid & 63;
  const int ln = lane & 15, quad = lane >> 4;
  const int ep = wv * 16 + ln;
  const int qh = quad >> 1, bb = (quad & 1) * 8;

  float s2l[8], s2h[8], v2l[24], v2h[24];
#pragma unroll
  for (int i = 0; i < 8; i++) {
    u32 d = fTd[(160 + bb + i) * FSTRD + ep];
    s2l[i] = lo_f(d); s2h[i] = hi_f(d);
  }
#pragma unroll
  for (int i = 0; i < 24; i++) {
    u32 d = fTd[(176 + i) * FSTRD + ep];
    v2l[i] = lo_f(d); v2h[i] = hi_f(d);
  }

  const u16* WS_l = WSp + (size_t)lane * 8;
  const u16* WV_l = WVp + (size_t)lane * 8;

#define LOAD_BS(B, ktv) { _Pragma("unroll") \
  for (int nt = 0; nt < 6; nt++) B[nt].s = *(const short8*)(WS_l + (size_t)(ktv) * 512 + nt * 20480); }
#define LOAD_BV(C, ktv) { _Pragma("unroll") \
  for (int nt = 0; nt < 2; nt++) C[nt].s = *(const short8*)(WV_l + (size_t)(ktv) * 512 + nt * 20480); }
#define MFMA_S(Al, Ah, B) { _Pragma("unroll") \
  for (int nt = 0; nt < 6; nt++) { \
    aS[0][nt] = __builtin_amdgcn_mfma_f32_16x16x32_bf16(Al.s, B[nt].s, aS[0][nt], 0, 0, 0); \
    aS[1][nt] = __builtin_amdgcn_mfma_f32_16x16x32_bf16(Ah.s, B[nt].s, aS[1][nt], 0, 0, 0); } }
#define MFMA_V(Al, Ah, C, p) { \
    aV[0][p][0] = __builtin_amdgcn_mfma_f32_16x16x32_bf16(Al.s, C[0].s, aV[0][p][0], 0, 0, 0); \
    aV[0][p][1] = __builtin_amdgcn_mfma_f32_16x16x32_bf16(Al.s, C[1].s, aV[0][p][1], 0, 0, 0); \
    aV[1][p][0] = __builtin_amdgcn_mfma_f32_16x16x32_bf16(Ah.s, C[0].s, aV[1][p][0], 0, 0, 0); \
    aV[1][p][1] = __builtin_amdgcn_mfma_f32_16x16x32_bf16(Ah.s, C[1].s, aV[1][p][1], 0, 0, 0); }

  // ================= S phase =================
  f32x4 aS[2][6];
#pragma unroll
  for (int t = 0; t < 2; t++)
#pragma unroll
    for (int i = 0; i < 6; i++) aS[t][i] = (f32x4){0.f, 0.f, 0.f, 0.f};

  frag_u B0[6], B1[6];
  LOAD_BS(B0, 0);

#pragma unroll 1
  for (int c = 0; c < 16; c++) {      // region ss: kt 0..31
    int kt = 2 * c;
    u32 dA = fTd[(2 * kt + qh) * FSTRD + ep];
    u32 dB = fTd[(2 * kt + 2 + qh) * FSTRD + ep];
    LOAD_BS(B1, kt + 1);
    {
      frag_u Al, Ah;
      float slo = lo_f(dA), shi = hi_f(dA);
#pragma unroll
      for (int jp = 0; jp < 4; jp++) {
        Al.w[jp] = pk2(slo * s2l[2 * jp], slo * s2l[2 * jp + 1]);
        Ah.w[jp] = pk2(shi * s2h[2 * jp], shi * s2h[2 * jp + 1]);
      }
      MFMA_S(Al, Ah, B0);
    }
    LOAD_BS(B0, kt + 2);
    {
      frag_u Al, Ah;
      float slo = lo_f(dB), shi = hi_f(dB);
#pragma unroll
      for (int jp = 0; jp < 4; jp++) {
        Al.w[jp] = pk2(slo * s2l[2 * jp], slo * s2l[2 * jp + 1]);
        Ah.w[jp] = pk2(shi * s2h[2 * jp], shi * s2h[2 * jp + 1]);
      }
      MFMA_S(Al, Ah, B1);
    }
  }
#pragma unroll 1
  for (int c = 0; c < 4; c++) {       // region dot3: kt 32..39
    int kt = 32 + 2 * c;
    int r0 = (64 + (4 * (kt - 32) + quad) * 3) * FSTRD + ep;
    int r1 = r0 + 12 * FSTRD;
    u32 d0 = fTd[r0], d1 = fTd[r0 + FSTRD], d2 = fTd[r0 + 2 * FSTRD];
    u32 e0 = fTd[r1], e1 = fTd[r1 + FSTRD], e2 = fTd[r1 + 2 * FSTRD];
    LOAD_BS(B1, kt + 1);
    {
      frag_u Al, Ah;
      float x0 = lo_f(d0), x1 = lo_f(d1), x2 = lo_f(d2);
      float y0 = hi_f(d0), y1 = hi_f(d1), y2 = hi_f(d2);
#pragma unroll
      for (int jp = 0; jp < 4; jp++) {
        int j0 = 6 * jp, j1 = 6 * jp + 3;
        Al.w[jp] = pk2(x0*v2l[j0] + x1*v2l[j0+1] + x2*v2l[j0+2],
                       x0*v2l[j1] + x1*v2l[j1+1] + x2*v2l[j1+2]);
        Ah.w[jp] = pk2(y0*v2h[j0] + y1*v2h[j0+1] + y2*v2h[j0+2],
                       y0*v2h[j1] + y1*v2h[j1+1] + y2*v2h[j1+2]);
      }
      MFMA_S(Al, Ah, B0);
    }
    LOAD_BS(B0, kt + 2);
    {
      frag_u Al, Ah;
      float x0 = lo_f(e0), x1 = lo_f(e1), x2 = lo_f(e2);
      float y0 = hi_f(e0), y1 = hi_f(e1), y2 = hi_f(e2);
#pragma unroll
      for (int jp = 0; jp < 4; jp++) {
        int j0 = 6 * jp, j1 = 6 * jp + 3;
        Al.w[jp] = pk2(x0*v2l[j0] + x1*v2l[j0+1] + x2*v2l[j0+2],
                       x0*v2l[j1] + x1*v2l[j1+1] + x2*v2l[j1+2]);
        Ah.w[jp] = pk2(y0*v2h[j0] + y1*v2h[j0+1] + y2*v2h[j0+2],
                       y0*v2h[j1] + y1*v2h[j1+1] + y2*v2h[j1+2]);
      }
      MFMA_S(Al, Ah, B1);
    }
  }

  frag_u C0[2], C1[2];
  LOAD_BV(C0, 32);

  // S epilogue
  float gateR[16];
#pragma unroll
  for (int t = 0; t < 2; t++) {
#pragma unroll
    for (int r = 0; r < 4; r++) {
      int er = wv * 16 + quad * 4 + r + t * 64;
      int nid = idxL[er];
#pragma unroll
      for (int nt = 0; nt < 6; nt++) {
        float v = aS[t][nt][r];
        float sg = 1.f / (1.f + __expf(-v));
        if (nt < 4) {
          if (use_msg) ms16[(size_t)(eb + er) * 64 + nt * 16 + ln] = f2b(v * sg);
          else         atomicAdd(&s_n[nid * 64 + nt * 16 + ln], v * sg);
        } else gateR[t * 8 + (nt - 4) * 4 + r] = sg;
      }
    }
  }

  // ================= V phase =================
  f32x4 aV[2][3][2];
#pragma unroll
  for (int t = 0; t < 2; t++)
#pragma unroll
    for (int p = 0; p < 3; p++)
#pragma unroll
      for (int nt = 0; nt < 2; nt++) aV[t][p][nt] = (f32x4){0.f, 0.f, 0.f, 0.f};

#pragma unroll 1
  for (int c = 0; c < 4; c++) {       // region cross: kt 32..39
    int kt = 32 + 2 * c;
    int r0 = (64 + (4 * (kt - 32) + quad) * 3) * FSTRD + ep;
    int r1 = r0 + 12 * FSTRD;
    u32 d0 = fTd[r0], d1 = fTd[r0 + FSTRD], d2 = fTd[r0 + 2 * FSTRD];
    u32 e0 = fTd[r1], e1 = fTd[r1 + FSTRD], e2 = fTd[r1 + 2 * FSTRD];
    LOAD_BV(C1, kt + 1);
    {
      float wl[3] = { lo_f(d0), lo_f(d1), lo_f(d2) };
      float wh[3] = { hi_f(d0), hi_f(d1), hi_f(d2) };
#pragma unroll
      for (int p = 0; p < 3; p++) {
        const int p1 = (p + 1) % 3, p2 = (p + 2) % 3;
        frag_u Al, Ah;
#pragma unroll
        for (int jp = 0; jp < 4; jp++) {
          int j0 = 6 * jp, j1 = 6 * jp + 3;
          Al.w[jp] = pk2(wl[p1]*v2l[j0+p2] - wl[p2]*v2l[j0+p1],
                         wl[p1]*v2l[j1+p2] - wl[p2]*v2l[j1+p1]);
          Ah.w[jp] = pk2(wh[p1]*v2h[j0+p2] - wh[p2]*v2h[j0+p1],
                         wh[p1]*v2h[j1+p2] - wh[p2]*v2h[j1+p1]);
        }
        MFMA_V(Al, Ah, C0, p);
      }
    }
    LOAD_BV(C0, (c < 3) ? (kt + 2) : 0);
    {
      float wl[3] = { lo_f(e0), lo_f(e1), lo_f(e2) };
      float wh[3] = { hi_f(e0), hi_f(e1), hi_f(e2) };
#pragma unroll
      for (int p = 0; p < 3; p++) {
        const int p1 = (p + 1) % 3, p2 = (p + 2) % 3;
        frag_u Al, Ah;
#pragma unroll
        for (int jp = 0; jp < 4; jp++) {
          int j0 = 6 * jp, j1 = 6 * jp + 3;
          Al.w[jp] = pk2(wl[p1]*v2l[j0+p2] - wl[p2]*v2l[j0+p1],
                         wl[p1]*v2l[j1+p2] - wl[p2]*v2l[j1+p1]);
          Ah.w[jp] = pk2(wh[p1]*v2h[j0+p2] - wh[p2]*v2h[j0+p1],
                         wh[p1]*v2h[j1+p2] - wh[p2]*v2h[j1+p1]);
        }
        MFMA_V(Al, Ah, C1, p);
      }
    }
  }
#pragma unroll 1
  for (int c = 0; c < 8; c++) {       // region sv: kt 0..15
    int kt = 2 * c;
    u32 dA = fTd[(4 * kt + quad) * FSTRD + ep];
    u32 dB = fTd[(4 * kt + 4 + quad) * FSTRD + ep];
    LOAD_BV(C1, kt + 1);
    {
      float slo = lo_f(dA), shi = hi_f(dA);
#pragma unroll
      for (int p = 0; p < 3; p++) {
        frag_u Al, Ah;
#pragma unroll
        for (int jp = 0; jp < 4; jp++) {
          Al.w[jp] = pk2(slo * v2l[(2*jp)*3 + p], slo * v2l[(2*jp+1)*3 + p]);
          Ah.w[jp] = pk2(shi * v2h[(2*jp)*3 + p], shi * v2h[(2*jp+1)*3 + p]);
        }
        MFMA_V(Al, Ah, C0, p);
      }
    }
    LOAD_BV(C0, kt + 2);
    {
      float slo = lo_f(dB), shi = hi_f(dB);
#pragma unroll
      for (int p = 0; p < 3; p++) {
        frag_u Al, Ah;
#pragma unroll
        for (int jp = 0; jp < 4; jp++) {
          Al.w[jp] = pk2(slo * v2l[(2*jp)*3 + p], slo * v2l[(2*jp+1)*3 + p]);
          Ah.w[jp] = pk2(shi * v2h[(2*jp)*3 + p], shi * v2h[(2*jp+1)*3 + p]);
        }
        MFMA_V(Al, Ah, C1, p);
      }
    }
  }
#pragma unroll 1
  for (int c = 0; c < 8; c++) {       // region vs: kt 16..31
    int kt = 16 + 2 * c;
    int r0 = (64 + (2 * (kt - 16) + qh) * 3) * FSTRD + ep;
    int r1 = r0 + 6 * FSTRD;
    u32 d0 = fTd[r0], d1 = fTd[r0 + FSTRD], d2 = fTd[r0 + 2 * FSTRD];
    u32 e0 = fTd[r1], e1 = fTd[r1 + FSTRD], e2 = fTd[r1 + 2 * FSTRD];
    LOAD_BV(C1, kt + 1);
    {
      float vl[3] = { lo_f(d0), lo_f(d1), lo_f(d2) };
      float vh[3] = { hi_f(d0), hi_f(d1), hi_f(d2) };
#pragma unroll
      for (int p = 0; p < 3; p++) {
        frag_u Al, Ah;
#pragma unroll
        for (int jp = 0; jp < 4; jp++) {
          Al.w[jp] = pk2(vl[p] * s2l[2*jp], vl[p] * s2l[2*jp+1]);
          Ah.w[jp] = pk2(vh[p] * s2h[2*jp], vh[p] * s2h[2*jp+1]);
        }
        MFMA_V(Al, Ah, C0, p);
      }
    }
    LOAD_BV(C0, (c < 7) ? (kt + 2) : 0);
    {
      float vl[3] = { lo_f(e0), lo_f(e1), lo_f(e2) };
      float vh[3] = { hi_f(e0), hi_f(e1), hi_f(e2) };
#pragma unroll
      for (int p = 0; p < 3; p++) {
        frag_u Al, Ah;
#pragma unroll
        for (int jp = 0; jp < 4; jp++) {
          Al.w[jp] = pk2(vl[p] * s2l[2*jp], vl[p] * s2l[2*jp+1]);
          Ah.w[jp] = pk2(vh[p] * s2h[2*jp], vh[p] * s2h[2*jp+1]);
        }
        MFMA_V(Al, Ah, C1, p);
      }
    }
  }

  // V epilogue: gate + store/scatter
#pragma unroll
  for (int t = 0; t < 2; t++) {
#pragma unroll
    for (int r = 0; r < 4; r++) {
      int er = wv * 16 + quad * 4 + r + t * 64;
      int nid = idxL[er];
#pragma unroll
      for (int nt = 0; nt < 2; nt++) {
        int c = nt * 16 + ln;
        float g = gateR[t * 8 + nt * 4 + r];
#pragma unroll
        for (int p = 0; p < 3; p++) {
          float val = aV[t][p][nt][r] * g;
          if (use_msg) mv16[(size_t)p * 5120000 + (size_t)(eb + er) * 32 + c] = f2b(val);
          else         atomicAdd(&v_n[nid * 96 + c * 3 + p], val);
        }
      }
    }
  }
}

// ---- gather: one wave per node, no atomics -------------------------------
__global__ __launch_bounds__(256) void gather_kernel(
    const int* __restrict__ off, const int* __restrict__ elist,
    const u32* __restrict__ msd, const u32* __restrict__ mvd,
    float* __restrict__ s_n, float* __restrict__ v_n) {
  int tid = threadIdx.x;
  int n = blockIdx.x * 4 + (tid >> 6);
  int lane = tid & 63;
  int beg = off[n], end = off[n + 1];
  float a0 = 0.f, a1 = 0.f, b0 = 0.f, b1 = 0.f, c0 = 0.f, c1 = 0.f;
  int pp = (lane < 48) ? 0 : 1, dd = lane & 15;
#pragma unroll 1
  for (int k = beg; k < end; k++) {
    int e = elist[k];
    if (lane < 32) { u32 w = msd[(size_t)e * 32 + lane]; a0 += lo_f(w); a1 += hi_f(w); }
    else           { u32 w = mvd[(size_t)pp * 2560000 + (size_t)e * 16 + dd]; b0 += lo_f(w); b1 += hi_f(w); }
    if (lane < 16) { u32 w = mvd[(size_t)2 * 2560000 + (size_t)e * 16 + lane]; c0 += lo_f(w); c1 += hi_f(w); }
  }
  if (lane < 32) {
    s_n[n * 64 + 2 * lane] = a0; s_n[n * 64 + 2 * lane + 1] = a1;
  } else {
    v_n[n * 96 + (2 * dd) * 3 + pp] = b0; v_n[n * 96 + (2 * dd + 1) * 3 + pp] = b1;
  }
  if (lane < 16) {
    v_n[n * 96 + (2 * lane) * 3 + 2] = c0; v_n[n * 96 + (2 * lane + 1) * 3 + 2] = c1;
  }
}

// ---- BN stats ------------------------------------------------------------
__global__ void stats_kernel(const float* __restrict__ s_n, const float* __restrict__ v_n,
                             float* __restrict__ stats) {
  int b = blockIdx.x, tid = threadIdx.x;
  int r0 = b * 50;
  int c = tid & 63, rg = tid >> 6;
  float s = 0.f, sq = 0.f;
  for (int r = r0 + rg; r < r0 + 50; r += 4) {
    float v = s_n[r * 64 + c];
    s += v; sq += v * v;
  }
  atomicAdd(&stats[c], s);
  atomicAdd(&stats[64 + c], sq);
  int c2 = tid & 31, rg2 = tid >> 5;
  float vn = 0.f;
  for (int r = r0 + rg2; r < r0 + 50; r += 8) {
    const float* vp = &v_n[r * 96 + c2 * 3];
    vn += vp[0] * vp[0] + vp[1] * vp[1] + vp[2] * vp[2];
  }
  atomicAdd(&stats[128 + c2], vn);
}

// ---- finalize ------------------------------------------------------------
__global__ void finalize_kernel(const float* __restrict__ s_n, const float* __restrict__ v_n,
                                const float* __restrict__ stats,
                                const float* __restrict__ x,
                                const float* __restrict__ bw_s, const float* __restrict__ bb_s,
                                const float* __restrict__ bw_v,
                                float* __restrict__ out) {
  int t = blockIdx.x * 256 + threadIdx.x;
  if (t >= NNODES * 160) return;
  int n = t / 160, j = t - n * 160;
  float xv = x[t];
  float r;
  if (j < 64) {
    float mu  = stats[j] * (1.f / NNODES);
    float var = stats[64 + j] * (1.f / NNODES) - mu * mu;
    var = fmaxf(var, 0.f);
    float v = s_n[n * 64 + j];
    r = (v - mu) * rsqrtf(var + 1e-5f) * bw_s[j] + bb_s[j];
  } else {
    int qq = j - 64;
    int c = qq / 3;
    float vn = stats[128 + c] * (1.f / (3.f * NNODES));
    float v = v_n[n * 96 + qq];
    r = v * rsqrtf(vn + 1e-5f) * bw_v[c];
  }
  out[t] = r + xv;
}

extern "C" void kernel_launch(void* const* d_in, const int* in_sizes, int n_in,
                              void* d_out, int out_size, void* d_ws, size_t ws_size,
                              hipStream_t stream) {
  const float* x      = (const float*)d_in[0];
  const float* ea     = (const float*)d_in[1];
  const float* W_ss   = (const float*)d_in[2];
  const float* W_vv_s = (const float*)d_in[3];
  const float* W_sv   = (const float*)d_in[4];
  const float* W_vs   = (const float*)d_in[5];
  const float* W_vv_v = (const float*)d_in[6];
  const float* bw_s   = (const float*)d_in[7];
  const float* bb_s   = (const float*)d_in[8];
  const float* bw_v   = (const float*)d_in[9];
  const int* eidx     = (const int*)d_in[10];
  float* out = (float*)d_out;

  float* ws    = (float*)d_ws;
  u16* WSp     = (u16*)d_ws;              // 122880 u16
  u16* WVp     = WSp + 122880;            // 40960 u16
  float* s_n   = ws + 81920;              // 640000
  float* v_n   = s_n + 640000;            // 960000
  float* stats = v_n + 960000;            // 160  (at 1681920)
  int* cnt     = (int*)(ws + 1682080);    // 10000
  int* off     = (int*)(ws + 1692080);    // 10001 (pad to 10004)
  int* cursor  = (int*)(ws + 1702084);    // 10000
  int* elist   = (int*)(ws + 1712084);    // 160000
  u32* msd     = (u32*)(ws + 1872084);    // 5,120,000 dwords (msg_s bf16 pairs)
  u32* mvd     = msd + 5120000;           // 7,680,000 dwords (msg_v, 3 p-planes)
  // total = 14,672,084 floats = 58,688,336 bytes

  int use_msg = (ws_size >= 58688336ULL) ? 1 : 0;

  if (use_msg)
    prep_kernel<<<6251, 256, 0, stream>>>(W_ss, W_vv_s, W_sv, W_vs, W_vv_v,
                                          (u32*)WSp, (u32*)WVp, stats, 10160);
  else
    prep_kernel<<<6251, 256, 0, stream>>>(W_ss, W_vv_s, W_sv, W_vs, W_vv_v,
                                          (u32*)WSp, (u32*)WVp, s_n, 1600160);
  if (use_msg) {
    count_kernel<<<625, 256, 0, stream>>>(eidx, cnt);
    scan_kernel<<<1, 1024, 0, stream>>>(cnt, off, cursor);
    fill_kernel<<<625, 256, 0, stream>>>(eidx, cursor, elist);
  }
  edge_kernel<<<NEDGES / EB, 256, 0, stream>>>(x, ea, eidx, WSp, WVp, s_n, v_n,
                                               (u16*)msd, (u16*)mvd, use_msg);
  if (use_msg)
    gather_kernel<<<2500, 256, 0, stream>>>(off, elist, msd, mvd, s_n, v_n);
  stats_kernel<<<200, 256, 0, stream>>>(s_n, v_n, stats);
  finalize_kernel<<<(NNODES * 160 + 255) / 256, 256, 0, stream>>>(
      s_n, v_n, stats, x, bw_s, bb_s, bw_v, out);
}

// Round 12
// 390.861 us; speedup vs baseline: 1.4120x; 1.0777x over previous
//
#include <hip/hip_runtime.h>
#include <hip/hip_bf16.h>

// NodeProcessor via MFMA. R12 = R11 minus the prep/count fusion race (count
// must be a separate launch AFTER prep zeroes cnt — stream order is the only
// ordering guarantee; R11 fused them and poisoned elist -> wild reads).
// (1) fTd stride 65 dwords (52 KB -> aim 3 blocks/CU); (2) unified bf16
// msg[e][160] + shfl-broadcast CSR gather; GEMM structure from R9/R10.

#define NNODES 10000
#define NEDGES 160000
#define EB 128
#define FSTRD 65                    // fTd row stride in dwords (==1 mod 32)

typedef unsigned short u16;
typedef unsigned int u32;
typedef short short8 __attribute__((ext_vector_type(8)));
typedef float f32x4 __attribute__((ext_vector_type(4)));

__device__ __forceinline__ u16 f2b(float f) {  // RNE
  union { float f; u32 i; } v; v.f = f;
  u32 r = v.i + 0x7FFFu + ((v.i >> 16) & 1u);
  return (u16)(r >> 16);
}
__device__ __forceinline__ float lo_f(u32 d) {
  union { u32 i; float f; } v; v.i = d << 16; return v.f;
}
__device__ __forceinline__ float hi_f(u32 d) {
  union { u32 i; float f; } v; v.i = d & 0xFFFF0000u; return v.f;
}
__device__ __forceinline__ u32 pk2(float lo, float hi) {
  return __builtin_amdgcn_perm(__float_as_uint(hi), __float_as_uint(lo), 0x07060302u);
}
union frag_u { u32 w[4]; short8 s; };

#define INVF  0.02795084971874737f   // 1/sqrt(1280)
#define INV3  0.5773502691896258f    // 1/sqrt(3)
#define INV2  0.7071067811865476f    // 1/sqrt(2)

// ---- prep: pack weights + zero accum/cnt region --------------------------
__global__ void prep_kernel(const float* __restrict__ W_ss, const float* __restrict__ W_vv_s,
                            const float* __restrict__ W_sv, const float* __restrict__ W_vs,
                            const float* __restrict__ W_vv_v,
                            u32* __restrict__ WSd, u32* __restrict__ WVd,
                            float* __restrict__ zbase, int zcount) {
  int t = blockIdx.x * 256 + threadIdx.x;
  if (t < zcount) zbase[t] = 0.f;
  if (t < 61440) {            // W_S dwords
    int d = t;
    int nt = d / 10240, r = d - nt * 10240;
    int kt = r >> 8, l = (r & 255) >> 2, jp = r & 3;
    int n = nt * 16 + (l & 15);
    int k0 = kt * 32 + ((l >> 4) << 3) + jp * 2;
    float f0, f1;
    f0 = (k0     < 1024) ? W_ss[k0 * 96 + n] * INVF       : W_vv_s[(k0 - 1024) * 96 + n] * (INVF * INV3);
    f1 = (k0 + 1 < 1024) ? W_ss[(k0 + 1) * 96 + n] * INVF : W_vv_s[(k0 - 1023) * 96 + n] * (INVF * INV3);
    WSd[d] = (u32)f2b(f0) | ((u32)f2b(f1) << 16);
  } else if (t < 81920) {     // W_V dwords
    int d = t - 61440;
    int nt = d / 10240, r = d - nt * 10240;
    int kt = r >> 8, l = (r & 255) >> 2, jp = r & 3;
    int n = nt * 16 + (l & 15);
    int k0 = kt * 32 + ((l >> 4) << 3) + jp * 2;
    float f[2];
#pragma unroll
    for (int jj = 0; jj < 2; jj++) {
      int k = k0 + jj;
      if (k < 512)       f[jj] = W_sv[k * 32 + n] * INVF;
      else if (k < 1024) f[jj] = W_vs[(k - 512) * 32 + n] * INVF;
      else               f[jj] = W_vv_v[(k - 1024) * 32 + n] * (INVF * INV2);
    }
    WVd[d] = (u32)f2b(f[0]) | ((u32)f2b(f[1]) << 16);
  }
}

// ---- CSR build (count AFTER prep zeroes cnt; separate launches!) ---------
__global__ void count_kernel(const int* __restrict__ eidx, int* __restrict__ cnt) {
  int t = blockIdx.x * 256 + threadIdx.x;
  if (t < NEDGES) atomicAdd(&cnt[eidx[t]], 1);
}

__global__ void scan_kernel(const int* __restrict__ cnt, int* __restrict__ off,
                            int* __restrict__ cursor) {
  __shared__ int part[1024];
  int t = threadIdx.x;
  int local[10]; int s = 0;
  if (t < 1000) {
#pragma unroll
    for (int i = 0; i < 10; i++) { local[i] = cnt[t * 10 + i]; s += local[i]; }
  }
  part[t] = s; __syncthreads();
  for (int d = 1; d < 1024; d <<= 1) {
    int v = (t >= d) ? part[t - d] : 0; __syncthreads();
    part[t] += v; __syncthreads();
  }
  if (t < 1000) {
    int ex = (t == 0) ? 0 : part[t - 1];
#pragma unroll
    for (int i = 0; i < 10; i++) { off[t * 10 + i] = ex; cursor[t * 10 + i] = ex; ex += local[i]; }
  }
  if (t == 0) off[10000] = NEDGES;
}

__global__ void fill_kernel(const int* __restrict__ eidx, int* __restrict__ cursor,
                            int* __restrict__ elist) {
  int t = blockIdx.x * 256 + threadIdx.x;
  if (t < NEDGES) {
    int slot = atomicAdd(&cursor[eidx[t]], 1);
    elist[slot] = t;
  }
}

// ---- edge kernel ---------------------------------------------------------
__global__ __launch_bounds__(256, 2) void edge_kernel(
    const float* __restrict__ x, const float* __restrict__ ea,
    const int* __restrict__ eidx,
    const u16* __restrict__ WSp, const u16* __restrict__ WVp,
    float* __restrict__ s_n, float* __restrict__ v_n,
    u16* __restrict__ msg16, int use_msg) {
  __shared__ int idxL[EB];
  __shared__ u32 fTd[200 * FSTRD];  // [j][ep]: lo=edge ep, hi=edge ep+64
  const int tid = threadIdx.x;
  const int eb = blockIdx.x * EB;

  if (tid < EB) idxL[tid] = eidx[eb + tid];
  __syncthreads();
#pragma unroll 1
  for (int t = tid; t < 64 * 200; t += 256) {
    int ep = t / 200, j = t - ep * 200;
    float vlo, vhi;
    if (j < 160) {
      vlo = x[(size_t)idxL[ep] * 160 + j];
      vhi = x[(size_t)idxL[ep + 64] * 160 + j];
    } else {
      vlo = ea[(size_t)(eb + ep) * 40 + (j - 160)];
      vhi = ea[(size_t)(eb + ep + 64) * 40 + (j - 160)];
    }
    fTd[j * FSTRD + ep] = (u32)f2b(vlo) | ((u32)f2b(vhi) << 16);
  }
  __syncthreads();

  const int wv = tid >> 6, lane = tid & 63;
  const int ln = lane & 15, quad = lane >> 4;
  const int ep = wv * 16 + ln;
  const int qh = quad >> 1, bb = (quad & 1) * 8;

  float s2l[8], s2h[8], v2l[24], v2h[24];
#pragma unroll
  for (int i = 0; i < 8; i++) {
    u32 d = fTd[(160 + bb + i) * FSTRD + ep];
    s2l[i] = lo_f(d); s2h[i] = hi_f(d);
  }
#pragma unroll
  for (int i = 0; i < 24; i++) {
    u32 d = fTd[(176 + i) * FSTRD + ep];
    v2l[i] = lo_f(d); v2h[i] = hi_f(d);
  }

  const u16* WS_l = WSp + (size_t)lane * 8;
  const u16* WV_l = WVp + (size_t)lane * 8;

#define LOAD_BS(B, ktv) { _Pragma("unroll") \
  for (int nt = 0; nt < 6; nt++) B[nt].s = *(const short8*)(WS_l + (size_t)(ktv) * 512 + nt * 20480); }
#define LOAD_BV(C, ktv) { _Pragma("unroll") \
  for (int nt = 0; nt < 2; nt++) C[nt].s = *(const short8*)(WV_l + (size_t)(ktv) * 512 + nt * 20480); }
#define MFMA_S(Al, Ah, B) { _Pragma("unroll") \
  for (int nt = 0; nt < 6; nt++) { \
    aS[0][nt] = __builtin_amdgcn_mfma_f32_16x16x32_bf16(Al.s, B[nt].s, aS[0][nt], 0, 0, 0); \
    aS[1][nt] = __builtin_amdgcn_mfma_f32_16x16x32_bf16(Ah.s, B[nt].s, aS[1][nt], 0, 0, 0); } }
#define MFMA_V(Al, Ah, C, p) { \
    aV[0][p][0] = __builtin_amdgcn_mfma_f32_16x16x32_bf16(Al.s, C[0].s, aV[0][p][0], 0, 0, 0); \
    aV[0][p][1] = __builtin_amdgcn_mfma_f32_16x16x32_bf16(Al.s, C[1].s, aV[0][p][1], 0, 0, 0); \
    aV[1][p][0] = __builtin_amdgcn_mfma_f32_16x16x32_bf16(Ah.s, C[0].s, aV[1][p][0], 0, 0, 0); \
    aV[1][p][1] = __builtin_amdgcn_mfma_f32_16x16x32_bf16(Ah.s, C[1].s, aV[1][p][1], 0, 0, 0); }

  // ================= S phase =================
  f32x4 aS[2][6];
#pragma unroll
  for (int t = 0; t < 2; t++)
#pragma unroll
    for (int i = 0; i < 6; i++) aS[t][i] = (f32x4){0.f, 0.f, 0.f, 0.f};

  frag_u B0[6], B1[6];
  LOAD_BS(B0, 0);

#pragma unroll 1
  for (int c = 0; c < 16; c++) {      // region ss: kt 0..31
    int kt = 2 * c;
    u32 dA = fTd[(2 * kt + qh) * FSTRD + ep];
    u32 dB = fTd[(2 * kt + 2 + qh) * FSTRD + ep];
    LOAD_BS(B1, kt + 1);
    {
      frag_u Al, Ah;
      float slo = lo_f(dA), shi = hi_f(dA);
#pragma unroll
      for (int jp = 0; jp < 4; jp++) {
        Al.w[jp] = pk2(slo * s2l[2 * jp], slo * s2l[2 * jp + 1]);
        Ah.w[jp] = pk2(shi * s2h[2 * jp], shi * s2h[2 * jp + 1]);
      }
      MFMA_S(Al, Ah, B0);
    }
    LOAD_BS(B0, kt + 2);
    {
      frag_u Al, Ah;
      float slo = lo_f(dB), shi = hi_f(dB);
#pragma unroll
      for (int jp = 0; jp < 4; jp++) {
        Al.w[jp] = pk2(slo * s2l[2 * jp], slo * s2l[2 * jp + 1]);
        Ah.w[jp] = pk2(shi * s2h[2 * jp], shi * s2h[2 * jp + 1]);
      }
      MFMA_S(Al, Ah, B1);
    }
  }
#pragma unroll 1
  for (int c = 0; c < 4; c++) {       // region dot3: kt 32..39
    int kt = 32 + 2 * c;
    int r0 = (64 + (4 * (kt - 32) + quad) * 3) * FSTRD + ep;
    int r1 = r0 + 12 * FSTRD;
    u32 d0 = fTd[r0], d1 = fTd[r0 + FSTRD], d2 = fTd[r0 + 2 * FSTRD];
    u32 e0 = fTd[r1], e1 = fTd[r1 + FSTRD], e2 = fTd[r1 + 2 * FSTRD];
    LOAD_BS(B1, kt + 1);
    {
      frag_u Al, Ah;
      float x0 = lo_f(d0), x1 = lo_f(d1), x2 = lo_f(d2);
      float y0 = hi_f(d0), y1 = hi_f(d1), y2 = hi_f(d2);
#pragma unroll
      for (int jp = 0; jp < 4; jp++) {
        int j0 = 6 * jp, j1 = 6 * jp + 3;
        Al.w[jp] = pk2(x0*v2l[j0] + x1*v2l[j0+1] + x2*v2l[j0+2],
                       x0*v2l[j1] + x1*v2l[j1+1] + x2*v2l[j1+2]);
        Ah.w[jp] = pk2(y0*v2h[j0] + y1*v2h[j0+1] + y2*v2h[j0+2],
                       y0*v2h[j1] + y1*v2h[j1+1] + y2*v2h[j1+2]);
      }
      MFMA_S(Al, Ah, B0);
    }
    LOAD_BS(B0, kt + 2);
    {
      frag_u Al, Ah;
      float x0 = lo_f(e0), x1 = lo_f(e1), x2 = lo_f(e2);
      float y0 = hi_f(e0), y1 = hi_f(e1), y2 = hi_f(e2);
#pragma unroll
      for (int jp = 0; jp < 4; jp++) {
        int j0 = 6 * jp, j1 = 6 * jp + 3;
        Al.w[jp] = pk2(x0*v2l[j0] + x1*v2l[j0+1] + x2*v2l[j0+2],
                       x0*v2l[j1] + x1*v2l[j1+1] + x2*v2l[j1+2]);
        Ah.w[jp] = pk2(y0*v2h[j0] + y1*v2h[j0+1] + y2*v2h[j0+2],
                       y0*v2h[j1] + y1*v2h[j1+1] + y2*v2h[j1+2]);
      }
      MFMA_S(Al, Ah, B1);
    }
  }

  frag_u C0[2], C1[2];
  LOAD_BV(C0, 32);

  // S epilogue: silu -> msg store (or atomic fallback); gates -> regs
  float gateR[16];
#pragma unroll
  for (int t = 0; t < 2; t++) {
#pragma unroll
    for (int r = 0; r < 4; r++) {
      int er = wv * 16 + quad * 4 + r + t * 64;
      int nid = idxL[er];
#pragma unroll
      for (int nt = 0; nt < 6; nt++) {
        float v = aS[t][nt][r];
        float sg = 1.f / (1.f + __expf(-v));
        if (nt < 4) {
          if (use_msg) msg16[(size_t)(eb + er) * 160 + nt * 16 + ln] = f2b(v * sg);
          else         atomicAdd(&s_n[nid * 64 + nt * 16 + ln], v * sg);
        } else gateR[t * 8 + (nt - 4) * 4 + r] = sg;
      }
    }
  }

  // ================= V phase =================
  f32x4 aV[2][3][2];
#pragma unroll
  for (int t = 0; t < 2; t++)
#pragma unroll
    for (int p = 0; p < 3; p++)
#pragma unroll
      for (int nt = 0; nt < 2; nt++) aV[t][p][nt] = (f32x4){0.f, 0.f, 0.f, 0.f};

#pragma unroll 1
  for (int c = 0; c < 4; c++) {       // region cross: kt 32..39
    int kt = 32 + 2 * c;
    int r0 = (64 + (4 * (kt - 32) + quad) * 3) * FSTRD + ep;
    int r1 = r0 + 12 * FSTRD;
    u32 d0 = fTd[r0], d1 = fTd[r0 + FSTRD], d2 = fTd[r0 + 2 * FSTRD];
    u32 e0 = fTd[r1], e1 = fTd[r1 + FSTRD], e2 = fTd[r1 + 2 * FSTRD];
    LOAD_BV(C1, kt + 1);
    {
      float wl[3] = { lo_f(d0), lo_f(d1), lo_f(d2) };
      float wh[3] = { hi_f(d0), hi_f(d1), hi_f(d2) };
#pragma unroll
      for (int p = 0; p < 3; p++) {
        const int p1 = (p + 1) % 3, p2 = (p + 2) % 3;
        frag_u Al, Ah;
#pragma unroll
        for (int jp = 0; jp < 4; jp++) {
          int j0 = 6 * jp, j1 = 6 * jp + 3;
          Al.w[jp] = pk2(wl[p1]*v2l[j0+p2] - wl[p2]*v2l[j0+p1],
                         wl[p1]*v2l[j1+p2] - wl[p2]*v2l[j1+p1]);
          Ah.w[jp] = pk2(wh[p1]*v2h[j0+p2] - wh[p2]*v2h[j0+p1],
                         wh[p1]*v2h[j1+p2] - wh[p2]*v2h[j1+p1]);
        }
        MFMA_V(Al, Ah, C0, p);
      }
    }
    LOAD_BV(C0, (c < 3) ? (kt + 2) : 0);
    {
      float wl[3] = { lo_f(e0), lo_f(e1), lo_f(e2) };
      float wh[3] = { hi_f(e0), hi_f(e1), hi_f(e2) };
#pragma unroll
      for (int p = 0; p < 3; p++) {
        const int p1 = (p + 1) % 3, p2 = (p + 2) % 3;
        frag_u Al, Ah;
#pragma unroll
        for (int jp = 0; jp < 4; jp++) {
          int j0 = 6 * jp, j1 = 6 * jp + 3;
          Al.w[jp] = pk2(wl[p1]*v2l[j0+p2] - wl[p2]*v2l[j0+p1],
                         wl[p1]*v2l[j1+p2] - wl[p2]*v2l[j1+p1]);
          Ah.w[jp] = pk2(wh[p1]*v2h[j0+p2] - wh[p2]*v2h[j0+p1],
                         wh[p1]*v2h[j1+p2] - wh[p2]*v2h[j1+p1]);
        }
        MFMA_V(Al, Ah, C1, p);
      }
    }
  }
#pragma unroll 1
  for (int c = 0; c < 8; c++) {       // region sv: kt 0..15
    int kt = 2 * c;
    u32 dA = fTd[(4 * kt + quad) * FSTRD + ep];
    u32 dB = fTd[(4 * kt + 4 + quad) * FSTRD + ep];
    LOAD_BV(C1, kt + 1);
    {
      float slo = lo_f(dA), shi = hi_f(dA);
#pragma unroll
      for (int p = 0; p < 3; p++) {
        frag_u Al, Ah;
#pragma unroll
        for (int jp = 0; jp < 4; jp++) {
          Al.w[jp] = pk2(slo * v2l[(2*jp)*3 + p], slo * v2l[(2*jp+1)*3 + p]);
          Ah.w[jp] = pk2(shi * v2h[(2*jp)*3 + p], shi * v2h[(2*jp+1)*3 + p]);
        }
        MFMA_V(Al, Ah, C0, p);
      }
    }
    LOAD_BV(C0, kt + 2);
    {
      float slo = lo_f(dB), shi = hi_f(dB);
#pragma unroll
      for (int p = 0; p < 3; p++) {
        frag_u Al, Ah;
#pragma unroll
        for (int jp = 0; jp < 4; jp++) {
          Al.w[jp] = pk2(slo * v2l[(2*jp)*3 + p], slo * v2l[(2*jp+1)*3 + p]);
          Ah.w[jp] = pk2(shi * v2h[(2*jp)*3 + p], shi * v2h[(2*jp+1)*3 + p]);
        }
        MFMA_V(Al, Ah, C1, p);
      }
    }
  }
#pragma unroll 1
  for (int c = 0; c < 8; c++) {       // region vs: kt 16..31
    int kt = 16 + 2 * c;
    int r0 = (64 + (2 * (kt - 16) + qh) * 3) * FSTRD + ep;
    int r1 = r0 + 6 * FSTRD;
    u32 d0 = fTd[r0], d1 = fTd[r0 + FSTRD], d2 = fTd[r0 + 2 * FSTRD];
    u32 e0 = fTd[r1], e1 = fTd[r1 + FSTRD], e2 = fTd[r1 + 2 * FSTRD];
    LOAD_BV(C1, kt + 1);
    {
      float vl[3] = { lo_f(d0), lo_f(d1), lo_f(d2) };
      float vh[3] = { hi_f(d0), hi_f(d1), hi_f(d2) };
#pragma unroll
      for (int p = 0; p < 3; p++) {
        frag_u Al, Ah;
#pragma unroll
        for (int jp = 0; jp < 4; jp++) {
          Al.w[jp] = pk2(vl[p] * s2l[2*jp], vl[p] * s2l[2*jp+1]);
          Ah.w[jp] = pk2(vh[p] * s2h[2*jp], vh[p] * s2h[2*jp+1]);
        }
        MFMA_V(Al, Ah, C0, p);
      }
    }
    LOAD_BV(C0, (c < 7) ? (kt + 2) : 0);
    {
      float vl[3] = { lo_f(e0), lo_f(e1), lo_f(e2) };
      float vh[3] = { hi_f(e0), hi_f(e1), hi_f(e2) };
#pragma unroll
      for (int p = 0; p < 3; p++) {
        frag_u Al, Ah;
#pragma unroll
        for (int jp = 0; jp < 4; jp++) {
          Al.w[jp] = pk2(vl[p] * s2l[2*jp], vl[p] * s2l[2*jp+1]);
          Ah.w[jp] = pk2(vh[p] * s2h[2*jp], vh[p] * s2h[2*jp+1]);
        }
        MFMA_V(Al, Ah, C1, p);
      }
    }
  }

  // V epilogue: gate + msg store (ch = 64 + c*3 + p, matches v_n order)
#pragma unroll
  for (int t = 0; t < 2; t++) {
#pragma unroll
    for (int r = 0; r < 4; r++) {
      int er = wv * 16 + quad * 4 + r + t * 64;
      int nid = idxL[er];
#pragma unroll
      for (int nt = 0; nt < 2; nt++) {
        int c = nt * 16 + ln;
        float g = gateR[t * 8 + nt * 4 + r];
#pragma unroll
        for (int p = 0; p < 3; p++) {
          float val = aV[t][p][nt][r] * g;
          if (use_msg) msg16[(size_t)(eb + er) * 160 + 64 + c * 3 + p] = f2b(val);
          else         atomicAdd(&v_n[nid * 96 + c * 3 + p], val);
        }
      }
    }
  }
}

// ---- gather: one wave per node, shfl-broadcast edge ids, no atomics ------
__global__ __launch_bounds__(256) void gather_kernel(
    const int* __restrict__ off, const int* __restrict__ elist,
    const u32* __restrict__ msg, float* __restrict__ s_n, float* __restrict__ v_n) {
  int tid = threadIdx.x;
  int n = blockIdx.x * 4 + (tid >> 6);
  int lane = tid & 63;
  int beg = off[n], end = off[n + 1];
  float a0 = 0.f, a1 = 0.f, b0 = 0.f, b1 = 0.f;
#pragma unroll 1
  for (int k0 = beg; k0 < end; k0 += 64) {
    int m = end - k0; if (m > 64) m = 64;
    int myE = (lane < m) ? elist[k0 + lane] : 0;
#pragma unroll 2
    for (int k = 0; k < m; k++) {
      int e = __shfl(myE, k);
      u32 w0 = msg[(size_t)e * 80 + lane];
      a0 += lo_f(w0); a1 += hi_f(w0);
      if (lane < 16) {
        u32 w1 = msg[(size_t)e * 80 + 64 + lane];
        b0 += lo_f(w1); b1 += hi_f(w1);
      }
    }
  }
  int ch = 2 * lane;
  if (ch < 64) {
    s_n[n * 64 + ch] = a0; s_n[n * 64 + ch + 1] = a1;
  } else {
    int q = ch - 64;
    v_n[n * 96 + q] = a0; v_n[n * 96 + q + 1] = a1;
  }
  if (lane < 16) {
    int q = 64 + 2 * lane;
    v_n[n * 96 + q] = b0; v_n[n * 96 + q + 1] = b1;
  }
}

// ---- BN stats ------------------------------------------------------------
__global__ void stats_kernel(const float* __restrict__ s_n, const float* __restrict__ v_n,
                             float* __restrict__ stats) {
  int b = blockIdx.x, tid = threadIdx.x;
  int r0 = b * 50;
  int c = tid & 63, rg = tid >> 6;
  float s = 0.f, sq = 0.f;
  for (int r = r0 + rg; r < r0 + 50; r += 4) {
    float v = s_n[r * 64 + c];
    s += v; sq += v * v;
  }
  atomicAdd(&stats[c], s);
  atomicAdd(&stats[64 + c], sq);
  int c2 = tid & 31, rg2 = tid >> 5;
  float vn = 0.f;
  for (int r = r0 + rg2; r < r0 + 50; r += 8) {
    const float* vp = &v_n[r * 96 + c2 * 3];
    vn += vp[0] * vp[0] + vp[1] * vp[1] + vp[2] * vp[2];
  }
  atomicAdd(&stats[128 + c2], vn);
}

// ---- finalize ------------------------------------------------------------
__global__ void finalize_kernel(const float* __restrict__ s_n, const float* __restrict__ v_n,
                                const float* __restrict__ stats,
                                const float* __restrict__ x,
                                const float* __restrict__ bw_s, const float* __restrict__ bb_s,
                                const float* __restrict__ bw_v,
                                float* __restrict__ out) {
  int t = blockIdx.x * 256 + threadIdx.x;
  if (t >= NNODES * 160) return;
  int n = t / 160, j = t - n * 160;
  float xv = x[t];
  float r;
  if (j < 64) {
    float mu  = stats[j] * (1.f / NNODES);
    float var = stats[64 + j] * (1.f / NNODES) - mu * mu;
    var = fmaxf(var, 0.f);
    float v = s_n[n * 64 + j];
    r = (v - mu) * rsqrtf(var + 1e-5f) * bw_s[j] + bb_s[j];
  } else {
    int qq = j - 64;
    int c = qq / 3;
    float vn = stats[128 + c] * (1.f / (3.f * NNODES));
    float v = v_n[n * 96 + qq];
    r = v * rsqrtf(vn + 1e-5f) * bw_v[c];
  }
  out[t] = r + xv;
}

extern "C" void kernel_launch(void* const* d_in, const int* in_sizes, int n_in,
                              void* d_out, int out_size, void* d_ws, size_t ws_size,
                              hipStream_t stream) {
  const float* x      = (const float*)d_in[0];
  const float* ea     = (const float*)d_in[1];
  const float* W_ss   = (const float*)d_in[2];
  const float* W_vv_s = (const float*)d_in[3];
  const float* W_sv   = (const float*)d_in[4];
  const float* W_vs   = (const float*)d_in[5];
  const float* W_vv_v = (const float*)d_in[6];
  const float* bw_s   = (const float*)d_in[7];
  const float* bb_s   = (const float*)d_in[8];
  const float* bw_v   = (const float*)d_in[9];
  const int* eidx     = (const int*)d_in[10];
  float* out = (float*)d_out;

  float* ws    = (float*)d_ws;
  u16* WSp     = (u16*)d_ws;              // 122880 u16
  u16* WVp     = WSp + 122880;            // 40960 u16
  float* s_n   = ws + 81920;              // 640000
  float* v_n   = s_n + 640000;            // 960000
  float* stats = v_n + 960000;            // 160  (at 1681920)
  int* cnt     = (int*)(ws + 1682080);    // 10000 (contiguous after stats)
  int* off     = (int*)(ws + 1692080);    // 10001 (pad to 10004)
  int* cursor  = (int*)(ws + 1702084);    // 10000
  int* elist   = (int*)(ws + 1712084);    // 160000
  u32* msg     = (u32*)(ws + 1872084);    // 12,800,000 dwords = msg[e][160] bf16
  // total = 14,672,084 floats = 58,688,336 bytes

  int use_msg = (ws_size >= 58688336ULL) ? 1 : 0;

  if (use_msg) {
    prep_kernel<<<6251, 256, 0, stream>>>(W_ss, W_vv_s, W_sv, W_vs, W_vv_v,
                                          (u32*)WSp, (u32*)WVp, stats, 10160);
    count_kernel<<<625, 256, 0, stream>>>(eidx, cnt);   // AFTER prep zeroes cnt
    scan_kernel<<<1, 1024, 0, stream>>>(cnt, off, cursor);
    fill_kernel<<<625, 256, 0, stream>>>(eidx, cursor, elist);
  } else {
    prep_kernel<<<6251, 256, 0, stream>>>(W_ss, W_vv_s, W_sv, W_vs, W_vv_v,
                                          (u32*)WSp, (u32*)WVp, s_n, 1600160);
  }
  edge_kernel<<<NEDGES / EB, 256, 0, stream>>>(x, ea, eidx, WSp, WVp, s_n, v_n,
                                               (u16*)msg, use_msg);
  if (use_msg)
    gather_kernel<<<2500, 256, 0, stream>>>(off, elist, msg, s_n, v_n);
  stats_kernel<<<200, 256, 0, stream>>>(s_n, v_n, stats);
  finalize_kernel<<<(NNODES * 160 + 255) / 256, 256, 0, stream>>>(
      s_n, v_n, stats, x, bw_s, bb_s, bw_v, out);
}

// Round 13
// 374.099 us; speedup vs baseline: 1.4753x; 1.0448x over previous
//
#include <hip/hip_runtime.h>
#include <hip/hip_bf16.h>

// NodeProcessor via MFMA. R13: shrink edge-kernel LDS 52.7->41.6 KB by NOT
// staging the s2/v2 (edge_attr) rows — each lane reads its own two edges'
// 40 floats directly from global as float4s (one-time, latency-hidden).
// Theory: schedulable LDS pool < nominal 160 KB pins us at 2 blocks/CU;
// 41.6 KB/block -> 3 blocks -> +50% waves. Math is bit-identical (same
// bf16 round-trip). Rest identical to R12 (msg[e][160] + CSR gather).

#define NNODES 10000
#define NEDGES 160000
#define EB 128
#define FSTRD 65                    // fTd row stride in dwords (==1 mod 32)

typedef unsigned short u16;
typedef unsigned int u32;
typedef short short8 __attribute__((ext_vector_type(8)));
typedef float f32x4 __attribute__((ext_vector_type(4)));

__device__ __forceinline__ u16 f2b(float f) {  // RNE
  union { float f; u32 i; } v; v.f = f;
  u32 r = v.i + 0x7FFFu + ((v.i >> 16) & 1u);
  return (u16)(r >> 16);
}
__device__ __forceinline__ float lo_f(u32 d) {
  union { u32 i; float f; } v; v.i = d << 16; return v.f;
}
__device__ __forceinline__ float hi_f(u32 d) {
  union { u32 i; float f; } v; v.i = d & 0xFFFF0000u; return v.f;
}
__device__ __forceinline__ float qb(float f) {  // quantize to bf16 grid
  union { u32 i; float f; } v; v.i = ((u32)f2b(f)) << 16; return v.f;
}
__device__ __forceinline__ u32 pk2(float lo, float hi) {
  return __builtin_amdgcn_perm(__float_as_uint(hi), __float_as_uint(lo), 0x07060302u);
}
union frag_u { u32 w[4]; short8 s; };

#define INVF  0.02795084971874737f   // 1/sqrt(1280)
#define INV3  0.5773502691896258f    // 1/sqrt(3)
#define INV2  0.7071067811865476f    // 1/sqrt(2)

// ---- prep: pack weights + zero region ------------------------------------
__global__ void prep_kernel(const float* __restrict__ W_ss, const float* __restrict__ W_vv_s,
                            const float* __restrict__ W_sv, const float* __restrict__ W_vs,
                            const float* __restrict__ W_vv_v,
                            u32* __restrict__ WSd, u32* __restrict__ WVd,
                            float* __restrict__ zbase, int zcount) {
  int t = blockIdx.x * 256 + threadIdx.x;
  if (t < zcount) zbase[t] = 0.f;
  if (t < 61440) {            // W_S dwords
    int d = t;
    int nt = d / 10240, r = d - nt * 10240;
    int kt = r >> 8, l = (r & 255) >> 2, jp = r & 3;
    int n = nt * 16 + (l & 15);
    int k0 = kt * 32 + ((l >> 4) << 3) + jp * 2;
    float f0, f1;
    f0 = (k0     < 1024) ? W_ss[k0 * 96 + n] * INVF       : W_vv_s[(k0 - 1024) * 96 + n] * (INVF * INV3);
    f1 = (k0 + 1 < 1024) ? W_ss[(k0 + 1) * 96 + n] * INVF : W_vv_s[(k0 - 1023) * 96 + n] * (INVF * INV3);
    WSd[d] = (u32)f2b(f0) | ((u32)f2b(f1) << 16);
  } else if (t < 81920) {     // W_V dwords
    int d = t - 61440;
    int nt = d / 10240, r = d - nt * 10240;
    int kt = r >> 8, l = (r & 255) >> 2, jp = r & 3;
    int n = nt * 16 + (l & 15);
    int k0 = kt * 32 + ((l >> 4) << 3) + jp * 2;
    float f[2];
#pragma unroll
    for (int jj = 0; jj < 2; jj++) {
      int k = k0 + jj;
      if (k < 512)       f[jj] = W_sv[k * 32 + n] * INVF;
      else if (k < 1024) f[jj] = W_vs[(k - 512) * 32 + n] * INVF;
      else               f[jj] = W_vv_v[(k - 1024) * 32 + n] * (INVF * INV2);
    }
    WVd[d] = (u32)f2b(f[0]) | ((u32)f2b(f[1]) << 16);
  }
}

// ---- CSR build (count AFTER prep zeroes cnt; separate launches) ----------
__global__ void count_kernel(const int* __restrict__ eidx, int* __restrict__ cnt) {
  int t = blockIdx.x * 256 + threadIdx.x;
  if (t < NEDGES) atomicAdd(&cnt[eidx[t]], 1);
}

__global__ void scan_kernel(const int* __restrict__ cnt, int* __restrict__ off,
                            int* __restrict__ cursor) {
  __shared__ int part[1024];
  int t = threadIdx.x;
  int local[10]; int s = 0;
  if (t < 1000) {
#pragma unroll
    for (int i = 0; i < 10; i++) { local[i] = cnt[t * 10 + i]; s += local[i]; }
  }
  part[t] = s; __syncthreads();
  for (int d = 1; d < 1024; d <<= 1) {
    int v = (t >= d) ? part[t - d] : 0; __syncthreads();
    part[t] += v; __syncthreads();
  }
  if (t < 1000) {
    int ex = (t == 0) ? 0 : part[t - 1];
#pragma unroll
    for (int i = 0; i < 10; i++) { off[t * 10 + i] = ex; cursor[t * 10 + i] = ex; ex += local[i]; }
  }
  if (t == 0) off[10000] = NEDGES;
}

__global__ void fill_kernel(const int* __restrict__ eidx, int* __restrict__ cursor,
                            int* __restrict__ elist) {
  int t = blockIdx.x * 256 + threadIdx.x;
  if (t < NEDGES) {
    int slot = atomicAdd(&cursor[eidx[t]], 1);
    elist[slot] = t;
  }
}

// ---- edge kernel ---------------------------------------------------------
__global__ __launch_bounds__(256, 2) void edge_kernel(
    const float* __restrict__ x, const float* __restrict__ ea,
    const int* __restrict__ eidx,
    const u16* __restrict__ WSp, const u16* __restrict__ WVp,
    float* __restrict__ s_n, float* __restrict__ v_n,
    u16* __restrict__ msg16, int use_msg) {
  __shared__ int idxL[EB];
  __shared__ u32 fTd[160 * FSTRD];  // [j][ep]: lo=edge ep, hi=edge ep+64 (x only)
  const int tid = threadIdx.x;
  const int eb = blockIdx.x * EB;

  if (tid < EB) idxL[tid] = eidx[eb + tid];
  __syncthreads();
#pragma unroll 1
  for (int t = tid; t < 64 * 160; t += 256) {
    int ep2 = t / 160, j = t - ep2 * 160;
    float vlo = x[(size_t)idxL[ep2] * 160 + j];
    float vhi = x[(size_t)idxL[ep2 + 64] * 160 + j];
    fTd[j * FSTRD + ep2] = (u32)f2b(vlo) | ((u32)f2b(vhi) << 16);
  }
  __syncthreads();

  const int wv = tid >> 6, lane = tid & 63;
  const int ln = lane & 15, quad = lane >> 4;
  const int ep = wv * 16 + ln;
  const int qh = quad >> 1, bb = (quad & 1) * 8;

  // s2/v2 hoists: straight from global (this lane's 2 edges), bf16-quantized
  const float* eaL = ea + (size_t)(eb + ep) * 40;
  const float* eaH = eaL + 64 * 40;
  float s2l[8], s2h[8], v2l[24], v2h[24];
  {
    float4 a0 = *(const float4*)(eaL + bb), a1 = *(const float4*)(eaL + bb + 4);
    float4 b0 = *(const float4*)(eaH + bb), b1 = *(const float4*)(eaH + bb + 4);
    s2l[0]=qb(a0.x); s2l[1]=qb(a0.y); s2l[2]=qb(a0.z); s2l[3]=qb(a0.w);
    s2l[4]=qb(a1.x); s2l[5]=qb(a1.y); s2l[6]=qb(a1.z); s2l[7]=qb(a1.w);
    s2h[0]=qb(b0.x); s2h[1]=qb(b0.y); s2h[2]=qb(b0.z); s2h[3]=qb(b0.w);
    s2h[4]=qb(b1.x); s2h[5]=qb(b1.y); s2h[6]=qb(b1.z); s2h[7]=qb(b1.w);
#pragma unroll
    for (int i = 0; i < 6; i++) {
      float4 va = *(const float4*)(eaL + 16 + 4 * i);
      float4 vb = *(const float4*)(eaH + 16 + 4 * i);
      v2l[4*i+0]=qb(va.x); v2l[4*i+1]=qb(va.y); v2l[4*i+2]=qb(va.z); v2l[4*i+3]=qb(va.w);
      v2h[4*i+0]=qb(vb.x); v2h[4*i+1]=qb(vb.y); v2h[4*i+2]=qb(vb.z); v2h[4*i+3]=qb(vb.w);
    }
  }

  const u16* WS_l = WSp + (size_t)lane * 8;
  const u16* WV_l = WVp + (size_t)lane * 8;

#define LOAD_BS(B, ktv) { _Pragma("unroll") \
  for (int nt = 0; nt < 6; nt++) B[nt].s = *(const short8*)(WS_l + (size_t)(ktv) * 512 + nt * 20480); }
#define LOAD_BV(C, ktv) { _Pragma("unroll") \
  for (int nt = 0; nt < 2; nt++) C[nt].s = *(const short8*)(WV_l + (size_t)(ktv) * 512 + nt * 20480); }
#define MFMA_S(Al, Ah, B) { _Pragma("unroll") \
  for (int nt = 0; nt < 6; nt++) { \
    aS[0][nt] = __builtin_amdgcn_mfma_f32_16x16x32_bf16(Al.s, B[nt].s, aS[0][nt], 0, 0, 0); \
    aS[1][nt] = __builtin_amdgcn_mfma_f32_16x16x32_bf16(Ah.s, B[nt].s, aS[1][nt], 0, 0, 0); } }
#define MFMA_V(Al, Ah, C, p) { \
    aV[0][p][0] = __builtin_amdgcn_mfma_f32_16x16x32_bf16(Al.s, C[0].s, aV[0][p][0], 0, 0, 0); \
    aV[0][p][1] = __builtin_amdgcn_mfma_f32_16x16x32_bf16(Al.s, C[1].s, aV[0][p][1], 0, 0, 0); \
    aV[1][p][0] = __builtin_amdgcn_mfma_f32_16x16x32_bf16(Ah.s, C[0].s, aV[1][p][0], 0, 0, 0); \
    aV[1][p][1] = __builtin_amdgcn_mfma_f32_16x16x32_bf16(Ah.s, C[1].s, aV[1][p][1], 0, 0, 0); }

  // ================= S phase =================
  f32x4 aS[2][6];
#pragma unroll
  for (int t = 0; t < 2; t++)
#pragma unroll
    for (int i = 0; i < 6; i++) aS[t][i] = (f32x4){0.f, 0.f, 0.f, 0.f};

  frag_u B0[6], B1[6];
  LOAD_BS(B0, 0);

#pragma unroll 1
  for (int c = 0; c < 16; c++) {      // region ss: kt 0..31
    int kt = 2 * c;
    u32 dA = fTd[(2 * kt + qh) * FSTRD + ep];
    u32 dB = fTd[(2 * kt + 2 + qh) * FSTRD + ep];
    LOAD_BS(B1, kt + 1);
    {
      frag_u Al, Ah;
      float slo = lo_f(dA), shi = hi_f(dA);
#pragma unroll
      for (int jp = 0; jp < 4; jp++) {
        Al.w[jp] = pk2(slo * s2l[2 * jp], slo * s2l[2 * jp + 1]);
        Ah.w[jp] = pk2(shi * s2h[2 * jp], shi * s2h[2 * jp + 1]);
      }
      MFMA_S(Al, Ah, B0);
    }
    LOAD_BS(B0, kt + 2);
    {
      frag_u Al, Ah;
      float slo = lo_f(dB), shi = hi_f(dB);
#pragma unroll
      for (int jp = 0; jp < 4; jp++) {
        Al.w[jp] = pk2(slo * s2l[2 * jp], slo * s2l[2 * jp + 1]);
        Ah.w[jp] = pk2(shi * s2h[2 * jp], shi * s2h[2 * jp + 1]);
      }
      MFMA_S(Al, Ah, B1);
    }
  }
#pragma unroll 1
  for (int c = 0; c < 4; c++) {       // region dot3: kt 32..39
    int kt = 32 + 2 * c;
    int r0 = (64 + (4 * (kt - 32) + quad) * 3) * FSTRD + ep;
    int r1 = r0 + 12 * FSTRD;
    u32 d0 = fTd[r0], d1 = fTd[r0 + FSTRD], d2 = fTd[r0 + 2 * FSTRD];
    u32 e0 = fTd[r1], e1 = fTd[r1 + FSTRD], e2 = fTd[r1 + 2 * FSTRD];
    LOAD_BS(B1, kt + 1);
    {
      frag_u Al, Ah;
      float x0 = lo_f(d0), x1 = lo_f(d1), x2 = lo_f(d2);
      float y0 = hi_f(d0), y1 = hi_f(d1), y2 = hi_f(d2);
#pragma unroll
      for (int jp = 0; jp < 4; jp++) {
        int j0 = 6 * jp, j1 = 6 * jp + 3;
        Al.w[jp] = pk2(x0*v2l[j0] + x1*v2l[j0+1] + x2*v2l[j0+2],
                       x0*v2l[j1] + x1*v2l[j1+1] + x2*v2l[j1+2]);
        Ah.w[jp] = pk2(y0*v2h[j0] + y1*v2h[j0+1] + y2*v2h[j0+2],
                       y0*v2h[j1] + y1*v2h[j1+1] + y2*v2h[j1+2]);
      }
      MFMA_S(Al, Ah, B0);
    }
    LOAD_BS(B0, kt + 2);
    {
      frag_u Al, Ah;
      float x0 = lo_f(e0), x1 = lo_f(e1), x2 = lo_f(e2);
      float y0 = hi_f(e0), y1 = hi_f(e1), y2 = hi_f(e2);
#pragma unroll
      for (int jp = 0; jp < 4; jp++) {
        int j0 = 6 * jp, j1 = 6 * jp + 3;
        Al.w[jp] = pk2(x0*v2l[j0] + x1*v2l[j0+1] + x2*v2l[j0+2],
                       x0*v2l[j1] + x1*v2l[j1+1] + x2*v2l[j1+2]);
        Ah.w[jp] = pk2(y0*v2h[j0] + y1*v2h[j0+1] + y2*v2h[j0+2],
                       y0*v2h[j1] + y1*v2h[j1+1] + y2*v2h[j1+2]);
      }
      MFMA_S(Al, Ah, B1);
    }
  }

  frag_u C0[2], C1[2];
  LOAD_BV(C0, 32);

  // S epilogue: silu -> msg store (or atomic fallback); gates -> regs
  float gateR[16];
#pragma unroll
  for (int t = 0; t < 2; t++) {
#pragma unroll
    for (int r = 0; r < 4; r++) {
      int er = wv * 16 + quad * 4 + r + t * 64;
      int nid = idxL[er];
#pragma unroll
      for (int nt = 0; nt < 6; nt++) {
        float v = aS[t][nt][r];
        float sg = 1.f / (1.f + __expf(-v));
        if (nt < 4) {
          if (use_msg) msg16[(size_t)(eb + er) * 160 + nt * 16 + ln] = f2b(v * sg);
          else         atomicAdd(&s_n[nid * 64 + nt * 16 + ln], v * sg);
        } else gateR[t * 8 + (nt - 4) * 4 + r] = sg;
      }
    }
  }

  // ================= V phase =================
  f32x4 aV[2][3][2];
#pragma unroll
  for (int t = 0; t < 2; t++)
#pragma unroll
    for (int p = 0; p < 3; p++)
#pragma unroll
      for (int nt = 0; nt < 2; nt++) aV[t][p][nt] = (f32x4){0.f, 0.f, 0.f, 0.f};

#pragma unroll 1
  for (int c = 0; c < 4; c++) {       // region cross: kt 32..39
    int kt = 32 + 2 * c;
    int r0 = (64 + (4 * (kt - 32) + quad) * 3) * FSTRD + ep;
    int r1 = r0 + 12 * FSTRD;
    u32 d0 = fTd[r0], d1 = fTd[r0 + FSTRD], d2 = fTd[r0 + 2 * FSTRD];
    u32 e0 = fTd[r1], e1 = fTd[r1 + FSTRD], e2 = fTd[r1 + 2 * FSTRD];
    LOAD_BV(C1, kt + 1);
    {
      float wl[3] = { lo_f(d0), lo_f(d1), lo_f(d2) };
      float wh[3] = { hi_f(d0), hi_f(d1), hi_f(d2) };
#pragma unroll
      for (int p = 0; p < 3; p++) {
        const int p1 = (p + 1) % 3, p2 = (p + 2) % 3;
        frag_u Al, Ah;
#pragma unroll
        for (int jp = 0; jp < 4; jp++) {
          int j0 = 6 * jp, j1 = 6 * jp + 3;
          Al.w[jp] = pk2(wl[p1]*v2l[j0+p2] - wl[p2]*v2l[j0+p1],
                         wl[p1]*v2l[j1+p2] - wl[p2]*v2l[j1+p1]);
          Ah.w[jp] = pk2(wh[p1]*v2h[j0+p2] - wh[p2]*v2h[j0+p1],
                         wh[p1]*v2h[j1+p2] - wh[p2]*v2h[j1+p1]);
        }
        MFMA_V(Al, Ah, C0, p);
      }
    }
    LOAD_BV(C0, (c < 3) ? (kt + 2) : 0);
    {
      float wl[3] = { lo_f(e0), lo_f(e1), lo_f(e2) };
      float wh[3] = { hi_f(e0), hi_f(e1), hi_f(e2) };
#pragma unroll
      for (int p = 0; p < 3; p++) {
        const int p1 = (p + 1) % 3, p2 = (p + 2) % 3;
        frag_u Al, Ah;
#pragma unroll
        for (int jp = 0; jp < 4; jp++) {
          int j0 = 6 * jp, j1 = 6 * jp + 3;
          Al.w[jp] = pk2(wl[p1]*v2l[j0+p2] - wl[p2]*v2l[j0+p1],
                         wl[p1]*v2l[j1+p2] - wl[p2]*v2l[j1+p1]);
          Ah.w[jp] = pk2(wh[p1]*v2h[j0+p2] - wh[p2]*v2h[j0+p1],
                         wh[p1]*v2h[j1+p2] - wh[p2]*v2h[j1+p1]);
        }
        MFMA_V(Al, Ah, C1, p);
      }
    }
  }
#pragma unroll 1
  for (int c = 0; c < 8; c++) {       // region sv: kt 0..15
    int kt = 2 * c;
    u32 dA = fTd[(4 * kt + quad) * FSTRD + ep];
    u32 dB = fTd[(4 * kt + 4 + quad) * FSTRD + ep];
    LOAD_BV(C1, kt + 1);
    {
      float slo = lo_f(dA), shi = hi_f(dA);
#pragma unroll
      for (int p = 0; p < 3; p++) {
        frag_u Al, Ah;
#pragma unroll
        for (int jp = 0; jp < 4; jp++) {
          Al.w[jp] = pk2(slo * v2l[(2*jp)*3 + p], slo * v2l[(2*jp+1)*3 + p]);
          Ah.w[jp] = pk2(shi * v2h[(2*jp)*3 + p], shi * v2h[(2*jp+1)*3 + p]);
        }
        MFMA_V(Al, Ah, C0, p);
      }
    }
    LOAD_BV(C0, kt + 2);
    {
      float slo = lo_f(dB), shi = hi_f(dB);
#pragma unroll
      for (int p = 0; p < 3; p++) {
        frag_u Al, Ah;
#pragma unroll
        for (int jp = 0; jp < 4; jp++) {
          Al.w[jp] = pk2(slo * v2l[(2*jp)*3 + p], slo * v2l[(2*jp+1)*3 + p]);
          Ah.w[jp] = pk2(shi * v2h[(2*jp)*3 + p], shi * v2h[(2*jp+1)*3 + p]);
        }
        MFMA_V(Al, Ah, C1, p);
      }
    }
  }
#pragma unroll 1
  for (int c = 0; c < 8; c++) {       // region vs: kt 16..31
    int kt = 16 + 2 * c;
    int r0 = (64 + (2 * (kt - 16) + qh) * 3) * FSTRD + ep;
    int r1 = r0 + 6 * FSTRD;
    u32 d0 = fTd[r0], d1 = fTd[r0 + FSTRD], d2 = fTd[r0 + 2 * FSTRD];
    u32 e0 = fTd[r1], e1 = fTd[r1 + FSTRD], e2 = fTd[r1 + 2 * FSTRD];
    LOAD_BV(C1, kt + 1);
    {
      float vl[3] = { lo_f(d0), lo_f(d1), lo_f(d2) };
      float vh[3] = { hi_f(d0), hi_f(d1), hi_f(d2) };
#pragma unroll
      for (int p = 0; p < 3; p++) {
        frag_u Al, Ah;
#pragma unroll
        for (int jp = 0; jp < 4; jp++) {
          Al.w[jp] = pk2(vl[p] * s2l[2*jp], vl[p] * s2l[2*jp+1]);
          Ah.w[jp] = pk2(vh[p] * s2h[2*jp], vh[p] * s2h[2*jp+1]);
        }
        MFMA_V(Al, Ah, C0, p);
      }
    }
    LOAD_BV(C0, (c < 7) ? (kt + 2) : 0);
    {
      float vl[3] = { lo_f(e0), lo_f(e1), lo_f(e2) };
      float vh[3] = { hi_f(e0), hi_f(e1), hi_f(e2) };
#pragma unroll
      for (int p = 0; p < 3; p++) {
        frag_u Al, Ah;
#pragma unroll
        for (int jp = 0; jp < 4; jp++) {
          Al.w[jp] = pk2(vl[p] * s2l[2*jp], vl[p] * s2l[2*jp+1]);
          Ah.w[jp] = pk2(vh[p] * s2h[2*jp], vh[p] * s2h[2*jp+1]);
        }
        MFMA_V(Al, Ah, C1, p);
      }
    }
  }

  // V epilogue: gate + msg store (ch = 64 + c*3 + p, matches v_n order)
#pragma unroll
  for (int t = 0; t < 2; t++) {
#pragma unroll
    for (int r = 0; r < 4; r++) {
      int er = wv * 16 + quad * 4 + r + t * 64;
      int nid = idxL[er];
#pragma unroll
      for (int nt = 0; nt < 2; nt++) {
        int c = nt * 16 + ln;
        float g = gateR[t * 8 + nt * 4 + r];
#pragma unroll
        for (int p = 0; p < 3; p++) {
          float val = aV[t][p][nt][r] * g;
          if (use_msg) msg16[(size_t)(eb + er) * 160 + 64 + c * 3 + p] = f2b(val);
          else         atomicAdd(&v_n[nid * 96 + c * 3 + p], val);
        }
      }
    }
  }
}

// ---- gather: one wave per node, shfl-broadcast edge ids, no atomics ------
__global__ __launch_bounds__(256) void gather_kernel(
    const int* __restrict__ off, const int* __restrict__ elist,
    const u32* __restrict__ msg, float* __restrict__ s_n, float* __restrict__ v_n) {
  int tid = threadIdx.x;
  int n = blockIdx.x * 4 + (tid >> 6);
  int lane = tid & 63;
  int beg = off[n], end = off[n + 1];
  float a0 = 0.f, a1 = 0.f, b0 = 0.f, b1 = 0.f;
#pragma unroll 1
  for (int k0 = beg; k0 < end; k0 += 64) {
    int m = end - k0; if (m > 64) m = 64;
    int myE = (lane < m) ? elist[k0 + lane] : 0;
#pragma unroll 2
    for (int k = 0; k < m; k++) {
      int e = __shfl(myE, k);
      u32 w0 = msg[(size_t)e * 80 + lane];
      a0 += lo_f(w0); a1 += hi_f(w0);
      if (lane < 16) {
        u32 w1 = msg[(size_t)e * 80 + 64 + lane];
        b0 += lo_f(w1); b1 += hi_f(w1);
      }
    }
  }
  int ch = 2 * lane;
  if (ch < 64) {
    s_n[n * 64 + ch] = a0; s_n[n * 64 + ch + 1] = a1;
  } else {
    int q = ch - 64;
    v_n[n * 96 + q] = a0; v_n[n * 96 + q + 1] = a1;
  }
  if (lane < 16) {
    int q = 64 + 2 * lane;
    v_n[n * 96 + q] = b0; v_n[n * 96 + q + 1] = b1;
  }
}

// ---- BN stats ------------------------------------------------------------
__global__ void stats_kernel(const float* __restrict__ s_n, const float* __restrict__ v_n,
                             float* __restrict__ stats) {
  int b = blockIdx.x, tid = threadIdx.x;
  int r0 = b * 50;
  int c = tid & 63, rg = tid >> 6;
  float s = 0.f, sq = 0.f;
  for (int r = r0 + rg; r < r0 + 50; r += 4) {
    float v = s_n[r * 64 + c];
    s += v; sq += v * v;
  }
  atomicAdd(&stats[c], s);
  atomicAdd(&stats[64 + c], sq);
  int c2 = tid & 31, rg2 = tid >> 5;
  float vn = 0.f;
  for (int r = r0 + rg2; r < r0 + 50; r += 8) {
    const float* vp = &v_n[r * 96 + c2 * 3];
    vn += vp[0] * vp[0] + vp[1] * vp[1] + vp[2] * vp[2];
  }
  atomicAdd(&stats[128 + c2], vn);
}

// ---- finalize ------------------------------------------------------------
__global__ void finalize_kernel(const float* __restrict__ s_n, const float* __restrict__ v_n,
                                const float* __restrict__ stats,
                                const float* __restrict__ x,
                                const float* __restrict__ bw_s, const float* __restrict__ bb_s,
                                const float* __restrict__ bw_v,
                                float* __restrict__ out) {
  int t = blockIdx.x * 256 + threadIdx.x;
  if (t >= NNODES * 160) return;
  int n = t / 160, j = t - n * 160;
  float xv = x[t];
  float r;
  if (j < 64) {
    float mu  = stats[j] * (1.f / NNODES);
    float var = stats[64 + j] * (1.f / NNODES) - mu * mu;
    var = fmaxf(var, 0.f);
    float v = s_n[n * 64 + j];
    r = (v - mu) * rsqrtf(var + 1e-5f) * bw_s[j] + bb_s[j];
  } else {
    int qq = j - 64;
    int c = qq / 3;
    float vn = stats[128 + c] * (1.f / (3.f * NNODES));
    float v = v_n[n * 96 + qq];
    r = v * rsqrtf(vn + 1e-5f) * bw_v[c];
  }
  out[t] = r + xv;
}

extern "C" void kernel_launch(void* const* d_in, const int* in_sizes, int n_in,
                              void* d_out, int out_size, void* d_ws, size_t ws_size,
                              hipStream_t stream) {
  const float* x      = (const float*)d_in[0];
  const float* ea     = (const float*)d_in[1];
  const float* W_ss   = (const float*)d_in[2];
  const float* W_vv_s = (const float*)d_in[3];
  const float* W_sv   = (const float*)d_in[4];
  const float* W_vs   = (const float*)d_in[5];
  const float* W_vv_v = (const float*)d_in[6];
  const float* bw_s   = (const float*)d_in[7];
  const float* bb_s   = (const float*)d_in[8];
  const float* bw_v   = (const float*)d_in[9];
  const int* eidx     = (const int*)d_in[10];
  float* out = (float*)d_out;

  float* ws    = (float*)d_ws;
  u16* WSp     = (u16*)d_ws;              // 122880 u16
  u16* WVp     = WSp + 122880;            // 40960 u16
  float* s_n   = ws + 81920;              // 640000
  float* v_n   = s_n + 640000;            // 960000
  float* stats = v_n + 960000;            // 160  (at 1681920)
  int* cnt     = (int*)(ws + 1682080);    // 10000 (contiguous after stats)
  int* off     = (int*)(ws + 1692080);    // 10001 (pad to 10004)
  int* cursor  = (int*)(ws + 1702084);    // 10000
  int* elist   = (int*)(ws + 1712084);    // 160000
  u32* msg     = (u32*)(ws + 1872084);    // 12,800,000 dwords = msg[e][160] bf16
  // total = 14,672,084 floats = 58,688,336 bytes

  int use_msg = (ws_size >= 58688336ULL) ? 1 : 0;

  if (use_msg) {
    prep_kernel<<<6251, 256, 0, stream>>>(W_ss, W_vv_s, W_sv, W_vs, W_vv_v,
                                          (u32*)WSp, (u32*)WVp, stats, 10160);
    count_kernel<<<625, 256, 0, stream>>>(eidx, cnt);   // AFTER prep zeroes cnt
    scan_kernel<<<1, 1024, 0, stream>>>(cnt, off, cursor);
    fill_kernel<<<625, 256, 0, stream>>>(eidx, cursor, elist);
  } else {
    prep_kernel<<<6251, 256, 0, stream>>>(W_ss, W_vv_s, W_sv, W_vs, W_vv_v,
                                          (u32*)WSp, (u32*)WVp, s_n, 1600160);
  }
  edge_kernel<<<NEDGES / EB, 256, 0, stream>>>(x, ea, eidx, WSp, WVp, s_n, v_n,
                                               (u16*)msg, use_msg);
  if (use_msg)
    gather_kernel<<<2500, 256, 0, stream>>>(off, elist, msg, s_n, v_n);
  stats_kernel<<<200, 256, 0, stream>>>(s_n, v_n, stats);
  finalize_kernel<<<(NNODES * 160 + 255) / 256, 256, 0, stream>>>(
      s_n, v_n, stats, x, bw_s, bb_s, bw_v, out);
}

// Round 14
// 373.171 us; speedup vs baseline: 1.4790x; 1.0025x over previous
//
#include <hip/hip_runtime.h>
#include <hip/hip_bf16.h>

// NodeProcessor via MFMA. R14: NODE-SORTED edge processing. Edge kernel
// consumes CSR slot order (elist) so consecutive edges share x rows (~16-run
// reuse -> x staging hits cache; R13 FETCH showed 87MB = random-row HBM
// misses). Messages land contiguous per node -> gather streams msg[off[n]..)
// with no elist indirection. Aux: zeroing via hipMemsetAsync; count fused
// into prep (cnt zeroed by stream-ordered memset BEFORE prep — not R11's
// same-kernel race). GEMM core unchanged from R13.

#define NNODES 10000
#define NEDGES 160000
#define EB 128
#define FSTRD 65                    // fTd row stride in dwords (==1 mod 32)

typedef unsigned short u16;
typedef unsigned int u32;
typedef short short8 __attribute__((ext_vector_type(8)));
typedef float f32x4 __attribute__((ext_vector_type(4)));

__device__ __forceinline__ u16 f2b(float f) {  // RNE
  union { float f; u32 i; } v; v.f = f;
  u32 r = v.i + 0x7FFFu + ((v.i >> 16) & 1u);
  return (u16)(r >> 16);
}
__device__ __forceinline__ float lo_f(u32 d) {
  union { u32 i; float f; } v; v.i = d << 16; return v.f;
}
__device__ __forceinline__ float hi_f(u32 d) {
  union { u32 i; float f; } v; v.i = d & 0xFFFF0000u; return v.f;
}
__device__ __forceinline__ float qb(float f) {  // quantize to bf16 grid
  union { u32 i; float f; } v; v.i = ((u32)f2b(f)) << 16; return v.f;
}
__device__ __forceinline__ u32 pk2(float lo, float hi) {
  return __builtin_amdgcn_perm(__float_as_uint(hi), __float_as_uint(lo), 0x07060302u);
}
union frag_u { u32 w[4]; short8 s; };

#define INVF  0.02795084971874737f   // 1/sqrt(1280)
#define INV3  0.5773502691896258f    // 1/sqrt(3)
#define INV2  0.7071067811865476f    // 1/sqrt(2)

// ---- prep: pack weights (+ fused degree count; cnt pre-zeroed by memset) --
__global__ void prep_kernel(const float* __restrict__ W_ss, const float* __restrict__ W_vv_s,
                            const float* __restrict__ W_sv, const float* __restrict__ W_vs,
                            const float* __restrict__ W_vv_v,
                            u32* __restrict__ WSd, u32* __restrict__ WVd,
                            const int* __restrict__ eidx, int* __restrict__ cnt,
                            int do_count) {
  int t = blockIdx.x * 256 + threadIdx.x;
  if (do_count && t < NEDGES) atomicAdd(&cnt[eidx[t]], 1);
  if (t < 61440) {            // W_S dwords
    int d = t;
    int nt = d / 10240, r = d - nt * 10240;
    int kt = r >> 8, l = (r & 255) >> 2, jp = r & 3;
    int n = nt * 16 + (l & 15);
    int k0 = kt * 32 + ((l >> 4) << 3) + jp * 2;
    float f0, f1;
    f0 = (k0     < 1024) ? W_ss[k0 * 96 + n] * INVF       : W_vv_s[(k0 - 1024) * 96 + n] * (INVF * INV3);
    f1 = (k0 + 1 < 1024) ? W_ss[(k0 + 1) * 96 + n] * INVF : W_vv_s[(k0 - 1023) * 96 + n] * (INVF * INV3);
    WSd[d] = (u32)f2b(f0) | ((u32)f2b(f1) << 16);
  } else if (t < 81920) {     // W_V dwords
    int d = t - 61440;
    int nt = d / 10240, r = d - nt * 10240;
    int kt = r >> 8, l = (r & 255) >> 2, jp = r & 3;
    int n = nt * 16 + (l & 15);
    int k0 = kt * 32 + ((l >> 4) << 3) + jp * 2;
    float f[2];
#pragma unroll
    for (int jj = 0; jj < 2; jj++) {
      int k = k0 + jj;
      if (k < 512)       f[jj] = W_sv[k * 32 + n] * INVF;
      else if (k < 1024) f[jj] = W_vs[(k - 512) * 32 + n] * INVF;
      else               f[jj] = W_vv_v[(k - 1024) * 32 + n] * (INVF * INV2);
    }
    WVd[d] = (u32)f2b(f[0]) | ((u32)f2b(f[1]) << 16);
  }
}

__global__ void scan_kernel(const int* __restrict__ cnt, int* __restrict__ off,
                            int* __restrict__ cursor) {
  __shared__ int part[1024];
  int t = threadIdx.x;
  int local[10]; int s = 0;
  if (t < 1000) {
#pragma unroll
    for (int i = 0; i < 10; i++) { local[i] = cnt[t * 10 + i]; s += local[i]; }
  }
  part[t] = s; __syncthreads();
  for (int d = 1; d < 1024; d <<= 1) {
    int v = (t >= d) ? part[t - d] : 0; __syncthreads();
    part[t] += v; __syncthreads();
  }
  if (t < 1000) {
    int ex = (t == 0) ? 0 : part[t - 1];
#pragma unroll
    for (int i = 0; i < 10; i++) { off[t * 10 + i] = ex; cursor[t * 10 + i] = ex; ex += local[i]; }
  }
  if (t == 0) off[10000] = NEDGES;
}

__global__ void fill_kernel(const int* __restrict__ eidx, int* __restrict__ cursor,
                            int* __restrict__ elist) {
  int t = blockIdx.x * 256 + threadIdx.x;
  if (t < NEDGES) {
    int slot = atomicAdd(&cursor[eidx[t]], 1);
    elist[slot] = t;
  }
}

// ---- edge kernel (processes SLOT order when use_msg) ---------------------
__global__ __launch_bounds__(256, 2) void edge_kernel(
    const float* __restrict__ x, const float* __restrict__ ea,
    const int* __restrict__ eidx, const int* __restrict__ elist,
    const u16* __restrict__ WSp, const u16* __restrict__ WVp,
    float* __restrict__ s_n, float* __restrict__ v_n,
    u16* __restrict__ msg16, int use_msg) {
  __shared__ int idxL[EB];
  __shared__ int eoL[EB];
  __shared__ u32 fTd[160 * FSTRD];  // [j][ep]: lo=edge ep, hi=edge ep+64 (x only)
  const int tid = threadIdx.x;
  const int eb = blockIdx.x * EB;

  if (tid < EB) {
    int eo = use_msg ? elist[eb + tid] : (eb + tid);
    eoL[tid] = eo;
    idxL[tid] = eidx[eo];
  }
  __syncthreads();
#pragma unroll 1
  for (int t = tid; t < 64 * 160; t += 256) {
    int ep2 = t / 160, j = t - ep2 * 160;
    float vlo = x[(size_t)idxL[ep2] * 160 + j];
    float vhi = x[(size_t)idxL[ep2 + 64] * 160 + j];
    fTd[j * FSTRD + ep2] = (u32)f2b(vlo) | ((u32)f2b(vhi) << 16);
  }
  __syncthreads();

  const int wv = tid >> 6, lane = tid & 63;
  const int ln = lane & 15, quad = lane >> 4;
  const int ep = wv * 16 + ln;
  const int qh = quad >> 1, bb = (quad & 1) * 8;

  // s2/v2 hoists: straight from global (this lane's 2 edges), bf16-quantized
  const float* eaL = ea + (size_t)eoL[ep] * 40;
  const float* eaH = ea + (size_t)eoL[ep + 64] * 40;
  float s2l[8], s2h[8], v2l[24], v2h[24];
  {
    float4 a0 = *(const float4*)(eaL + bb), a1 = *(const float4*)(eaL + bb + 4);
    float4 b0 = *(const float4*)(eaH + bb), b1 = *(const float4*)(eaH + bb + 4);
    s2l[0]=qb(a0.x); s2l[1]=qb(a0.y); s2l[2]=qb(a0.z); s2l[3]=qb(a0.w);
    s2l[4]=qb(a1.x); s2l[5]=qb(a1.y); s2l[6]=qb(a1.z); s2l[7]=qb(a1.w);
    s2h[0]=qb(b0.x); s2h[1]=qb(b0.y); s2h[2]=qb(b0.z); s2h[3]=qb(b0.w);
    s2h[4]=qb(b1.x); s2h[5]=qb(b1.y); s2h[6]=qb(b1.z); s2h[7]=qb(b1.w);
#pragma unroll
    for (int i = 0; i < 6; i++) {
      float4 va = *(const float4*)(eaL + 16 + 4 * i);
      float4 vb = *(const float4*)(eaH + 16 + 4 * i);
      v2l[4*i+0]=qb(va.x); v2l[4*i+1]=qb(va.y); v2l[4*i+2]=qb(va.z); v2l[4*i+3]=qb(va.w);
      v2h[4*i+0]=qb(vb.x); v2h[4*i+1]=qb(vb.y); v2h[4*i+2]=qb(vb.z); v2h[4*i+3]=qb(vb.w);
    }
  }

  const u16* WS_l = WSp + (size_t)lane * 8;
  const u16* WV_l = WVp + (size_t)lane * 8;

#define LOAD_BS(B, ktv) { _Pragma("unroll") \
  for (int nt = 0; nt < 6; nt++) B[nt].s = *(const short8*)(WS_l + (size_t)(ktv) * 512 + nt * 20480); }
#define LOAD_BV(C, ktv) { _Pragma("unroll") \
  for (int nt = 0; nt < 2; nt++) C[nt].s = *(const short8*)(WV_l + (size_t)(ktv) * 512 + nt * 20480); }
#define MFMA_S(Al, Ah, B) { _Pragma("unroll") \
  for (int nt = 0; nt < 6; nt++) { \
    aS[0][nt] = __builtin_amdgcn_mfma_f32_16x16x32_bf16(Al.s, B[nt].s, aS[0][nt], 0, 0, 0); \
    aS[1][nt] = __builtin_amdgcn_mfma_f32_16x16x32_bf16(Ah.s, B[nt].s, aS[1][nt], 0, 0, 0); } }
#define MFMA_V(Al, Ah, C, p) { \
    aV[0][p][0] = __builtin_amdgcn_mfma_f32_16x16x32_bf16(Al.s, C[0].s, aV[0][p][0], 0, 0, 0); \
    aV[0][p][1] = __builtin_amdgcn_mfma_f32_16x16x32_bf16(Al.s, C[1].s, aV[0][p][1], 0, 0, 0); \
    aV[1][p][0] = __builtin_amdgcn_mfma_f32_16x16x32_bf16(Ah.s, C[0].s, aV[1][p][0], 0, 0, 0); \
    aV[1][p][1] = __builtin_amdgcn_mfma_f32_16x16x32_bf16(Ah.s, C[1].s, aV[1][p][1], 0, 0, 0); }

  // ================= S phase =================
  f32x4 aS[2][6];
#pragma unroll
  for (int t = 0; t < 2; t++)
#pragma unroll
    for (int i = 0; i < 6; i++) aS[t][i] = (f32x4){0.f, 0.f, 0.f, 0.f};

  frag_u B0[6], B1[6];
  LOAD_BS(B0, 0);

#pragma unroll 1
  for (int c = 0; c < 16; c++) {      // region ss: kt 0..31
    int kt = 2 * c;
    u32 dA = fTd[(2 * kt + qh) * FSTRD + ep];
    u32 dB = fTd[(2 * kt + 2 + qh) * FSTRD + ep];
    LOAD_BS(B1, kt + 1);
    {
      frag_u Al, Ah;
      float slo = lo_f(dA), shi = hi_f(dA);
#pragma unroll
      for (int jp = 0; jp < 4; jp++) {
        Al.w[jp] = pk2(slo * s2l[2 * jp], slo * s2l[2 * jp + 1]);
        Ah.w[jp] = pk2(shi * s2h[2 * jp], shi * s2h[2 * jp + 1]);
      }
      MFMA_S(Al, Ah, B0);
    }
    LOAD_BS(B0, kt + 2);
    {
      frag_u Al, Ah;
      float slo = lo_f(dB), shi = hi_f(dB);
#pragma unroll
      for (int jp = 0; jp < 4; jp++) {
        Al.w[jp] = pk2(slo * s2l[2 * jp], slo * s2l[2 * jp + 1]);
        Ah.w[jp] = pk2(shi * s2h[2 * jp], shi * s2h[2 * jp + 1]);
      }
      MFMA_S(Al, Ah, B1);
    }
  }
#pragma unroll 1
  for (int c = 0; c < 4; c++) {       // region dot3: kt 32..39
    int kt = 32 + 2 * c;
    int r0 = (64 + (4 * (kt - 32) + quad) * 3) * FSTRD + ep;
    int r1 = r0 + 12 * FSTRD;
    u32 d0 = fTd[r0], d1 = fTd[r0 + FSTRD], d2 = fTd[r0 + 2 * FSTRD];
    u32 e0 = fTd[r1], e1 = fTd[r1 + FSTRD], e2 = fTd[r1 + 2 * FSTRD];
    LOAD_BS(B1, kt + 1);
    {
      frag_u Al, Ah;
      float x0 = lo_f(d0), x1 = lo_f(d1), x2 = lo_f(d2);
      float y0 = hi_f(d0), y1 = hi_f(d1), y2 = hi_f(d2);
#pragma unroll
      for (int jp = 0; jp < 4; jp++) {
        int j0 = 6 * jp, j1 = 6 * jp + 3;
        Al.w[jp] = pk2(x0*v2l[j0] + x1*v2l[j0+1] + x2*v2l[j0+2],
                       x0*v2l[j1] + x1*v2l[j1+1] + x2*v2l[j1+2]);
        Ah.w[jp] = pk2(y0*v2h[j0] + y1*v2h[j0+1] + y2*v2h[j0+2],
                       y0*v2h[j1] + y1*v2h[j1+1] + y2*v2h[j1+2]);
      }
      MFMA_S(Al, Ah, B0);
    }
    LOAD_BS(B0, kt + 2);
    {
      frag_u Al, Ah;
      float x0 = lo_f(e0), x1 = lo_f(e1), x2 = lo_f(e2);
      float y0 = hi_f(e0), y1 = hi_f(e1), y2 = hi_f(e2);
#pragma unroll
      for (int jp = 0; jp < 4; jp++) {
        int j0 = 6 * jp, j1 = 6 * jp + 3;
        Al.w[jp] = pk2(x0*v2l[j0] + x1*v2l[j0+1] + x2*v2l[j0+2],
                       x0*v2l[j1] + x1*v2l[j1+1] + x2*v2l[j1+2]);
        Ah.w[jp] = pk2(y0*v2h[j0] + y1*v2h[j0+1] + y2*v2h[j0+2],
                       y0*v2h[j1] + y1*v2h[j1+1] + y2*v2h[j1+2]);
      }
      MFMA_S(Al, Ah, B1);
    }
  }

  frag_u C0[2], C1[2];
  LOAD_BV(C0, 32);

  // S epilogue: silu -> msg store (or atomic fallback); gates -> regs
  float gateR[16];
#pragma unroll
  for (int t = 0; t < 2; t++) {
#pragma unroll
    for (int r = 0; r < 4; r++) {
      int er = wv * 16 + quad * 4 + r + t * 64;
      int nid = idxL[er];
#pragma unroll
      for (int nt = 0; nt < 6; nt++) {
        float v = aS[t][nt][r];
        float sg = 1.f / (1.f + __expf(-v));
        if (nt < 4) {
          if (use_msg) msg16[(size_t)(eb + er) * 160 + nt * 16 + ln] = f2b(v * sg);
          else         atomicAdd(&s_n[nid * 64 + nt * 16 + ln], v * sg);
        } else gateR[t * 8 + (nt - 4) * 4 + r] = sg;
      }
    }
  }

  // ================= V phase =================
  f32x4 aV[2][3][2];
#pragma unroll
  for (int t = 0; t < 2; t++)
#pragma unroll
    for (int p = 0; p < 3; p++)
#pragma unroll
      for (int nt = 0; nt < 2; nt++) aV[t][p][nt] = (f32x4){0.f, 0.f, 0.f, 0.f};

#pragma unroll 1
  for (int c = 0; c < 4; c++) {       // region cross: kt 32..39
    int kt = 32 + 2 * c;
    int r0 = (64 + (4 * (kt - 32) + quad) * 3) * FSTRD + ep;
    int r1 = r0 + 12 * FSTRD;
    u32 d0 = fTd[r0], d1 = fTd[r0 + FSTRD], d2 = fTd[r0 + 2 * FSTRD];
    u32 e0 = fTd[r1], e1 = fTd[r1 + FSTRD], e2 = fTd[r1 + 2 * FSTRD];
    LOAD_BV(C1, kt + 1);
    {
      float wl[3] = { lo_f(d0), lo_f(d1), lo_f(d2) };
      float wh[3] = { hi_f(d0), hi_f(d1), hi_f(d2) };
#pragma unroll
      for (int p = 0; p < 3; p++) {
        const int p1 = (p + 1) % 3, p2 = (p + 2) % 3;
        frag_u Al, Ah;
#pragma unroll
        for (int jp = 0; jp < 4; jp++) {
          int j0 = 6 * jp, j1 = 6 * jp + 3;
          Al.w[jp] = pk2(wl[p1]*v2l[j0+p2] - wl[p2]*v2l[j0+p1],
                         wl[p1]*v2l[j1+p2] - wl[p2]*v2l[j1+p1]);
          Ah.w[jp] = pk2(wh[p1]*v2h[j0+p2] - wh[p2]*v2h[j0+p1],
                         wh[p1]*v2h[j1+p2] - wh[p2]*v2h[j1+p1]);
        }
        MFMA_V(Al, Ah, C0, p);
      }
    }
    LOAD_BV(C0, (c < 3) ? (kt + 2) : 0);
    {
      float wl[3] = { lo_f(e0), lo_f(e1), lo_f(e2) };
      float wh[3] = { hi_f(e0), hi_f(e1), hi_f(e2) };
#pragma unroll
      for (int p = 0; p < 3; p++) {
        const int p1 = (p + 1) % 3, p2 = (p + 2) % 3;
        frag_u Al, Ah;
#pragma unroll
        for (int jp = 0; jp < 4; jp++) {
          int j0 = 6 * jp, j1 = 6 * jp + 3;
          Al.w[jp] = pk2(wl[p1]*v2l[j0+p2] - wl[p2]*v2l[j0+p1],
                         wl[p1]*v2l[j1+p2] - wl[p2]*v2l[j1+p1]);
          Ah.w[jp] = pk2(wh[p1]*v2h[j0+p2] - wh[p2]*v2h[j0+p1],
                         wh[p1]*v2h[j1+p2] - wh[p2]*v2h[j1+p1]);
        }
        MFMA_V(Al, Ah, C1, p);
      }
    }
  }
#pragma unroll 1
  for (int c = 0; c < 8; c++) {       // region sv: kt 0..15
    int kt = 2 * c;
    u32 dA = fTd[(4 * kt + quad) * FSTRD + ep];
    u32 dB = fTd[(4 * kt + 4 + quad) * FSTRD + ep];
    LOAD_BV(C1, kt + 1);
    {
      float slo = lo_f(dA), shi = hi_f(dA);
#pragma unroll
      for (int p = 0; p < 3; p++) {
        frag_u Al, Ah;
#pragma unroll
        for (int jp = 0; jp < 4; jp++) {
          Al.w[jp] = pk2(slo * v2l[(2*jp)*3 + p], slo * v2l[(2*jp+1)*3 + p]);
          Ah.w[jp] = pk2(shi * v2h[(2*jp)*3 + p], shi * v2h[(2*jp+1)*3 + p]);
        }
        MFMA_V(Al, Ah, C0, p);
      }
    }
    LOAD_BV(C0, kt + 2);
    {
      float slo = lo_f(dB), shi = hi_f(dB);
#pragma unroll
      for (int p = 0; p < 3; p++) {
        frag_u Al, Ah;
#pragma unroll
        for (int jp = 0; jp < 4; jp++) {
          Al.w[jp] = pk2(slo * v2l[(2*jp)*3 + p], slo * v2l[(2*jp+1)*3 + p]);
          Ah.w[jp] = pk2(shi * v2h[(2*jp)*3 + p], shi * v2h[(2*jp+1)*3 + p]);
        }
        MFMA_V(Al, Ah, C1, p);
      }
    }
  }
#pragma unroll 1
  for (int c = 0; c < 8; c++) {       // region vs: kt 16..31
    int kt = 16 + 2 * c;
    int r0 = (64 + (2 * (kt - 16) + qh) * 3) * FSTRD + ep;
    int r1 = r0 + 6 * FSTRD;
    u32 d0 = fTd[r0], d1 = fTd[r0 + FSTRD], d2 = fTd[r0 + 2 * FSTRD];
    u32 e0 = fTd[r1], e1 = fTd[r1 + FSTRD], e2 = fTd[r1 + 2 * FSTRD];
    LOAD_BV(C1, kt + 1);
    {
      float vl[3] = { lo_f(d0), lo_f(d1), lo_f(d2) };
      float vh[3] = { hi_f(d0), hi_f(d1), hi_f(d2) };
#pragma unroll
      for (int p = 0; p < 3; p++) {
        frag_u Al, Ah;
#pragma unroll
        for (int jp = 0; jp < 4; jp++) {
          Al.w[jp] = pk2(vl[p] * s2l[2*jp], vl[p] * s2l[2*jp+1]);
          Ah.w[jp] = pk2(vh[p] * s2h[2*jp], vh[p] * s2h[2*jp+1]);
        }
        MFMA_V(Al, Ah, C0, p);
      }
    }
    LOAD_BV(C0, (c < 7) ? (kt + 2) : 0);
    {
      float vl[3] = { lo_f(e0), lo_f(e1), lo_f(e2) };
      float vh[3] = { hi_f(e0), hi_f(e1), hi_f(e2) };
#pragma unroll
      for (int p = 0; p < 3; p++) {
        frag_u Al, Ah;
#pragma unroll
        for (int jp = 0; jp < 4; jp++) {
          Al.w[jp] = pk2(vl[p] * s2l[2*jp], vl[p] * s2l[2*jp+1]);
          Ah.w[jp] = pk2(vh[p] * s2h[2*jp], vh[p] * s2h[2*jp+1]);
        }
        MFMA_V(Al, Ah, C1, p);
      }
    }
  }

  // V epilogue: gate + msg store (ch = 64 + c*3 + p, matches v_n order)
#pragma unroll
  for (int t = 0; t < 2; t++) {
#pragma unroll
    for (int r = 0; r < 4; r++) {
      int er = wv * 16 + quad * 4 + r + t * 64;
      int nid = idxL[er];
#pragma unroll
      for (int nt = 0; nt < 2; nt++) {
        int c = nt * 16 + ln;
        float g = gateR[t * 8 + nt * 4 + r];
#pragma unroll
        for (int p = 0; p < 3; p++) {
          float val = aV[t][p][nt][r] * g;
          if (use_msg) msg16[(size_t)(eb + er) * 160 + 64 + c * 3 + p] = f2b(val);
          else         atomicAdd(&v_n[nid * 96 + c * 3 + p], val);
        }
      }
    }
  }
}

// ---- gather: one wave per node; msg slots contiguous per node ------------
__global__ __launch_bounds__(256) void gather_kernel(
    const int* __restrict__ off, const u32* __restrict__ msg,
    float* __restrict__ s_n, float* __restrict__ v_n) {
  int tid = threadIdx.x;
  int n = blockIdx.x * 4 + (tid >> 6);
  int lane = tid & 63;
  int beg = off[n], end = off[n + 1];
  float a0 = 0.f, a1 = 0.f, b0 = 0.f, b1 = 0.f;
#pragma unroll 2
  for (int k = beg; k < end; k++) {
    u32 w0 = msg[(size_t)k * 80 + lane];
    a0 += lo_f(w0); a1 += hi_f(w0);
    if (lane < 16) {
      u32 w1 = msg[(size_t)k * 80 + 64 + lane];
      b0 += lo_f(w1); b1 += hi_f(w1);
    }
  }
  int ch = 2 * lane;
  if (ch < 64) {
    s_n[n * 64 + ch] = a0; s_n[n * 64 + ch + 1] = a1;
  } else {
    int q = ch - 64;
    v_n[n * 96 + q] = a0; v_n[n * 96 + q + 1] = a1;
  }
  if (lane < 16) {
    int q = 64 + 2 * lane;
    v_n[n * 96 + q] = b0; v_n[n * 96 + q + 1] = b1;
  }
}

// ---- BN stats ------------------------------------------------------------
__global__ void stats_kernel(const float* __restrict__ s_n, const float* __restrict__ v_n,
                             float* __restrict__ stats) {
  int b = blockIdx.x, tid = threadIdx.x;
  int r0 = b * 50;
  int c = tid & 63, rg = tid >> 6;
  float s = 0.f, sq = 0.f;
  for (int r = r0 + rg; r < r0 + 50; r += 4) {
    float v = s_n[r * 64 + c];
    s += v; sq += v * v;
  }
  atomicAdd(&stats[c], s);
  atomicAdd(&stats[64 + c], sq);
  int c2 = tid & 31, rg2 = tid >> 5;
  float vn = 0.f;
  for (int r = r0 + rg2; r < r0 + 50; r += 8) {
    const float* vp = &v_n[r * 96 + c2 * 3];
    vn += vp[0] * vp[0] + vp[1] * vp[1] + vp[2] * vp[2];
  }
  atomicAdd(&stats[128 + c2], vn);
}

// ---- finalize ------------------------------------------------------------
__global__ void finalize_kernel(const float* __restrict__ s_n, const float* __restrict__ v_n,
                                const float* __restrict__ stats,
                                const float* __restrict__ x,
                                const float* __restrict__ bw_s, const float* __restrict__ bb_s,
                                const float* __restrict__ bw_v,
                                float* __restrict__ out) {
  int t = blockIdx.x * 256 + threadIdx.x;
  if (t >= NNODES * 160) return;
  int n = t / 160, j = t - n * 160;
  float xv = x[t];
  float r;
  if (j < 64) {
    float mu  = stats[j] * (1.f / NNODES);
    float var = stats[64 + j] * (1.f / NNODES) - mu * mu;
    var = fmaxf(var, 0.f);
    float v = s_n[n * 64 + j];
    r = (v - mu) * rsqrtf(var + 1e-5f) * bw_s[j] + bb_s[j];
  } else {
    int qq = j - 64;
    int c = qq / 3;
    float vn = stats[128 + c] * (1.f / (3.f * NNODES));
    float v = v_n[n * 96 + qq];
    r = v * rsqrtf(vn + 1e-5f) * bw_v[c];
  }
  out[t] = r + xv;
}

extern "C" void kernel_launch(void* const* d_in, const int* in_sizes, int n_in,
                              void* d_out, int out_size, void* d_ws, size_t ws_size,
                              hipStream_t stream) {
  const float* x      = (const float*)d_in[0];
  const float* ea     = (const float*)d_in[1];
  const float* W_ss   = (const float*)d_in[2];
  const float* W_vv_s = (const float*)d_in[3];
  const float* W_sv   = (const float*)d_in[4];
  const float* W_vs   = (const float*)d_in[5];
  const float* W_vv_v = (const float*)d_in[6];
  const float* bw_s   = (const float*)d_in[7];
  const float* bb_s   = (const float*)d_in[8];
  const float* bw_v   = (const float*)d_in[9];
  const int* eidx     = (const int*)d_in[10];
  float* out = (float*)d_out;

  float* ws    = (float*)d_ws;
  u16* WSp     = (u16*)d_ws;              // 122880 u16
  u16* WVp     = WSp + 122880;            // 40960 u16
  float* s_n   = ws + 81920;              // 640000
  float* v_n   = s_n + 640000;            // 960000
  float* stats = v_n + 960000;            // 160  (at 1681920)
  int* cnt     = (int*)(ws + 1682080);    // 10000
  int* off     = (int*)(ws + 1692080);    // 10001 (pad to 10004)
  int* cursor  = (int*)(ws + 1702084);    // 10000
  int* elist   = (int*)(ws + 1712084);    // 160000
  u32* msg     = (u32*)(ws + 1872084);    // 12,800,000 dwords = msg[e][160] bf16
  // total = 14,672,084 floats = 58,688,336 bytes

  int use_msg = (ws_size >= 58688336ULL) ? 1 : 0;

  if (use_msg) {
    hipMemsetAsync(stats, 0, 160 * sizeof(float), stream);
    hipMemsetAsync(cnt, 0, NNODES * sizeof(int), stream);
    prep_kernel<<<625, 256, 0, stream>>>(W_ss, W_vv_s, W_sv, W_vs, W_vv_v,
                                         (u32*)WSp, (u32*)WVp, eidx, cnt, 1);
    scan_kernel<<<1, 1024, 0, stream>>>(cnt, off, cursor);
    fill_kernel<<<625, 256, 0, stream>>>(eidx, cursor, elist);
  } else {
    hipMemsetAsync(s_n, 0, 1600160 * sizeof(float), stream);
    prep_kernel<<<625, 256, 0, stream>>>(W_ss, W_vv_s, W_sv, W_vs, W_vv_v,
                                         (u32*)WSp, (u32*)WVp, eidx, cnt, 0);
  }
  edge_kernel<<<NEDGES / EB, 256, 0, stream>>>(x, ea, eidx, elist, WSp, WVp,
                                               s_n, v_n, (u16*)msg, use_msg);
  if (use_msg)
    gather_kernel<<<2500, 256, 0, stream>>>(off, msg, s_n, v_n);
  stats_kernel<<<200, 256, 0, stream>>>(s_n, v_n, stats);
  finalize_kernel<<<(NNODES * 160 + 255) / 256, 256, 0, stream>>>(
      s_n, v_n, stats, x, bw_s, bb_s, bw_v, out);
}